// Round 1
// baseline (1139.685 us; speedup 1.0000x reference)
//
#include <hip/hip_runtime.h>

#define LN_EPS 1e-5f

// ---------------- CSR build ----------------

__global__ void k_hist(const int* __restrict__ dst, int e, int* __restrict__ cnt) {
    int i = blockIdx.x * blockDim.x + threadIdx.x;
    if (i < e) atomicAdd(&cnt[dst[i]], 1);
}

__global__ void k_dinv(const int* __restrict__ cnt, int n, float* __restrict__ dinv) {
    int i = blockIdx.x * blockDim.x + threadIdx.x;
    if (i < n) dinv[i] = rsqrtf((float)(cnt[i] + 1));   // +1 self loop, deg>=1
}

__global__ void k_scan1(const int* __restrict__ cnt, int n,
                        int* __restrict__ row_ptr, int* __restrict__ bsum) {
    __shared__ int s[1024];
    int tid = threadIdx.x;
    int i = blockIdx.x * 1024 + tid;
    int v = (i < n) ? cnt[i] : 0;
    s[tid] = v; __syncthreads();
    for (int o = 1; o < 1024; o <<= 1) {
        int t = (tid >= o) ? s[tid - o] : 0;
        __syncthreads();
        s[tid] += t;
        __syncthreads();
    }
    if (i < n) row_ptr[i] = s[tid] - v;          // local exclusive
    if (tid == 1023) bsum[blockIdx.x] = s[tid];  // block total
}

__global__ void k_scan2(int* __restrict__ bsum, int nb) {
    __shared__ int s[1024];
    int tid = threadIdx.x;
    int v = (tid < nb) ? bsum[tid] : 0;
    s[tid] = v; __syncthreads();
    for (int o = 1; o < 1024; o <<= 1) {
        int t = (tid >= o) ? s[tid - o] : 0;
        __syncthreads();
        s[tid] += t;
        __syncthreads();
    }
    if (tid < nb) bsum[tid] = s[tid] - v;        // exclusive
}

__global__ void k_scan3(int* __restrict__ row_ptr, const int* __restrict__ bsum,
                        int n, int e) {
    int i = blockIdx.x * blockDim.x + threadIdx.x;
    if (i < n) row_ptr[i] += bsum[i >> 10];
    if (i == 0) row_ptr[n] = e;
}

__global__ void k_scatter(const int* __restrict__ src, const int* __restrict__ dst, int e,
                          const float* __restrict__ dinv, const int* __restrict__ row_ptr,
                          int* __restrict__ pos, int* __restrict__ csr_src,
                          float* __restrict__ csr_w) {
    int i = blockIdx.x * blockDim.x + threadIdx.x;
    if (i < e) {
        int d = dst[i], s = src[i];
        int p = row_ptr[d] + atomicAdd(&pos[d], 1);
        csr_src[p] = s;
        csr_w[p] = dinv[s] * dinv[d];
    }
}

// ---------------- Aggregation (gather by destination) ----------------

__global__ void k_agg64(const float* __restrict__ x, const float* __restrict__ dinv,
                        const int* __restrict__ row_ptr, const int* __restrict__ csr_src,
                        const float* __restrict__ csr_w, float* __restrict__ out, int n) {
    int lane = threadIdx.x & 63;
    int wid = (blockIdx.x * blockDim.x + threadIdx.x) >> 6;
    int nw = (gridDim.x * blockDim.x) >> 6;
    for (int i = wid; i < n; i += nw) {
        float di = dinv[i];
        float acc = x[(size_t)i * 64 + lane] * di * di;
        int j0 = row_ptr[i], j1 = row_ptr[i + 1];
        for (int j = j0; j < j1; ++j) {
            int s = csr_src[j];
            float w = csr_w[j];
            acc += x[(size_t)s * 64 + lane] * w;
        }
        out[(size_t)i * 64 + lane] = acc;
    }
}

__global__ void k_agg128(const float* __restrict__ h, const float* __restrict__ dinv,
                         const int* __restrict__ row_ptr, const int* __restrict__ csr_src,
                         const float* __restrict__ csr_w, float* __restrict__ out, int n) {
    int lane = threadIdx.x & 63;
    int wid = (blockIdx.x * blockDim.x + threadIdx.x) >> 6;
    int nw = (gridDim.x * blockDim.x) >> 6;
    const float2* h2 = (const float2*)h;
    float2* o2 = (float2*)out;
    for (int i = wid; i < n; i += nw) {
        float di = dinv[i];
        float2 v = h2[(size_t)i * 64 + lane];
        float2 acc = make_float2(v.x * di * di, v.y * di * di);
        int j0 = row_ptr[i], j1 = row_ptr[i + 1];
        for (int j = j0; j < j1; ++j) {
            int s = csr_src[j];
            float w = csr_w[j];
            float2 u = h2[(size_t)s * 64 + lane];
            acc.x += u.x * w;
            acc.y += u.y * w;
        }
        o2[(size_t)i * 64 + lane] = acc;
    }
}

// ---------------- GEMM + LayerNorm (+ReLU) fused ----------------

__launch_bounds__(256)
__global__ void k_gemm1(const float* __restrict__ agg, const float* __restrict__ W,
                        const float* __restrict__ bias, const float* __restrict__ gam,
                        const float* __restrict__ bet, float* __restrict__ out, int n) {
    __shared__ float sW[64 * 128];
    for (int t = threadIdx.x; t < 64 * 128; t += blockDim.x) sW[t] = W[t];
    __syncthreads();
    int lane = threadIdx.x & 63, wv = threadIdx.x >> 6;
    int wpb = blockDim.x >> 6;
    float bs0 = bias[lane], bs1 = bias[64 + lane];
    float gm0 = gam[lane],  gm1 = gam[64 + lane];
    float bt0 = bet[lane],  bt1 = bet[64 + lane];
    for (int i = blockIdx.x * wpb + wv; i < n; i += gridDim.x * wpb) {
        float v = agg[(size_t)i * 64 + lane];
        float a0 = 0.f, a1 = 0.f;
        #pragma unroll
        for (int k = 0; k < 64; ++k) {
            float xv = __shfl(v, k);
            a0 = fmaf(xv, sW[k * 128 + lane], a0);
            a1 = fmaf(xv, sW[k * 128 + 64 + lane], a1);
        }
        a0 += bs0; a1 += bs1;
        float s = a0 + a1;
        #pragma unroll
        for (int o = 32; o > 0; o >>= 1) s += __shfl_xor(s, o);
        float mu = s * (1.f / 128.f);
        float e0 = a0 - mu, e1 = a1 - mu;
        float q = e0 * e0 + e1 * e1;
        #pragma unroll
        for (int o = 32; o > 0; o >>= 1) q += __shfl_xor(q, o);
        float rstd = rsqrtf(q * (1.f / 128.f) + LN_EPS);
        float r0 = fmaf(e0 * rstd, gm0, bt0);
        float r1 = fmaf(e1 * rstd, gm1, bt1);
        out[(size_t)i * 128 + lane]      = fmaxf(r0, 0.f);
        out[(size_t)i * 128 + 64 + lane] = fmaxf(r1, 0.f);
    }
}

__launch_bounds__(256)
__global__ void k_gemm2(const float* __restrict__ agg, const float* __restrict__ W,
                        const float* __restrict__ bias, const float* __restrict__ gam,
                        const float* __restrict__ bet, float* __restrict__ out, int n) {
    __shared__ float sW[128 * 128];   // 64 KiB
    for (int t = threadIdx.x; t < 128 * 128; t += blockDim.x) sW[t] = W[t];
    __syncthreads();
    int lane = threadIdx.x & 63, wv = threadIdx.x >> 6;
    int wpb = blockDim.x >> 6;
    float bs0 = bias[lane], bs1 = bias[64 + lane];
    float gm0 = gam[lane],  gm1 = gam[64 + lane];
    float bt0 = bet[lane],  bt1 = bet[64 + lane];
    for (int i = blockIdx.x * wpb + wv; i < n; i += gridDim.x * wpb) {
        float v0 = agg[(size_t)i * 128 + lane];
        float v1 = agg[(size_t)i * 128 + 64 + lane];
        float a0 = 0.f, a1 = 0.f;
        #pragma unroll
        for (int k = 0; k < 64; ++k) {
            float xv = __shfl(v0, k);
            a0 = fmaf(xv, sW[k * 128 + lane], a0);
            a1 = fmaf(xv, sW[k * 128 + 64 + lane], a1);
        }
        #pragma unroll
        for (int k = 0; k < 64; ++k) {
            float xv = __shfl(v1, k);
            a0 = fmaf(xv, sW[(64 + k) * 128 + lane], a0);
            a1 = fmaf(xv, sW[(64 + k) * 128 + 64 + lane], a1);
        }
        a0 += bs0; a1 += bs1;
        float s = a0 + a1;
        #pragma unroll
        for (int o = 32; o > 0; o >>= 1) s += __shfl_xor(s, o);
        float mu = s * (1.f / 128.f);
        float e0 = a0 - mu, e1 = a1 - mu;
        float q = e0 * e0 + e1 * e1;
        #pragma unroll
        for (int o = 32; o > 0; o >>= 1) q += __shfl_xor(q, o);
        float rstd = rsqrtf(q * (1.f / 128.f) + LN_EPS);
        out[(size_t)i * 128 + lane]      = fmaf(e0 * rstd, gm0, bt0);
        out[(size_t)i * 128 + 64 + lane] = fmaf(e1 * rstd, gm1, bt1);
    }
}

// ---------------- Mean pooling over sorted batch ----------------

__device__ __forceinline__ int lowerb(const int* __restrict__ b, int n, int key) {
    int lo = 0, hi = n;
    while (lo < hi) {
        int m = (lo + hi) >> 1;
        if (b[m] < key) lo = m + 1; else hi = m;
    }
    return lo;
}

__global__ void k_pool(const float* __restrict__ h2, const int* __restrict__ batch,
                       int n, float* __restrict__ out) {
    int g = blockIdx.x;
    int start = lowerb(batch, n, g);
    int end   = lowerb(batch, n, g + 1);
    int f = threadIdx.x & 127, half = threadIdx.x >> 7;   // 8 row-groups
    float acc = 0.f;
    for (int r = start + half; r < end; r += 8)
        acc += h2[(size_t)r * 128 + f];
    __shared__ float part[1024];
    part[threadIdx.x] = acc;
    __syncthreads();
    if (threadIdx.x < 128) {
        float v = 0.f;
        #pragma unroll
        for (int j = 0; j < 8; ++j) v += part[f + 128 * j];
        int c = end - start;
        out[g * 128 + f] = v / fmaxf((float)c, 1.f);
    }
}

// ---------------- launch ----------------

extern "C" void kernel_launch(void* const* d_in, const int* in_sizes, int n_in,
                              void* d_out, int out_size, void* d_ws, size_t ws_size,
                              hipStream_t stream) {
    const float* x   = (const float*)d_in[0];
    const int*   ei  = (const int*)d_in[1];
    const int*   bat = (const int*)d_in[2];
    const float* W1  = (const float*)d_in[3];
    const float* b1  = (const float*)d_in[4];
    const float* g1  = (const float*)d_in[5];
    const float* be1 = (const float*)d_in[6];
    const float* W2  = (const float*)d_in[7];
    const float* b2  = (const float*)d_in[8];
    const float* g2  = (const float*)d_in[9];
    const float* be2 = (const float*)d_in[10];

    int n = in_sizes[0] / 64;     // 100000
    int e = in_sizes[1] / 2;      // 1600000
    int G = out_size / 128;       // 128
    const int* src = ei;
    const int* dst = ei + e;

    char* ws = (char*)d_ws;
    size_t off = 0;
    auto take = [&](size_t bytes) -> void* {
        void* p = ws + off;
        off = (off + bytes + 255) & ~(size_t)255;
        return p;
    };
    int*   cnt     = (int*)  take((size_t)n * 4);
    int*   pos     = (int*)  take((size_t)n * 4);
    float* dinv    = (float*)take((size_t)n * 4);
    int*   row_ptr = (int*)  take((size_t)(n + 1) * 4);
    int*   bsum    = (int*)  take(1024 * 4);
    int*   csr_src = (int*)  take((size_t)e * 4);
    float* csr_w   = (float*)take((size_t)e * 4);
    float* aggx    = (float*)take((size_t)n * 64 * 4);
    float* h       = (float*)take((size_t)n * 128 * 4);
    float* agg2    = (float*)take((size_t)n * 128 * 4);

    hipMemsetAsync(cnt, 0, (size_t)n * 4, stream);
    hipMemsetAsync(pos, 0, (size_t)n * 4, stream);

    k_hist<<<(e + 255) / 256, 256, 0, stream>>>(dst, e, cnt);
    k_dinv<<<(n + 255) / 256, 256, 0, stream>>>(cnt, n, dinv);
    int nb = (n + 1023) / 1024;
    k_scan1<<<nb, 1024, 0, stream>>>(cnt, n, row_ptr, bsum);
    k_scan2<<<1, 1024, 0, stream>>>(bsum, nb);
    k_scan3<<<(n + 255) / 256, 256, 0, stream>>>(row_ptr, bsum, n, e);
    k_scatter<<<(e + 255) / 256, 256, 0, stream>>>(src, dst, e, dinv, row_ptr, pos,
                                                   csr_src, csr_w);

    k_agg64<<<2048, 256, 0, stream>>>(x, dinv, row_ptr, csr_src, csr_w, aggx, n);
    k_gemm1<<<1024, 256, 0, stream>>>(aggx, W1, b1, g1, be1, h, n);
    k_agg128<<<2048, 256, 0, stream>>>(h, dinv, row_ptr, csr_src, csr_w, agg2, n);
    k_gemm2<<<1024, 256, 0, stream>>>(agg2, W2, b2, g2, be2, agg2, n);
    k_pool<<<G, 1024, 0, stream>>>(agg2, bat, n, (float*)d_out);
}

// Round 2
// 446.008 us; speedup vs baseline: 2.5553x; 2.5553x over previous
//
#include <hip/hip_runtime.h>

#define LN_EPS 1e-5f

typedef __attribute__((ext_vector_type(8))) short short8v;
typedef __attribute__((ext_vector_type(4))) float float4v;

__device__ __forceinline__ float bflo(unsigned u) { return __uint_as_float(u << 16); }
__device__ __forceinline__ float bfhi(unsigned u) { return __uint_as_float(u & 0xffff0000u); }
__device__ __forceinline__ unsigned short f2bf(float f) {
    unsigned b = __float_as_uint(f);
    unsigned r = b + 0x7fffu + ((b >> 16) & 1u);
    return (unsigned short)(r >> 16);
}
__device__ __forceinline__ unsigned pack2(float x, float y) {
    return (unsigned)f2bf(x) | ((unsigned)f2bf(y) << 16);
}

union U4S8 { uint4 u; short8v s; };

// ---------------- CSR build ----------------

__global__ void k_hist(const int* __restrict__ dst, int e, int* __restrict__ cnt) {
    int i = blockIdx.x * blockDim.x + threadIdx.x;
    if (i < e) atomicAdd(&cnt[dst[i]], 1);
}

__global__ void k_dinv(const int* __restrict__ cnt, int n, float* __restrict__ dinv) {
    int i = blockIdx.x * blockDim.x + threadIdx.x;
    if (i < n) dinv[i] = rsqrtf((float)(cnt[i] + 1));
}

__global__ void k_scan1(const int* __restrict__ cnt, int n,
                        int* __restrict__ row_ptr, int* __restrict__ bsum) {
    __shared__ int s[1024];
    int tid = threadIdx.x;
    int i = blockIdx.x * 1024 + tid;
    int v = (i < n) ? cnt[i] : 0;
    s[tid] = v; __syncthreads();
    for (int o = 1; o < 1024; o <<= 1) {
        int t = (tid >= o) ? s[tid - o] : 0;
        __syncthreads();
        s[tid] += t;
        __syncthreads();
    }
    if (i < n) row_ptr[i] = s[tid] - v;
    if (tid == 1023) bsum[blockIdx.x] = s[tid];
}

__global__ void k_scan2(int* __restrict__ bsum, int nb) {
    __shared__ int s[1024];
    int tid = threadIdx.x;
    int v = (tid < nb) ? bsum[tid] : 0;
    s[tid] = v; __syncthreads();
    for (int o = 1; o < 1024; o <<= 1) {
        int t = (tid >= o) ? s[tid - o] : 0;
        __syncthreads();
        s[tid] += t;
        __syncthreads();
    }
    if (tid < nb) bsum[tid] = s[tid] - v;
}

__global__ void k_scan3(int* __restrict__ row_ptr, const int* __restrict__ bsum,
                        int n, int e) {
    int i = blockIdx.x * blockDim.x + threadIdx.x;
    if (i < n) row_ptr[i] += bsum[i >> 10];
    if (i == 0) row_ptr[n] = e;
}

__global__ void k_scatter(const int* __restrict__ src, const int* __restrict__ dst, int e,
                          const float* __restrict__ dinv, const int* __restrict__ row_ptr,
                          int* __restrict__ pos, int* __restrict__ csr_src,
                          float* __restrict__ csr_w) {
    int i = blockIdx.x * blockDim.x + threadIdx.x;
    if (i < e) {
        int d = dst[i], s = src[i];
        int p = row_ptr[d] + atomicAdd(&pos[d], 1);
        csr_src[p] = s;
        csr_w[p] = dinv[s] * dinv[d];
    }
}

// ---------------- fp32 -> bf16x2 pack ----------------

__global__ void k_f2b(const float* __restrict__ in, unsigned* __restrict__ out, int nu) {
    int i = blockIdx.x * blockDim.x + threadIdx.x;
    if (i < nu) {
        float2 v = ((const float2*)in)[i];
        out[i] = pack2(v.x, v.y);
    }
}

// ---------------- Aggregation (bf16 gathers, fp32 accumulate) ----------------

// x: [N][64] bf16 as uint[N][32]. Two edges in flight: lanes 0-31 even, 32-63 odd.
__global__ void k_agg64b(const unsigned* __restrict__ xb, const float* __restrict__ dinv,
                         const int* __restrict__ row_ptr, const int* __restrict__ csr_src,
                         const float* __restrict__ csr_w, unsigned* __restrict__ outb, int n) {
    int lane = threadIdx.x & 63;
    int half = lane >> 5;
    int c = lane & 31;
    int wid = (blockIdx.x * blockDim.x + threadIdx.x) >> 6;
    int nw = (gridDim.x * blockDim.x) >> 6;
    for (int i = wid; i < n; i += nw) {
        float di = dinv[i];
        unsigned su = xb[(size_t)i * 32 + c];
        float accx = 0.f, accy = 0.f;
        if (half == 0) {
            float dd = di * di;
            accx = bflo(su) * dd;
            accy = bfhi(su) * dd;
        }
        int j0 = row_ptr[i], j1 = row_ptr[i + 1];
        int j = j0 + half;
        if (j < j1) {
            int s_n = csr_src[j];
            float w_n = csr_w[j];
            for (; j < j1; j += 2) {
                int s = s_n; float w = w_n;
                if (j + 2 < j1) { s_n = csr_src[j + 2]; w_n = csr_w[j + 2]; }
                unsigned u = xb[(size_t)s * 32 + c];
                accx = fmaf(bflo(u), w, accx);
                accy = fmaf(bfhi(u), w, accy);
            }
        }
        accx += __shfl_xor(accx, 32);
        accy += __shfl_xor(accy, 32);
        if (half == 0) outb[(size_t)i * 32 + c] = pack2(accx, accy);
    }
}

// h: [N][128] bf16 as uint[N][64]. One edge per iteration, 64 lanes cover 128 cols.
__global__ void k_agg128b(const unsigned* __restrict__ hb, const float* __restrict__ dinv,
                          const int* __restrict__ row_ptr, const int* __restrict__ csr_src,
                          const float* __restrict__ csr_w, unsigned* __restrict__ outb, int n) {
    int lane = threadIdx.x & 63;
    int wid = (blockIdx.x * blockDim.x + threadIdx.x) >> 6;
    int nw = (gridDim.x * blockDim.x) >> 6;
    for (int i = wid; i < n; i += nw) {
        float di = dinv[i];
        unsigned su = hb[(size_t)i * 64 + lane];
        float dd = di * di;
        float accx = bflo(su) * dd, accy = bfhi(su) * dd;
        int j0 = row_ptr[i], j1 = row_ptr[i + 1];
        if (j0 < j1) {
            int s_n = csr_src[j0];
            float w_n = csr_w[j0];
            for (int j = j0; j < j1; ++j) {
                int s = s_n; float w = w_n;
                if (j + 1 < j1) { s_n = csr_src[j + 1]; w_n = csr_w[j + 1]; }
                unsigned u = hb[(size_t)s * 64 + lane];
                accx = fmaf(bflo(u), w, accx);
                accy = fmaf(bfhi(u), w, accy);
            }
        }
        outb[(size_t)i * 64 + lane] = pack2(accx, accy);
    }
}

// ---------------- MFMA GEMM + LN (+ReLU) fused ----------------
// mfma_f32_16x16x32_bf16. A frag: lane holds row (lane&15), k = (lane>>4)*8 + j.
// B frag: lane holds col (lane&15), k = (lane>>4)*8 + j.
// C/D: col = lane&15, row = (lane>>4)*4 + reg.

// agg[N][64] bf16 (uint[N][32]) @ W1[64][128] fp32 -> LN -> relu -> hb[N][128] bf16
__launch_bounds__(256)
__global__ void k_mm1(const unsigned* __restrict__ aggb, const float* __restrict__ W1,
                      const float* __restrict__ b1, const float* __restrict__ g1,
                      const float* __restrict__ be1, unsigned short* __restrict__ hbs,
                      int ntiles) {
    int lane = threadIdx.x & 63;
    int wv = threadIdx.x >> 6;
    int wpb = blockDim.x >> 6;
    int lc = lane & 15, lg = lane >> 4;

    // pack B fragments in registers: [kstep][colblock]
    short8v B[2][8];
    #pragma unroll
    for (int ks = 0; ks < 2; ++ks)
        #pragma unroll
        for (int cb = 0; cb < 8; ++cb) {
            short8v f;
            #pragma unroll
            for (int j = 0; j < 8; ++j) {
                int k = ks * 32 + lg * 8 + j;
                f[j] = (short)f2bf(W1[k * 128 + cb * 16 + lc]);
            }
            B[ks][cb] = f;
        }
    float bs[8], gm[8], bt[8];
    #pragma unroll
    for (int cb = 0; cb < 8; ++cb) {
        bs[cb] = b1[cb * 16 + lc];
        gm[cb] = g1[cb * 16 + lc];
        bt[cb] = be1[cb * 16 + lc];
    }

    for (int t = blockIdx.x * wpb + wv; t < ntiles; t += gridDim.x * wpb) {
        size_t arow = (size_t)(t * 16 + lc) * 32;
        U4S8 a0, a1;
        a0.u = *(const uint4*)&aggb[arow + lg * 4];
        a1.u = *(const uint4*)&aggb[arow + 16 + lg * 4];
        float4v acc[8];
        #pragma unroll
        for (int cb = 0; cb < 8; ++cb) acc[cb] = (float4v){0.f, 0.f, 0.f, 0.f};
        #pragma unroll
        for (int cb = 0; cb < 8; ++cb) {
            acc[cb] = __builtin_amdgcn_mfma_f32_16x16x32_bf16(a0.s, B[0][cb], acc[cb], 0, 0, 0);
            acc[cb] = __builtin_amdgcn_mfma_f32_16x16x32_bf16(a1.s, B[1][cb], acc[cb], 0, 0, 0);
        }
        // epilogue: bias + LN + relu, rows = t*16 + lg*4 + reg
        #pragma unroll
        for (int reg = 0; reg < 4; ++reg) {
            float s = 0.f;
            #pragma unroll
            for (int cb = 0; cb < 8; ++cb) { acc[cb][reg] += bs[cb]; s += acc[cb][reg]; }
            s += __shfl_xor(s, 1); s += __shfl_xor(s, 2);
            s += __shfl_xor(s, 4); s += __shfl_xor(s, 8);
            float mu = s * (1.f / 128.f);
            float q = 0.f;
            #pragma unroll
            for (int cb = 0; cb < 8; ++cb) { float e = acc[cb][reg] - mu; q += e * e; }
            q += __shfl_xor(q, 1); q += __shfl_xor(q, 2);
            q += __shfl_xor(q, 4); q += __shfl_xor(q, 8);
            float rstd = rsqrtf(q * (1.f / 128.f) + LN_EPS);
            size_t row = (size_t)(t * 16 + lg * 4 + reg) * 128;
            #pragma unroll
            for (int cb = 0; cb < 8; ++cb) {
                float o = fmaf((acc[cb][reg] - mu) * rstd, gm[cb], bt[cb]);
                hbs[row + cb * 16 + lc] = f2bf(fmaxf(o, 0.f));
            }
        }
    }
}

// agg2[N][128] bf16 (uint[N][64]) @ W2[128][128] fp32 -> LN -> h2[N][128] fp32
__launch_bounds__(256)
__global__ void k_mm2(const unsigned* __restrict__ aggb, const float* __restrict__ W2,
                      const float* __restrict__ b2, const float* __restrict__ g2,
                      const float* __restrict__ be2, float* __restrict__ h2,
                      int ntiles) {
    __shared__ uint4 sB[4 * 8 * 64];   // 32 KiB: frag (ks*8+cb), lane
    for (int idx = threadIdx.x; idx < 2048; idx += blockDim.x) {
        int l = idx & 63;
        int f = idx >> 6;
        int ks = f >> 3, cb = f & 7;
        int kb = ks * 32 + (l >> 4) * 8;
        int col = cb * 16 + (l & 15);
        float p[8];
        #pragma unroll
        for (int j = 0; j < 8; ++j) p[j] = W2[(kb + j) * 128 + col];
        uint4 v;
        v.x = pack2(p[0], p[1]); v.y = pack2(p[2], p[3]);
        v.z = pack2(p[4], p[5]); v.w = pack2(p[6], p[7]);
        sB[idx] = v;
    }
    __syncthreads();

    int lane = threadIdx.x & 63;
    int wv = threadIdx.x >> 6;
    int wpb = blockDim.x >> 6;
    int lc = lane & 15, lg = lane >> 4;
    float bs[8], gm[8], bt[8];
    #pragma unroll
    for (int cb = 0; cb < 8; ++cb) {
        bs[cb] = b2[cb * 16 + lc];
        gm[cb] = g2[cb * 16 + lc];
        bt[cb] = be2[cb * 16 + lc];
    }

    for (int t = blockIdx.x * wpb + wv; t < ntiles; t += gridDim.x * wpb) {
        size_t arow = (size_t)(t * 16 + lc) * 64;
        U4S8 a[4];
        #pragma unroll
        for (int ks = 0; ks < 4; ++ks)
            a[ks].u = *(const uint4*)&aggb[arow + ks * 16 + lg * 4];
        float4v acc[8];
        #pragma unroll
        for (int cb = 0; cb < 8; ++cb) acc[cb] = (float4v){0.f, 0.f, 0.f, 0.f};
        #pragma unroll
        for (int ks = 0; ks < 4; ++ks) {
            #pragma unroll
            for (int cb = 0; cb < 8; ++cb) {
                U4S8 fb;
                fb.u = sB[(ks * 8 + cb) * 64 + lane];
                acc[cb] = __builtin_amdgcn_mfma_f32_16x16x32_bf16(a[ks].s, fb.s, acc[cb], 0, 0, 0);
            }
        }
        #pragma unroll
        for (int reg = 0; reg < 4; ++reg) {
            float s = 0.f;
            #pragma unroll
            for (int cb = 0; cb < 8; ++cb) { acc[cb][reg] += bs[cb]; s += acc[cb][reg]; }
            s += __shfl_xor(s, 1); s += __shfl_xor(s, 2);
            s += __shfl_xor(s, 4); s += __shfl_xor(s, 8);
            float mu = s * (1.f / 128.f);
            float q = 0.f;
            #pragma unroll
            for (int cb = 0; cb < 8; ++cb) { float e = acc[cb][reg] - mu; q += e * e; }
            q += __shfl_xor(q, 1); q += __shfl_xor(q, 2);
            q += __shfl_xor(q, 4); q += __shfl_xor(q, 8);
            float rstd = rsqrtf(q * (1.f / 128.f) + LN_EPS);
            size_t row = (size_t)(t * 16 + lg * 4 + reg) * 128;
            #pragma unroll
            for (int cb = 0; cb < 8; ++cb)
                h2[row + cb * 16 + lc] = fmaf((acc[cb][reg] - mu) * rstd, gm[cb], bt[cb]);
        }
    }
}

// ---------------- Mean pooling over sorted batch ----------------

__device__ __forceinline__ int lowerb(const int* __restrict__ b, int n, int key) {
    int lo = 0, hi = n;
    while (lo < hi) {
        int m = (lo + hi) >> 1;
        if (b[m] < key) lo = m + 1; else hi = m;
    }
    return lo;
}

__global__ void k_pool(const float* __restrict__ h2, const int* __restrict__ batch,
                       int n, float* __restrict__ out) {
    int g = blockIdx.x;
    int start = lowerb(batch, n, g);
    int end   = lowerb(batch, n, g + 1);
    int f = threadIdx.x & 127, half = threadIdx.x >> 7;
    float acc = 0.f;
    for (int r = start + half; r < end; r += 8)
        acc += h2[(size_t)r * 128 + f];
    __shared__ float part[1024];
    part[threadIdx.x] = acc;
    __syncthreads();
    if (threadIdx.x < 128) {
        float v = 0.f;
        #pragma unroll
        for (int j = 0; j < 8; ++j) v += part[f + 128 * j];
        int c = end - start;
        out[g * 128 + f] = v / fmaxf((float)c, 1.f);
    }
}

// ---------------- launch ----------------

extern "C" void kernel_launch(void* const* d_in, const int* in_sizes, int n_in,
                              void* d_out, int out_size, void* d_ws, size_t ws_size,
                              hipStream_t stream) {
    const float* x   = (const float*)d_in[0];
    const int*   ei  = (const int*)d_in[1];
    const int*   bat = (const int*)d_in[2];
    const float* W1  = (const float*)d_in[3];
    const float* b1  = (const float*)d_in[4];
    const float* g1  = (const float*)d_in[5];
    const float* be1 = (const float*)d_in[6];
    const float* W2  = (const float*)d_in[7];
    const float* b2  = (const float*)d_in[8];
    const float* g2  = (const float*)d_in[9];
    const float* be2 = (const float*)d_in[10];

    int n = in_sizes[0] / 64;     // 100000
    int e = in_sizes[1] / 2;      // 1600000
    int G = out_size / 128;       // 128
    const int* src = ei;
    const int* dst = ei + e;

    char* ws = (char*)d_ws;
    size_t off = 0;
    auto take = [&](size_t bytes) -> void* {
        void* p = ws + off;
        off = (off + bytes + 255) & ~(size_t)255;
        return p;
    };
    int*      cnt     = (int*)     take((size_t)n * 4);
    int*      pos     = (int*)     take((size_t)n * 4);
    float*    dinv    = (float*)   take((size_t)n * 4);
    int*      row_ptr = (int*)     take((size_t)(n + 1) * 4);
    int*      bsum    = (int*)     take(1024 * 4);
    int*      csr_src = (int*)     take((size_t)e * 4);
    float*    csr_w   = (float*)   take((size_t)e * 4);
    unsigned* xb      = (unsigned*)take((size_t)n * 64 * 2);   // bf16 x
    unsigned* aggb    = (unsigned*)take((size_t)n * 64 * 2);   // bf16 agg1
    unsigned* hb      = (unsigned*)take((size_t)n * 128 * 2);  // bf16 h
    unsigned* agg2b   = (unsigned*)take((size_t)n * 128 * 2);  // bf16 agg2
    float*    h2      = (float*)   take((size_t)n * 128 * 4);  // fp32 final features

    hipMemsetAsync(cnt, 0, (size_t)n * 4, stream);
    hipMemsetAsync(pos, 0, (size_t)n * 4, stream);

    k_hist<<<(e + 255) / 256, 256, 0, stream>>>(dst, e, cnt);
    k_dinv<<<(n + 255) / 256, 256, 0, stream>>>(cnt, n, dinv);
    int nb = (n + 1023) / 1024;
    k_scan1<<<nb, 1024, 0, stream>>>(cnt, n, row_ptr, bsum);
    k_scan2<<<1, 1024, 0, stream>>>(bsum, nb);
    k_scan3<<<(n + 255) / 256, 256, 0, stream>>>(row_ptr, bsum, n, e);
    k_scatter<<<(e + 255) / 256, 256, 0, stream>>>(src, dst, e, dinv, row_ptr, pos,
                                                   csr_src, csr_w);

    int nux = n * 32;  // uint count of x bf16
    k_f2b<<<(nux + 255) / 256, 256, 0, stream>>>(x, xb, nux);

    k_agg64b<<<2048, 256, 0, stream>>>(xb, dinv, row_ptr, csr_src, csr_w, aggb, n);

    int ntiles = n / 16;  // 6250, exact
    int mmblocks = (ntiles + 3) / 4;
    k_mm1<<<mmblocks, 256, 0, stream>>>(aggb, W1, b1, g1, be1, (unsigned short*)hb, ntiles);

    k_agg128b<<<2048, 256, 0, stream>>>(hb, dinv, row_ptr, csr_src, csr_w, agg2b, n);

    k_mm2<<<mmblocks, 256, 0, stream>>>(agg2b, W2, b2, g2, be2, h2, ntiles);

    k_pool<<<G, 1024, 0, stream>>>(h2, bat, n, (float*)d_out);
}

// Round 3
// 379.659 us; speedup vs baseline: 3.0019x; 1.1748x over previous
//
#include <hip/hip_runtime.h>

#define LN_EPS 1e-5f

typedef __attribute__((ext_vector_type(8))) short short8v;
typedef __attribute__((ext_vector_type(4))) float float4v;

__device__ __forceinline__ float bflo(unsigned u) { return __uint_as_float(u << 16); }
__device__ __forceinline__ float bfhi(unsigned u) { return __uint_as_float(u & 0xffff0000u); }
__device__ __forceinline__ unsigned short f2bf(float f) {
    unsigned b = __float_as_uint(f);
    unsigned r = b + 0x7fffu + ((b >> 16) & 1u);
    return (unsigned short)(r >> 16);
}
__device__ __forceinline__ unsigned pack2(float x, float y) {
    return (unsigned)f2bf(x) | ((unsigned)f2bf(y) << 16);
}

union U4S8 { uint4 u; short8v s; };

// ---------------- CSR build ----------------

__global__ void k_hist(const int* __restrict__ dst, int e, int* __restrict__ cnt) {
    int i = blockIdx.x * blockDim.x + threadIdx.x;
    if (i < e) atomicAdd(&cnt[dst[i]], 1);
}

__global__ void k_dinv(const int* __restrict__ cnt, int n, float* __restrict__ dinv) {
    int i = blockIdx.x * blockDim.x + threadIdx.x;
    if (i < n) dinv[i] = rsqrtf((float)(cnt[i] + 1));
}

__global__ void k_scan1(const int* __restrict__ cnt, int n,
                        int* __restrict__ row_ptr, int* __restrict__ bsum) {
    __shared__ int s[1024];
    int tid = threadIdx.x;
    int i = blockIdx.x * 1024 + tid;
    int v = (i < n) ? cnt[i] : 0;
    s[tid] = v; __syncthreads();
    for (int o = 1; o < 1024; o <<= 1) {
        int t = (tid >= o) ? s[tid - o] : 0;
        __syncthreads();
        s[tid] += t;
        __syncthreads();
    }
    if (i < n) row_ptr[i] = s[tid] - v;
    if (tid == 1023) bsum[blockIdx.x] = s[tid];
}

__global__ void k_scan2(int* __restrict__ bsum, int nb) {
    __shared__ int s[1024];
    int tid = threadIdx.x;
    int v = (tid < nb) ? bsum[tid] : 0;
    s[tid] = v; __syncthreads();
    for (int o = 1; o < 1024; o <<= 1) {
        int t = (tid >= o) ? s[tid - o] : 0;
        __syncthreads();
        s[tid] += t;
        __syncthreads();
    }
    if (tid < nb) bsum[tid] = s[tid] - v;
}

__global__ void k_scan3(int* __restrict__ row_ptr, const int* __restrict__ bsum,
                        int n, int e) {
    int i = blockIdx.x * blockDim.x + threadIdx.x;
    if (i < n) row_ptr[i] += bsum[i >> 10];
    if (i == 0) row_ptr[n] = e;
}

// single 8B write per edge: (src, weight)
__global__ void k_scatter(const int* __restrict__ src, const int* __restrict__ dst, int e,
                          const float* __restrict__ dinv, const int* __restrict__ row_ptr,
                          int* __restrict__ pos, uint2* __restrict__ csr) {
    int i = blockIdx.x * blockDim.x + threadIdx.x;
    if (i < e) {
        int d = dst[i], s = src[i];
        int p = row_ptr[d] + atomicAdd(&pos[d], 1);
        float w = dinv[s] * dinv[d];
        csr[p] = make_uint2((unsigned)s, __float_as_uint(w));
    }
}

// ---------------- fp32 -> bf16x2 pack ----------------

__global__ void k_f2b(const float* __restrict__ in, unsigned* __restrict__ out, int nu) {
    int i = blockIdx.x * blockDim.x + threadIdx.x;
    if (i < nu) {
        float2 v = ((const float2*)in)[i];
        out[i] = pack2(v.x, v.y);
    }
}

// ---------------- Aggregation (bf16 gathers, fp32 accumulate) ----------------

// x: [N][64] bf16 = uint2[N][16]. 4 edges in flight (quarters), uint2 per lane.
__global__ void k_agg64b(const unsigned* __restrict__ xb, const float* __restrict__ dinv,
                         const int* __restrict__ row_ptr, const uint2* __restrict__ csr,
                         unsigned* __restrict__ outb, int n) {
    int lane = threadIdx.x & 63;
    int q = lane >> 4;       // quarter 0..3
    int c = lane & 15;
    const uint2* xb2 = (const uint2*)xb;
    uint2* out2 = (uint2*)outb;
    int wid = (blockIdx.x * blockDim.x + threadIdx.x) >> 6;
    int nw = (gridDim.x * blockDim.x) >> 6;
    for (int i = wid; i < n; i += nw) {
        float a0 = 0.f, a1 = 0.f, a2 = 0.f, a3 = 0.f;
        if (q == 0) {
            float di = dinv[i];
            float dd = di * di;
            uint2 su = xb2[(size_t)i * 16 + c];
            a0 = bflo(su.x) * dd; a1 = bfhi(su.x) * dd;
            a2 = bflo(su.y) * dd; a3 = bfhi(su.y) * dd;
        }
        int j0 = row_ptr[i], j1 = row_ptr[i + 1];
        int j = j0 + q;
        if (j < j1) {
            uint2 ew = csr[j];
            for (; j < j1; j += 4) {
                int jn = j + 4;
                uint2 ewn = csr[jn < j1 ? jn : j0];
                int s = (int)ew.x;
                float w = __uint_as_float(ew.y);
                uint2 u = xb2[(size_t)s * 16 + c];
                a0 = fmaf(bflo(u.x), w, a0);
                a1 = fmaf(bfhi(u.x), w, a1);
                a2 = fmaf(bflo(u.y), w, a2);
                a3 = fmaf(bfhi(u.y), w, a3);
                ew = ewn;
            }
        }
        a0 += __shfl_xor(a0, 16); a0 += __shfl_xor(a0, 32);
        a1 += __shfl_xor(a1, 16); a1 += __shfl_xor(a1, 32);
        a2 += __shfl_xor(a2, 16); a2 += __shfl_xor(a2, 32);
        a3 += __shfl_xor(a3, 16); a3 += __shfl_xor(a3, 32);
        if (q == 0) out2[(size_t)i * 16 + c] = make_uint2(pack2(a0, a1), pack2(a2, a3));
    }
}

// h: [N][128] bf16 = uint2[N][32]. 2 edges in flight (halves), uint2 per lane.
__global__ void k_agg128b(const unsigned* __restrict__ hb, const float* __restrict__ dinv,
                          const int* __restrict__ row_ptr, const uint2* __restrict__ csr,
                          unsigned* __restrict__ outb, int n) {
    int lane = threadIdx.x & 63;
    int hf = lane >> 5;
    int c = lane & 31;
    const uint2* hb2 = (const uint2*)hb;
    uint2* out2 = (uint2*)outb;
    int wid = (blockIdx.x * blockDim.x + threadIdx.x) >> 6;
    int nw = (gridDim.x * blockDim.x) >> 6;
    for (int i = wid; i < n; i += nw) {
        float a0 = 0.f, a1 = 0.f, a2 = 0.f, a3 = 0.f;
        if (hf == 0) {
            float di = dinv[i];
            float dd = di * di;
            uint2 su = hb2[(size_t)i * 32 + c];
            a0 = bflo(su.x) * dd; a1 = bfhi(su.x) * dd;
            a2 = bflo(su.y) * dd; a3 = bfhi(su.y) * dd;
        }
        int j0 = row_ptr[i], j1 = row_ptr[i + 1];
        int j = j0 + hf;
        if (j < j1) {
            uint2 ew = csr[j];
            for (; j < j1; j += 2) {
                int jn = j + 2;
                uint2 ewn = csr[jn < j1 ? jn : j0];
                int s = (int)ew.x;
                float w = __uint_as_float(ew.y);
                uint2 u = hb2[(size_t)s * 32 + c];
                a0 = fmaf(bflo(u.x), w, a0);
                a1 = fmaf(bfhi(u.x), w, a1);
                a2 = fmaf(bflo(u.y), w, a2);
                a3 = fmaf(bfhi(u.y), w, a3);
                ew = ewn;
            }
        }
        a0 += __shfl_xor(a0, 32);
        a1 += __shfl_xor(a1, 32);
        a2 += __shfl_xor(a2, 32);
        a3 += __shfl_xor(a3, 32);
        if (hf == 0) out2[(size_t)i * 32 + c] = make_uint2(pack2(a0, a1), pack2(a2, a3));
    }
}

// ---------------- MFMA GEMM + LN (+ReLU) fused ----------------
// mfma_f32_16x16x32_bf16. A/B frag: k = (lane>>4)*8 + j. C/D: col=lane&15, row=(lane>>4)*4+reg.

// agg[N][64] bf16 @ W1[64][128] -> LN -> relu -> hb[N][128] bf16
__launch_bounds__(256)
__global__ void k_mm1(const unsigned* __restrict__ aggb, const float* __restrict__ W1,
                      const float* __restrict__ b1, const float* __restrict__ g1,
                      const float* __restrict__ be1, unsigned short* __restrict__ hbs,
                      int ntiles) {
    int lane = threadIdx.x & 63;
    int wv = threadIdx.x >> 6;
    int wpb = blockDim.x >> 6;
    int lc = lane & 15, lg = lane >> 4;

    short8v B[2][8];
    #pragma unroll
    for (int ks = 0; ks < 2; ++ks)
        #pragma unroll
        for (int cb = 0; cb < 8; ++cb) {
            short8v f;
            #pragma unroll
            for (int j = 0; j < 8; ++j) {
                int k = ks * 32 + lg * 8 + j;
                f[j] = (short)f2bf(W1[k * 128 + cb * 16 + lc]);
            }
            B[ks][cb] = f;
        }
    float bs[8], gm[8], bt[8];
    #pragma unroll
    for (int cb = 0; cb < 8; ++cb) {
        bs[cb] = b1[cb * 16 + lc];
        gm[cb] = g1[cb * 16 + lc];
        bt[cb] = be1[cb * 16 + lc];
    }

    for (int t = blockIdx.x * wpb + wv; t < ntiles; t += gridDim.x * wpb) {
        size_t arow = (size_t)(t * 16 + lc) * 32;
        U4S8 a0, a1;
        a0.u = *(const uint4*)&aggb[arow + lg * 4];
        a1.u = *(const uint4*)&aggb[arow + 16 + lg * 4];
        float4v acc[8];
        #pragma unroll
        for (int cb = 0; cb < 8; ++cb) acc[cb] = (float4v){0.f, 0.f, 0.f, 0.f};
        #pragma unroll
        for (int cb = 0; cb < 8; ++cb) {
            acc[cb] = __builtin_amdgcn_mfma_f32_16x16x32_bf16(a0.s, B[0][cb], acc[cb], 0, 0, 0);
            acc[cb] = __builtin_amdgcn_mfma_f32_16x16x32_bf16(a1.s, B[1][cb], acc[cb], 0, 0, 0);
        }
        #pragma unroll
        for (int reg = 0; reg < 4; ++reg) {
            float s = 0.f;
            #pragma unroll
            for (int cb = 0; cb < 8; ++cb) { acc[cb][reg] += bs[cb]; s += acc[cb][reg]; }
            s += __shfl_xor(s, 1); s += __shfl_xor(s, 2);
            s += __shfl_xor(s, 4); s += __shfl_xor(s, 8);
            float mu = s * (1.f / 128.f);
            float q = 0.f;
            #pragma unroll
            for (int cb = 0; cb < 8; ++cb) { float e = acc[cb][reg] - mu; q += e * e; }
            q += __shfl_xor(q, 1); q += __shfl_xor(q, 2);
            q += __shfl_xor(q, 4); q += __shfl_xor(q, 8);
            float rstd = rsqrtf(q * (1.f / 128.f) + LN_EPS);
            size_t row = (size_t)(t * 16 + lg * 4 + reg) * 128;
            #pragma unroll
            for (int cb = 0; cb < 8; ++cb) {
                float o = fmaf((acc[cb][reg] - mu) * rstd, gm[cb], bt[cb]);
                hbs[row + cb * 16 + lc] = f2bf(fmaxf(o, 0.f));
            }
        }
    }
}

// agg2[N][128] bf16 @ W2[128][128] -> LN -> pooled atomicAdd into psum[G][128]
__launch_bounds__(256)
__global__ void k_mm2p(const unsigned* __restrict__ aggb, const float* __restrict__ W2,
                       const float* __restrict__ b2, const float* __restrict__ g2,
                       const float* __restrict__ be2, const int* __restrict__ batch,
                       float* __restrict__ psum, int ntiles) {
    __shared__ uint4 sB[4 * 8 * 64];   // 32 KiB
    for (int idx = threadIdx.x; idx < 2048; idx += blockDim.x) {
        int l = idx & 63;
        int f = idx >> 6;
        int ks = f >> 3, cb = f & 7;
        int kb = ks * 32 + (l >> 4) * 8;
        int col = cb * 16 + (l & 15);
        float p[8];
        #pragma unroll
        for (int j = 0; j < 8; ++j) p[j] = W2[(kb + j) * 128 + col];
        uint4 v;
        v.x = pack2(p[0], p[1]); v.y = pack2(p[2], p[3]);
        v.z = pack2(p[4], p[5]); v.w = pack2(p[6], p[7]);
        sB[idx] = v;
    }
    __syncthreads();

    int lane = threadIdx.x & 63;
    int wv = threadIdx.x >> 6;
    int wpb = blockDim.x >> 6;
    int lc = lane & 15, lg = lane >> 4;
    float bs[8], gm[8], bt[8];
    #pragma unroll
    for (int cb = 0; cb < 8; ++cb) {
        bs[cb] = b2[cb * 16 + lc];
        gm[cb] = g2[cb * 16 + lc];
        bt[cb] = be2[cb * 16 + lc];
    }

    for (int t = blockIdx.x * wpb + wv; t < ntiles; t += gridDim.x * wpb) {
        int row0 = t * 16;
        size_t arow = (size_t)(row0 + lc) * 64;
        U4S8 a[4];
        #pragma unroll
        for (int ks = 0; ks < 4; ++ks)
            a[ks].u = *(const uint4*)&aggb[arow + ks * 16 + lg * 4];
        float4v acc[8];
        #pragma unroll
        for (int cb = 0; cb < 8; ++cb) acc[cb] = (float4v){0.f, 0.f, 0.f, 0.f};
        #pragma unroll
        for (int ks = 0; ks < 4; ++ks) {
            #pragma unroll
            for (int cb = 0; cb < 8; ++cb) {
                U4S8 fb;
                fb.u = sB[(ks * 8 + cb) * 64 + lane];
                acc[cb] = __builtin_amdgcn_mfma_f32_16x16x32_bf16(a[ks].s, fb.s, acc[cb], 0, 0, 0);
            }
        }
        // LN in place
        #pragma unroll
        for (int reg = 0; reg < 4; ++reg) {
            float s = 0.f;
            #pragma unroll
            for (int cb = 0; cb < 8; ++cb) { acc[cb][reg] += bs[cb]; s += acc[cb][reg]; }
            s += __shfl_xor(s, 1); s += __shfl_xor(s, 2);
            s += __shfl_xor(s, 4); s += __shfl_xor(s, 8);
            float mu = s * (1.f / 128.f);
            float q = 0.f;
            #pragma unroll
            for (int cb = 0; cb < 8; ++cb) { float e = acc[cb][reg] - mu; q += e * e; }
            q += __shfl_xor(q, 1); q += __shfl_xor(q, 2);
            q += __shfl_xor(q, 4); q += __shfl_xor(q, 8);
            float rstd = rsqrtf(q * (1.f / 128.f) + LN_EPS);
            #pragma unroll
            for (int cb = 0; cb < 8; ++cb)
                acc[cb][reg] = fmaf((acc[cb][reg] - mu) * rstd, gm[cb], bt[cb]);
        }
        // pooled accumulate (batch sorted -> tile spans gmin..gmax)
        int gmin = batch[row0];
        int gmax = batch[row0 + 15];
        int rg[4];
        #pragma unroll
        for (int reg = 0; reg < 4; ++reg) rg[reg] = batch[row0 + lg * 4 + reg];
        for (int g = gmin; g <= gmax; ++g) {
            #pragma unroll
            for (int cb = 0; cb < 8; ++cb) {
                float s = 0.f;
                #pragma unroll
                for (int reg = 0; reg < 4; ++reg)
                    s += (rg[reg] == g) ? acc[cb][reg] : 0.f;
                s += __shfl_xor(s, 16);
                s += __shfl_xor(s, 32);
                if (lg == 0) atomicAdd(&psum[g * 128 + cb * 16 + lc], s);
            }
        }
    }
}

// ---------------- divide by graph sizes ----------------

__device__ __forceinline__ int lowerb(const int* __restrict__ b, int n, int key) {
    int lo = 0, hi = n;
    while (lo < hi) {
        int m = (lo + hi) >> 1;
        if (b[m] < key) lo = m + 1; else hi = m;
    }
    return lo;
}

__global__ void k_div(float* __restrict__ out, const int* __restrict__ batch,
                      int n, int total) {
    int idx = blockIdx.x * blockDim.x + threadIdx.x;
    if (idx < total) {
        int g = idx >> 7;
        int start = lowerb(batch, n, g);
        int end   = lowerb(batch, n, g + 1);
        out[idx] /= fmaxf((float)(end - start), 1.f);
    }
}

// ---------------- launch ----------------

extern "C" void kernel_launch(void* const* d_in, const int* in_sizes, int n_in,
                              void* d_out, int out_size, void* d_ws, size_t ws_size,
                              hipStream_t stream) {
    const float* x   = (const float*)d_in[0];
    const int*   ei  = (const int*)d_in[1];
    const int*   bat = (const int*)d_in[2];
    const float* W1  = (const float*)d_in[3];
    const float* b1  = (const float*)d_in[4];
    const float* g1  = (const float*)d_in[5];
    const float* be1 = (const float*)d_in[6];
    const float* W2  = (const float*)d_in[7];
    const float* b2  = (const float*)d_in[8];
    const float* g2  = (const float*)d_in[9];
    const float* be2 = (const float*)d_in[10];

    int n = in_sizes[0] / 64;     // 100000
    int e = in_sizes[1] / 2;      // 1600000
    const int* src = ei;
    const int* dst = ei + e;

    char* ws = (char*)d_ws;
    size_t off = 0;
    auto take = [&](size_t bytes) -> void* {
        void* p = ws + off;
        off = (off + bytes + 255) & ~(size_t)255;
        return p;
    };
    int*      cnt     = (int*)     take((size_t)n * 4);
    int*      pos     = (int*)     take((size_t)n * 4);
    float*    dinv    = (float*)   take((size_t)n * 4);
    int*      row_ptr = (int*)     take((size_t)(n + 1) * 4);
    int*      bsum    = (int*)     take(1024 * 4);
    uint2*    csr     = (uint2*)   take((size_t)e * 8);
    unsigned* xb      = (unsigned*)take((size_t)n * 64 * 2);
    unsigned* aggb    = (unsigned*)take((size_t)n * 64 * 2);
    unsigned* hb      = (unsigned*)take((size_t)n * 128 * 2);
    unsigned* agg2b   = (unsigned*)take((size_t)n * 128 * 2);

    hipMemsetAsync(cnt, 0, (size_t)n * 4, stream);
    hipMemsetAsync(pos, 0, (size_t)n * 4, stream);
    hipMemsetAsync(d_out, 0, (size_t)out_size * 4, stream);

    k_hist<<<(e + 255) / 256, 256, 0, stream>>>(dst, e, cnt);
    k_dinv<<<(n + 255) / 256, 256, 0, stream>>>(cnt, n, dinv);
    int nb = (n + 1023) / 1024;
    k_scan1<<<nb, 1024, 0, stream>>>(cnt, n, row_ptr, bsum);
    k_scan2<<<1, 1024, 0, stream>>>(bsum, nb);
    k_scan3<<<(n + 255) / 256, 256, 0, stream>>>(row_ptr, bsum, n, e);
    k_scatter<<<(e + 255) / 256, 256, 0, stream>>>(src, dst, e, dinv, row_ptr, pos, csr);

    int nux = n * 32;
    k_f2b<<<(nux + 255) / 256, 256, 0, stream>>>(x, xb, nux);

    k_agg64b<<<2048, 256, 0, stream>>>(xb, dinv, row_ptr, csr, aggb, n);

    int ntiles = n / 16;  // 6250
    int mmblocks = (ntiles + 3) / 4;
    k_mm1<<<mmblocks, 256, 0, stream>>>(aggb, W1, b1, g1, be1, (unsigned short*)hb, ntiles);

    k_agg128b<<<2048, 256, 0, stream>>>(hb, dinv, row_ptr, csr, agg2b, n);

    k_mm2p<<<mmblocks, 256, 0, stream>>>(agg2b, W2, b2, g2, be2, bat, (float*)d_out, ntiles);

    int total = out_size;
    k_div<<<(total + 255) / 256, 256, 0, stream>>>((float*)d_out, bat, n, total);
}

// Round 4
// 365.288 us; speedup vs baseline: 3.1200x; 1.0393x over previous
//
#include <hip/hip_runtime.h>

#define LN_EPS 1e-5f

typedef __attribute__((ext_vector_type(8))) short short8v;
typedef __attribute__((ext_vector_type(4))) float float4v;

__device__ __forceinline__ float bflo(unsigned u) { return __uint_as_float(u << 16); }
__device__ __forceinline__ float bfhi(unsigned u) { return __uint_as_float(u & 0xffff0000u); }
__device__ __forceinline__ unsigned short f2bf(float f) {
    unsigned b = __float_as_uint(f);
    unsigned r = b + 0x7fffu + ((b >> 16) & 1u);
    return (unsigned short)(r >> 16);
}
__device__ __forceinline__ unsigned pack2(float x, float y) {
    return (unsigned)f2bf(x) | ((unsigned)f2bf(y) << 16);
}
__device__ __forceinline__ void add8(float* a, uint4 u) {
    a[0] += bflo(u.x); a[1] += bfhi(u.x);
    a[2] += bflo(u.y); a[3] += bfhi(u.y);
    a[4] += bflo(u.z); a[5] += bfhi(u.z);
    a[6] += bflo(u.w); a[7] += bfhi(u.w);
}

union U4S8 { uint4 u; short8v s; };

// ---------------- CSR build ----------------

__global__ void k_hist(const int* __restrict__ dst, int e, int* __restrict__ cnt) {
    int i = blockIdx.x * blockDim.x + threadIdx.x;
    if (i < e) atomicAdd(&cnt[dst[i]], 1);
}

__global__ void k_dinv(const int* __restrict__ cnt, int n, float* __restrict__ dinv) {
    int i = blockIdx.x * blockDim.x + threadIdx.x;
    if (i < n) dinv[i] = rsqrtf((float)(cnt[i] + 1));
}

__global__ void k_scan1(const int* __restrict__ cnt, int n,
                        int* __restrict__ row_ptr, int* __restrict__ bsum) {
    __shared__ int s[1024];
    int tid = threadIdx.x;
    int i = blockIdx.x * 1024 + tid;
    int v = (i < n) ? cnt[i] : 0;
    s[tid] = v; __syncthreads();
    for (int o = 1; o < 1024; o <<= 1) {
        int t = (tid >= o) ? s[tid - o] : 0;
        __syncthreads();
        s[tid] += t;
        __syncthreads();
    }
    if (i < n) row_ptr[i] = s[tid] - v;
    if (tid == 1023) bsum[blockIdx.x] = s[tid];
}

__global__ void k_scan2(int* __restrict__ bsum, int nb) {
    __shared__ int s[1024];
    int tid = threadIdx.x;
    int v = (tid < nb) ? bsum[tid] : 0;
    s[tid] = v; __syncthreads();
    for (int o = 1; o < 1024; o <<= 1) {
        int t = (tid >= o) ? s[tid - o] : 0;
        __syncthreads();
        s[tid] += t;
        __syncthreads();
    }
    if (tid < nb) bsum[tid] = s[tid] - v;
}

__global__ void k_scan3(int* __restrict__ row_ptr, const int* __restrict__ bsum,
                        int n, int e) {
    int i = blockIdx.x * blockDim.x + threadIdx.x;
    if (i < n) row_ptr[i] += bsum[i >> 10];
    if (i == 0) row_ptr[n] = e;
}

// weights eliminated: only src index stored (4B/edge)
__global__ void k_scatter(const int* __restrict__ src, const int* __restrict__ dst, int e,
                          const int* __restrict__ row_ptr, int* __restrict__ pos,
                          int* __restrict__ csr_src) {
    int i = blockIdx.x * blockDim.x + threadIdx.x;
    if (i < e) {
        int d = dst[i];
        int p = row_ptr[d] + atomicAdd(&pos[d], 1);
        csr_src[p] = src[i];
    }
}

// ---------------- fp32 -> bf16x2 pack, pre-scaled by dinv[row] ----------------

__global__ void k_f2bs(const float* __restrict__ in, const float* __restrict__ dinv,
                       unsigned* __restrict__ out, int nu) {
    int i = blockIdx.x * blockDim.x + threadIdx.x;
    if (i < nu) {
        float2 v = ((const float2*)in)[i];
        float d = dinv[i >> 5];          // 32 uints per 64-feature row
        out[i] = pack2(v.x * d, v.y * d);
    }
}

// ---------------- Aggregation: out[d] = dinv[d] * (x'[d] + sum x'[s]) ----------------

// x': [N][64] bf16 = uint4[N][8]. 8 lanes/edge, 8 edges in flight, unroll 2.
__global__ void k_agg64b(const uint4* __restrict__ x4, const float* __restrict__ dinv,
                         const int* __restrict__ row_ptr, const int* __restrict__ csr_src,
                         uint4* __restrict__ out4, int n) {
    int lane = threadIdx.x & 63;
    int g = lane >> 3, c = lane & 7;
    int wid = (blockIdx.x * blockDim.x + threadIdx.x) >> 6;
    int nw = (gridDim.x * blockDim.x) >> 6;
    for (int i = wid; i < n; i += nw) {
        float a[8] = {0.f, 0.f, 0.f, 0.f, 0.f, 0.f, 0.f, 0.f};
        if (g == 0) {
            uint4 su = x4[(size_t)i * 8 + c];
            add8(a, su);
        }
        int j0 = row_ptr[i], j1 = row_ptr[i + 1];
        int j = j0 + g;
        for (; j + 8 < j1; j += 16) {
            int s0 = csr_src[j], s1 = csr_src[j + 8];
            uint4 u0 = x4[(size_t)s0 * 8 + c];
            uint4 u1 = x4[(size_t)s1 * 8 + c];
            add8(a, u0);
            add8(a, u1);
        }
        if (j < j1) {
            int s0 = csr_src[j];
            uint4 u0 = x4[(size_t)s0 * 8 + c];
            add8(a, u0);
        }
        #pragma unroll
        for (int k = 0; k < 8; ++k) {
            a[k] += __shfl_xor(a[k], 8);
            a[k] += __shfl_xor(a[k], 16);
            a[k] += __shfl_xor(a[k], 32);
        }
        if (g == 0) {
            float di = dinv[i];
            uint4 o;
            o.x = pack2(a[0] * di, a[1] * di);
            o.y = pack2(a[2] * di, a[3] * di);
            o.z = pack2(a[4] * di, a[5] * di);
            o.w = pack2(a[6] * di, a[7] * di);
            out4[(size_t)i * 8 + c] = o;
        }
    }
}

// h': [N][128] bf16 = uint4[N][16]. 16 lanes/edge, 4 edges in flight, unroll 2.
__global__ void k_agg128b(const uint4* __restrict__ h4, const float* __restrict__ dinv,
                          const int* __restrict__ row_ptr, const int* __restrict__ csr_src,
                          uint4* __restrict__ out4, int n) {
    int lane = threadIdx.x & 63;
    int q = lane >> 4, c = lane & 15;
    int wid = (blockIdx.x * blockDim.x + threadIdx.x) >> 6;
    int nw = (gridDim.x * blockDim.x) >> 6;
    for (int i = wid; i < n; i += nw) {
        float a[8] = {0.f, 0.f, 0.f, 0.f, 0.f, 0.f, 0.f, 0.f};
        if (q == 0) {
            uint4 su = h4[(size_t)i * 16 + c];
            add8(a, su);
        }
        int j0 = row_ptr[i], j1 = row_ptr[i + 1];
        int j = j0 + q;
        for (; j + 4 < j1; j += 8) {
            int s0 = csr_src[j], s1 = csr_src[j + 4];
            uint4 u0 = h4[(size_t)s0 * 16 + c];
            uint4 u1 = h4[(size_t)s1 * 16 + c];
            add8(a, u0);
            add8(a, u1);
        }
        if (j < j1) {
            int s0 = csr_src[j];
            uint4 u0 = h4[(size_t)s0 * 16 + c];
            add8(a, u0);
        }
        #pragma unroll
        for (int k = 0; k < 8; ++k) {
            a[k] += __shfl_xor(a[k], 16);
            a[k] += __shfl_xor(a[k], 32);
        }
        if (q == 0) {
            float di = dinv[i];
            uint4 o;
            o.x = pack2(a[0] * di, a[1] * di);
            o.y = pack2(a[2] * di, a[3] * di);
            o.z = pack2(a[4] * di, a[5] * di);
            o.w = pack2(a[6] * di, a[7] * di);
            out4[(size_t)i * 16 + c] = o;
        }
    }
}

// ---------------- MFMA GEMM + LN (+ReLU) fused ----------------
// mfma_f32_16x16x32_bf16. A/B frag: k = (lane>>4)*8 + j. C/D: col=lane&15, row=(lane>>4)*4+reg.

// agg[N][64] bf16 @ W1[64][128] -> LN -> relu -> *dinv[row] -> hb[N][128] bf16
__launch_bounds__(256)
__global__ void k_mm1(const unsigned* __restrict__ aggb, const float* __restrict__ W1,
                      const float* __restrict__ b1, const float* __restrict__ g1,
                      const float* __restrict__ be1, const float* __restrict__ dinv,
                      unsigned short* __restrict__ hbs, int ntiles) {
    int lane = threadIdx.x & 63;
    int wv = threadIdx.x >> 6;
    int wpb = blockDim.x >> 6;
    int lc = lane & 15, lg = lane >> 4;

    short8v B[2][8];
    #pragma unroll
    for (int ks = 0; ks < 2; ++ks)
        #pragma unroll
        for (int cb = 0; cb < 8; ++cb) {
            short8v f;
            #pragma unroll
            for (int j = 0; j < 8; ++j) {
                int k = ks * 32 + lg * 8 + j;
                f[j] = (short)f2bf(W1[k * 128 + cb * 16 + lc]);
            }
            B[ks][cb] = f;
        }
    float bs[8], gm[8], bt[8];
    #pragma unroll
    for (int cb = 0; cb < 8; ++cb) {
        bs[cb] = b1[cb * 16 + lc];
        gm[cb] = g1[cb * 16 + lc];
        bt[cb] = be1[cb * 16 + lc];
    }

    for (int t = blockIdx.x * wpb + wv; t < ntiles; t += gridDim.x * wpb) {
        size_t arow = (size_t)(t * 16 + lc) * 32;
        U4S8 a0, a1;
        a0.u = *(const uint4*)&aggb[arow + lg * 4];
        a1.u = *(const uint4*)&aggb[arow + 16 + lg * 4];
        float4v acc[8];
        #pragma unroll
        for (int cb = 0; cb < 8; ++cb) acc[cb] = (float4v){0.f, 0.f, 0.f, 0.f};
        #pragma unroll
        for (int cb = 0; cb < 8; ++cb) {
            acc[cb] = __builtin_amdgcn_mfma_f32_16x16x32_bf16(a0.s, B[0][cb], acc[cb], 0, 0, 0);
            acc[cb] = __builtin_amdgcn_mfma_f32_16x16x32_bf16(a1.s, B[1][cb], acc[cb], 0, 0, 0);
        }
        #pragma unroll
        for (int reg = 0; reg < 4; ++reg) {
            float s = 0.f;
            #pragma unroll
            for (int cb = 0; cb < 8; ++cb) { acc[cb][reg] += bs[cb]; s += acc[cb][reg]; }
            s += __shfl_xor(s, 1); s += __shfl_xor(s, 2);
            s += __shfl_xor(s, 4); s += __shfl_xor(s, 8);
            float mu = s * (1.f / 128.f);
            float q = 0.f;
            #pragma unroll
            for (int cb = 0; cb < 8; ++cb) { float e = acc[cb][reg] - mu; q += e * e; }
            q += __shfl_xor(q, 1); q += __shfl_xor(q, 2);
            q += __shfl_xor(q, 4); q += __shfl_xor(q, 8);
            float rstd = rsqrtf(q * (1.f / 128.f) + LN_EPS);
            int rowi = t * 16 + lg * 4 + reg;
            float di = dinv[rowi];
            size_t row = (size_t)rowi * 128;
            #pragma unroll
            for (int cb = 0; cb < 8; ++cb) {
                float o = fmaf((acc[cb][reg] - mu) * rstd, gm[cb], bt[cb]);
                hbs[row + cb * 16 + lc] = f2bf(fmaxf(o, 0.f) * di);
            }
        }
    }
}

// agg2[N][128] bf16 @ W2[128][128] -> LN -> pooled atomicAdd into psum[G][128]
__launch_bounds__(256)
__global__ void k_mm2p(const unsigned* __restrict__ aggb, const float* __restrict__ W2,
                       const float* __restrict__ b2, const float* __restrict__ g2,
                       const float* __restrict__ be2, const int* __restrict__ batch,
                       float* __restrict__ psum, int ntiles) {
    __shared__ uint4 sB[4 * 8 * 64];   // 32 KiB
    for (int idx = threadIdx.x; idx < 2048; idx += blockDim.x) {
        int l = idx & 63;
        int f = idx >> 6;
        int ks = f >> 3, cb = f & 7;
        int kb = ks * 32 + (l >> 4) * 8;
        int col = cb * 16 + (l & 15);
        float p[8];
        #pragma unroll
        for (int j = 0; j < 8; ++j) p[j] = W2[(kb + j) * 128 + col];
        uint4 v;
        v.x = pack2(p[0], p[1]); v.y = pack2(p[2], p[3]);
        v.z = pack2(p[4], p[5]); v.w = pack2(p[6], p[7]);
        sB[idx] = v;
    }
    __syncthreads();

    int lane = threadIdx.x & 63;
    int wv = threadIdx.x >> 6;
    int wpb = blockDim.x >> 6;
    int lc = lane & 15, lg = lane >> 4;
    float bs[8], gm[8], bt[8];
    #pragma unroll
    for (int cb = 0; cb < 8; ++cb) {
        bs[cb] = b2[cb * 16 + lc];
        gm[cb] = g2[cb * 16 + lc];
        bt[cb] = be2[cb * 16 + lc];
    }

    for (int t = blockIdx.x * wpb + wv; t < ntiles; t += gridDim.x * wpb) {
        int row0 = t * 16;
        size_t arow = (size_t)(row0 + lc) * 64;
        U4S8 a[4];
        #pragma unroll
        for (int ks = 0; ks < 4; ++ks)
            a[ks].u = *(const uint4*)&aggb[arow + ks * 16 + lg * 4];
        float4v acc[8];
        #pragma unroll
        for (int cb = 0; cb < 8; ++cb) acc[cb] = (float4v){0.f, 0.f, 0.f, 0.f};
        #pragma unroll
        for (int ks = 0; ks < 4; ++ks) {
            #pragma unroll
            for (int cb = 0; cb < 8; ++cb) {
                U4S8 fb;
                fb.u = sB[(ks * 8 + cb) * 64 + lane];
                acc[cb] = __builtin_amdgcn_mfma_f32_16x16x32_bf16(a[ks].s, fb.s, acc[cb], 0, 0, 0);
            }
        }
        #pragma unroll
        for (int reg = 0; reg < 4; ++reg) {
            float s = 0.f;
            #pragma unroll
            for (int cb = 0; cb < 8; ++cb) { acc[cb][reg] += bs[cb]; s += acc[cb][reg]; }
            s += __shfl_xor(s, 1); s += __shfl_xor(s, 2);
            s += __shfl_xor(s, 4); s += __shfl_xor(s, 8);
            float mu = s * (1.f / 128.f);
            float q = 0.f;
            #pragma unroll
            for (int cb = 0; cb < 8; ++cb) { float e = acc[cb][reg] - mu; q += e * e; }
            q += __shfl_xor(q, 1); q += __shfl_xor(q, 2);
            q += __shfl_xor(q, 4); q += __shfl_xor(q, 8);
            float rstd = rsqrtf(q * (1.f / 128.f) + LN_EPS);
            #pragma unroll
            for (int cb = 0; cb < 8; ++cb)
                acc[cb][reg] = fmaf((acc[cb][reg] - mu) * rstd, gm[cb], bt[cb]);
        }
        int gmin = batch[row0];
        int gmax = batch[row0 + 15];
        int rg[4];
        #pragma unroll
        for (int reg = 0; reg < 4; ++reg) rg[reg] = batch[row0 + lg * 4 + reg];
        for (int g = gmin; g <= gmax; ++g) {
            #pragma unroll
            for (int cb = 0; cb < 8; ++cb) {
                float s = 0.f;
                #pragma unroll
                for (int reg = 0; reg < 4; ++reg)
                    s += (rg[reg] == g) ? acc[cb][reg] : 0.f;
                s += __shfl_xor(s, 16);
                s += __shfl_xor(s, 32);
                if (lg == 0) atomicAdd(&psum[g * 128 + cb * 16 + lc], s);
            }
        }
    }
}

// ---------------- divide by graph sizes ----------------

__device__ __forceinline__ int lowerb(const int* __restrict__ b, int n, int key) {
    int lo = 0, hi = n;
    while (lo < hi) {
        int m = (lo + hi) >> 1;
        if (b[m] < key) lo = m + 1; else hi = m;
    }
    return lo;
}

__global__ void k_div(float* __restrict__ out, const int* __restrict__ batch,
                      int n, int total) {
    int idx = blockIdx.x * blockDim.x + threadIdx.x;
    if (idx < total) {
        int g = idx >> 7;
        int start = lowerb(batch, n, g);
        int end   = lowerb(batch, n, g + 1);
        out[idx] /= fmaxf((float)(end - start), 1.f);
    }
}

// ---------------- launch ----------------

extern "C" void kernel_launch(void* const* d_in, const int* in_sizes, int n_in,
                              void* d_out, int out_size, void* d_ws, size_t ws_size,
                              hipStream_t stream) {
    const float* x   = (const float*)d_in[0];
    const int*   ei  = (const int*)d_in[1];
    const int*   bat = (const int*)d_in[2];
    const float* W1  = (const float*)d_in[3];
    const float* b1  = (const float*)d_in[4];
    const float* g1  = (const float*)d_in[5];
    const float* be1 = (const float*)d_in[6];
    const float* W2  = (const float*)d_in[7];
    const float* b2  = (const float*)d_in[8];
    const float* g2  = (const float*)d_in[9];
    const float* be2 = (const float*)d_in[10];

    int n = in_sizes[0] / 64;     // 100000
    int e = in_sizes[1] / 2;      // 1600000
    const int* src = ei;
    const int* dst = ei + e;

    char* ws = (char*)d_ws;
    size_t off = 0;
    auto take = [&](size_t bytes) -> void* {
        void* p = ws + off;
        off = (off + bytes + 255) & ~(size_t)255;
        return p;
    };
    int*      cnt     = (int*)     take((size_t)n * 4);
    int*      pos     = (int*)     take((size_t)n * 4);
    float*    dinv    = (float*)   take((size_t)n * 4);
    int*      row_ptr = (int*)     take((size_t)(n + 1) * 4);
    int*      bsum    = (int*)     take(1024 * 4);
    int*      csr_src = (int*)     take((size_t)e * 4);
    unsigned* xb      = (unsigned*)take((size_t)n * 64 * 2);
    unsigned* aggb    = (unsigned*)take((size_t)n * 64 * 2);
    unsigned* hb      = (unsigned*)take((size_t)n * 128 * 2);
    unsigned* agg2b   = (unsigned*)take((size_t)n * 128 * 2);

    hipMemsetAsync(cnt, 0, (size_t)n * 4, stream);
    hipMemsetAsync(pos, 0, (size_t)n * 4, stream);
    hipMemsetAsync(d_out, 0, (size_t)out_size * 4, stream);

    k_hist<<<(e + 255) / 256, 256, 0, stream>>>(dst, e, cnt);
    k_dinv<<<(n + 255) / 256, 256, 0, stream>>>(cnt, n, dinv);
    int nb = (n + 1023) / 1024;
    k_scan1<<<nb, 1024, 0, stream>>>(cnt, n, row_ptr, bsum);
    k_scan2<<<1, 1024, 0, stream>>>(bsum, nb);
    k_scan3<<<(n + 255) / 256, 256, 0, stream>>>(row_ptr, bsum, n, e);
    k_scatter<<<(e + 255) / 256, 256, 0, stream>>>(src, dst, e, row_ptr, pos, csr_src);

    int nux = n * 32;
    k_f2bs<<<(nux + 255) / 256, 256, 0, stream>>>(x, dinv, xb, nux);

    k_agg64b<<<2048, 256, 0, stream>>>((const uint4*)xb, dinv, row_ptr, csr_src,
                                       (uint4*)aggb, n);

    int ntiles = n / 16;  // 6250
    int mmblocks = (ntiles + 3) / 4;
    k_mm1<<<mmblocks, 256, 0, stream>>>(aggb, W1, b1, g1, be1, dinv,
                                        (unsigned short*)hb, ntiles);

    k_agg128b<<<2048, 256, 0, stream>>>((const uint4*)hb, dinv, row_ptr, csr_src,
                                        (uint4*)agg2b, n);

    k_mm2p<<<mmblocks, 256, 0, stream>>>(agg2b, W2, b2, g2, be2, bat, (float*)d_out, ntiles);

    int total = out_size;
    k_div<<<(total + 255) / 256, 256, 0, stream>>>((float*)d_out, bat, n, total);
}

// Round 5
// 294.508 us; speedup vs baseline: 3.8698x; 1.2403x over previous
//
#include <hip/hip_runtime.h>

#define LN_EPS 1e-5f

typedef __attribute__((ext_vector_type(8))) short short8v;
typedef __attribute__((ext_vector_type(4))) float float4v;

__device__ __forceinline__ float bflo(unsigned u) { return __uint_as_float(u << 16); }
__device__ __forceinline__ float bfhi(unsigned u) { return __uint_as_float(u & 0xffff0000u); }
__device__ __forceinline__ unsigned short f2bf(float f) {
    unsigned b = __float_as_uint(f);
    unsigned r = b + 0x7fffu + ((b >> 16) & 1u);
    return (unsigned short)(r >> 16);
}
__device__ __forceinline__ unsigned pack2(float x, float y) {
    return (unsigned)f2bf(x) | ((unsigned)f2bf(y) << 16);
}
__device__ __forceinline__ void add8(float* a, uint4 u) {
    a[0] += bflo(u.x); a[1] += bfhi(u.x);
    a[2] += bflo(u.y); a[3] += bfhi(u.y);
    a[4] += bflo(u.z); a[5] += bfhi(u.z);
    a[6] += bflo(u.w); a[7] += bfhi(u.w);
}

union U4S8 { uint4 u; short8v s; };

// ---------------- degree histogram + scan ----------------

__global__ void k_hist(const int* __restrict__ dst, int e, int* __restrict__ cnt) {
    int i = blockIdx.x * blockDim.x + threadIdx.x;
    if (i < e) atomicAdd(&cnt[dst[i]], 1);
}

__global__ void k_dinv(const int* __restrict__ cnt, int n, float* __restrict__ dinv) {
    int i = blockIdx.x * blockDim.x + threadIdx.x;
    if (i < n) dinv[i] = rsqrtf((float)(cnt[i] + 1));
}

__global__ void k_scan1(const int* __restrict__ cnt, int n,
                        int* __restrict__ row_ptr, int* __restrict__ bsum) {
    __shared__ int s[1024];
    int tid = threadIdx.x;
    int i = blockIdx.x * 1024 + tid;
    int v = (i < n) ? cnt[i] : 0;
    s[tid] = v; __syncthreads();
    for (int o = 1; o < 1024; o <<= 1) {
        int t = (tid >= o) ? s[tid - o] : 0;
        __syncthreads();
        s[tid] += t;
        __syncthreads();
    }
    if (i < n) row_ptr[i] = s[tid] - v;
    if (tid == 1023) bsum[blockIdx.x] = s[tid];
}

__global__ void k_scan2(int* __restrict__ bsum, int nb) {
    __shared__ int s[1024];
    int tid = threadIdx.x;
    int v = (tid < nb) ? bsum[tid] : 0;
    s[tid] = v; __syncthreads();
    for (int o = 1; o < 1024; o <<= 1) {
        int t = (tid >= o) ? s[tid - o] : 0;
        __syncthreads();
        s[tid] += t;
        __syncthreads();
    }
    if (tid < nb) bsum[tid] = s[tid] - v;
}

__global__ void k_scan3(int* __restrict__ row_ptr, const int* __restrict__ bsum,
                        int n, int e) {
    int i = blockIdx.x * blockDim.x + threadIdx.x;
    if (i < n) row_ptr[i] += bsum[i >> 10];
    if (i == 0) row_ptr[n] = e;
}

// ---------------- two-pass bucketed CSR build ----------------
// bucket b = dst >> 8 (256 nodes/bucket). Bucket b's staging region is
// stage[row_ptr[b*256] .. row_ptr[min(n,(b+1)*256)]) — same layout as CSR.

#define CHUNK 4096
#define NBMAX 512

// pass 1: block-local LDS histogram -> one global atomic per (block,bucket)
// -> append (src,dst) runs into bucket staging regions.
__launch_bounds__(256)
__global__ void k_bucket(const int* __restrict__ src, const int* __restrict__ dst, int e,
                         const int* __restrict__ row_ptr, int* __restrict__ gcnt,
                         uint2* __restrict__ stage) {
    __shared__ uint2 ebuf[CHUNK];
    __shared__ int hist[NBMAX];
    __shared__ int base[NBMAX];
    int tid = threadIdx.x;
    int c0 = blockIdx.x * CHUNK;
    if (c0 >= e) return;
    int cnt = min(CHUNK, e - c0);

    for (int t = tid; t < NBMAX; t += 256) hist[t] = 0;
    __syncthreads();
    for (int t = tid; t < cnt; t += 256) {
        uint2 ed = make_uint2((unsigned)src[c0 + t], (unsigned)dst[c0 + t]);
        ebuf[t] = ed;
        atomicAdd(&hist[ed.y >> 8], 1);
    }
    __syncthreads();
    for (int b = tid; b < NBMAX; b += 256) {
        int h = hist[b];
        if (h > 0) base[b] = row_ptr[b << 8] + atomicAdd(&gcnt[b], h);
    }
    __syncthreads();
    for (int t = tid; t < cnt; t += 256) {
        uint2 ed = ebuf[t];
        int p = atomicAdd(&base[ed.y >> 8], 1);
        stage[p] = ed;
    }
}

// pass 2: one block per bucket; LDS rank counters; CSR segment staged in LDS
// then written fully coalesced.
#define CSRCAP 8192
__launch_bounds__(256)
__global__ void k_csr(const uint2* __restrict__ stage, const int* __restrict__ row_ptr,
                      int* __restrict__ csr_src, int n) {
    __shared__ int srow[257];
    __shared__ int lpos[256];
    __shared__ int cbuf[CSRCAP];
    int b = blockIdx.x;
    int lo = b << 8;
    int hi = min(n, lo + 256);
    int nn = hi - lo;
    int tid = threadIdx.x;
    for (int t = tid; t <= nn; t += 256) srow[t] = row_ptr[lo + t];
    for (int t = tid; t < nn; t += 256) lpos[t] = 0;
    __syncthreads();
    int s0 = srow[0];
    int cntB = srow[nn] - s0;
    for (int t = tid; t < cntB; t += 256) {
        uint2 ed = stage[s0 + t];
        int dl = (int)ed.y - lo;
        int r = atomicAdd(&lpos[dl], 1);
        int p = srow[dl] - s0 + r;
        if (p < CSRCAP) cbuf[p] = (int)ed.x;
        else csr_src[s0 + p] = (int)ed.x;   // overflow fallback (shouldn't trigger)
    }
    __syncthreads();
    int lim = min(cntB, CSRCAP);
    for (int t = tid; t < lim; t += 256) csr_src[s0 + t] = cbuf[t];
}

// ---------------- fp32 -> bf16x2 pack, pre-scaled by dinv[row] ----------------

__global__ void k_f2bs(const float* __restrict__ in, const float* __restrict__ dinv,
                       unsigned* __restrict__ out, int nu) {
    int i = blockIdx.x * blockDim.x + threadIdx.x;
    if (i < nu) {
        float2 v = ((const float2*)in)[i];
        float d = dinv[i >> 5];          // 32 uints per 64-feature row
        out[i] = pack2(v.x * d, v.y * d);
    }
}

// ---------------- Aggregation: out[d] = dinv[d] * (x'[d] + sum x'[s]) ----------------

// x': [N][64] bf16 = uint4[N][8]. 8 lanes/edge, 8 edge-groups, unroll 2.
__global__ void k_agg64b(const uint4* __restrict__ x4, const float* __restrict__ dinv,
                         const int* __restrict__ row_ptr, const int* __restrict__ csr_src,
                         uint4* __restrict__ out4, int n) {
    int lane = threadIdx.x & 63;
    int g = lane >> 3, c = lane & 7;
    int wid = (blockIdx.x * blockDim.x + threadIdx.x) >> 6;
    int nw = (gridDim.x * blockDim.x) >> 6;
    for (int i = wid; i < n; i += nw) {
        float a[8] = {0.f, 0.f, 0.f, 0.f, 0.f, 0.f, 0.f, 0.f};
        if (g == 0) {
            uint4 su = x4[(size_t)i * 8 + c];
            add8(a, su);
        }
        int j0 = row_ptr[i], j1 = row_ptr[i + 1];
        int j = j0 + g;
        for (; j + 8 < j1; j += 16) {
            int s0 = csr_src[j], s1 = csr_src[j + 8];
            uint4 u0 = x4[(size_t)s0 * 8 + c];
            uint4 u1 = x4[(size_t)s1 * 8 + c];
            add8(a, u0);
            add8(a, u1);
        }
        if (j < j1) {
            int s0 = csr_src[j];
            uint4 u0 = x4[(size_t)s0 * 8 + c];
            add8(a, u0);
        }
        #pragma unroll
        for (int k = 0; k < 8; ++k) {
            a[k] += __shfl_xor(a[k], 8);
            a[k] += __shfl_xor(a[k], 16);
            a[k] += __shfl_xor(a[k], 32);
        }
        if (g == 0) {
            float di = dinv[i];
            uint4 o;
            o.x = pack2(a[0] * di, a[1] * di);
            o.y = pack2(a[2] * di, a[3] * di);
            o.z = pack2(a[4] * di, a[5] * di);
            o.w = pack2(a[6] * di, a[7] * di);
            out4[(size_t)i * 8 + c] = o;
        }
    }
}

// h': [N][128] bf16 = uint4[N][16]. 16 lanes/edge, 4 edge-groups, unroll 4.
__global__ void k_agg128b(const uint4* __restrict__ h4, const float* __restrict__ dinv,
                          const int* __restrict__ row_ptr, const int* __restrict__ csr_src,
                          uint4* __restrict__ out4, int n) {
    int lane = threadIdx.x & 63;
    int q = lane >> 4, c = lane & 15;
    int wid = (blockIdx.x * blockDim.x + threadIdx.x) >> 6;
    int nw = (gridDim.x * blockDim.x) >> 6;
    for (int i = wid; i < n; i += nw) {
        float a[8] = {0.f, 0.f, 0.f, 0.f, 0.f, 0.f, 0.f, 0.f};
        if (q == 0) {
            uint4 su = h4[(size_t)i * 16 + c];
            add8(a, su);
        }
        int j0 = row_ptr[i], j1 = row_ptr[i + 1];
        int j = j0 + q;
        for (; j + 12 < j1; j += 16) {
            int s0 = csr_src[j], s1 = csr_src[j + 4];
            int s2 = csr_src[j + 8], s3 = csr_src[j + 12];
            uint4 u0 = h4[(size_t)s0 * 16 + c];
            uint4 u1 = h4[(size_t)s1 * 16 + c];
            uint4 u2 = h4[(size_t)s2 * 16 + c];
            uint4 u3 = h4[(size_t)s3 * 16 + c];
            add8(a, u0);
            add8(a, u1);
            add8(a, u2);
            add8(a, u3);
        }
        for (; j < j1; j += 4) {
            int s0 = csr_src[j];
            uint4 u0 = h4[(size_t)s0 * 16 + c];
            add8(a, u0);
        }
        #pragma unroll
        for (int k = 0; k < 8; ++k) {
            a[k] += __shfl_xor(a[k], 16);
            a[k] += __shfl_xor(a[k], 32);
        }
        if (q == 0) {
            float di = dinv[i];
            uint4 o;
            o.x = pack2(a[0] * di, a[1] * di);
            o.y = pack2(a[2] * di, a[3] * di);
            o.z = pack2(a[4] * di, a[5] * di);
            o.w = pack2(a[6] * di, a[7] * di);
            out4[(size_t)i * 16 + c] = o;
        }
    }
}

// ---------------- MFMA GEMM + LN (+ReLU) fused ----------------
// mfma_f32_16x16x32_bf16. A/B frag: k = (lane>>4)*8 + j. C/D: col=lane&15, row=(lane>>4)*4+reg.

// agg[N][64] bf16 @ W1[64][128] -> LN -> relu -> *dinv[row] -> hb[N][128] bf16
__launch_bounds__(256)
__global__ void k_mm1(const unsigned* __restrict__ aggb, const float* __restrict__ W1,
                      const float* __restrict__ b1, const float* __restrict__ g1,
                      const float* __restrict__ be1, const float* __restrict__ dinv,
                      unsigned short* __restrict__ hbs, int ntiles) {
    int lane = threadIdx.x & 63;
    int wv = threadIdx.x >> 6;
    int wpb = blockDim.x >> 6;
    int lc = lane & 15, lg = lane >> 4;

    short8v B[2][8];
    #pragma unroll
    for (int ks = 0; ks < 2; ++ks)
        #pragma unroll
        for (int cb = 0; cb < 8; ++cb) {
            short8v f;
            #pragma unroll
            for (int j = 0; j < 8; ++j) {
                int k = ks * 32 + lg * 8 + j;
                f[j] = (short)f2bf(W1[k * 128 + cb * 16 + lc]);
            }
            B[ks][cb] = f;
        }
    float bs[8], gm[8], bt[8];
    #pragma unroll
    for (int cb = 0; cb < 8; ++cb) {
        bs[cb] = b1[cb * 16 + lc];
        gm[cb] = g1[cb * 16 + lc];
        bt[cb] = be1[cb * 16 + lc];
    }

    for (int t = blockIdx.x * wpb + wv; t < ntiles; t += gridDim.x * wpb) {
        size_t arow = (size_t)(t * 16 + lc) * 32;
        U4S8 a0, a1;
        a0.u = *(const uint4*)&aggb[arow + lg * 4];
        a1.u = *(const uint4*)&aggb[arow + 16 + lg * 4];
        float4v acc[8];
        #pragma unroll
        for (int cb = 0; cb < 8; ++cb) acc[cb] = (float4v){0.f, 0.f, 0.f, 0.f};
        #pragma unroll
        for (int cb = 0; cb < 8; ++cb) {
            acc[cb] = __builtin_amdgcn_mfma_f32_16x16x32_bf16(a0.s, B[0][cb], acc[cb], 0, 0, 0);
            acc[cb] = __builtin_amdgcn_mfma_f32_16x16x32_bf16(a1.s, B[1][cb], acc[cb], 0, 0, 0);
        }
        #pragma unroll
        for (int reg = 0; reg < 4; ++reg) {
            float s = 0.f;
            #pragma unroll
            for (int cb = 0; cb < 8; ++cb) { acc[cb][reg] += bs[cb]; s += acc[cb][reg]; }
            s += __shfl_xor(s, 1); s += __shfl_xor(s, 2);
            s += __shfl_xor(s, 4); s += __shfl_xor(s, 8);
            float mu = s * (1.f / 128.f);
            float q = 0.f;
            #pragma unroll
            for (int cb = 0; cb < 8; ++cb) { float e = acc[cb][reg] - mu; q += e * e; }
            q += __shfl_xor(q, 1); q += __shfl_xor(q, 2);
            q += __shfl_xor(q, 4); q += __shfl_xor(q, 8);
            float rstd = rsqrtf(q * (1.f / 128.f) + LN_EPS);
            int rowi = t * 16 + lg * 4 + reg;
            float di = dinv[rowi];
            size_t row = (size_t)rowi * 128;
            #pragma unroll
            for (int cb = 0; cb < 8; ++cb) {
                float o = fmaf((acc[cb][reg] - mu) * rstd, gm[cb], bt[cb]);
                hbs[row + cb * 16 + lc] = f2bf(fmaxf(o, 0.f) * di);
            }
        }
    }
}

// agg2[N][128] bf16 @ W2[128][128] -> LN -> pooled atomicAdd into psum[G][128]
__launch_bounds__(256)
__global__ void k_mm2p(const unsigned* __restrict__ aggb, const float* __restrict__ W2,
                       const float* __restrict__ b2, const float* __restrict__ g2,
                       const float* __restrict__ be2, const int* __restrict__ batch,
                       float* __restrict__ psum, int ntiles) {
    __shared__ uint4 sB[4 * 8 * 64];   // 32 KiB
    for (int idx = threadIdx.x; idx < 2048; idx += blockDim.x) {
        int l = idx & 63;
        int f = idx >> 6;
        int ks = f >> 3, cb = f & 7;
        int kb = ks * 32 + (l >> 4) * 8;
        int col = cb * 16 + (l & 15);
        float p[8];
        #pragma unroll
        for (int j = 0; j < 8; ++j) p[j] = W2[(kb + j) * 128 + col];
        uint4 v;
        v.x = pack2(p[0], p[1]); v.y = pack2(p[2], p[3]);
        v.z = pack2(p[4], p[5]); v.w = pack2(p[6], p[7]);
        sB[idx] = v;
    }
    __syncthreads();

    int lane = threadIdx.x & 63;
    int wv = threadIdx.x >> 6;
    int wpb = blockDim.x >> 6;
    int lc = lane & 15, lg = lane >> 4;
    float bs[8], gm[8], bt[8];
    #pragma unroll
    for (int cb = 0; cb < 8; ++cb) {
        bs[cb] = b2[cb * 16 + lc];
        gm[cb] = g2[cb * 16 + lc];
        bt[cb] = be2[cb * 16 + lc];
    }

    for (int t = blockIdx.x * wpb + wv; t < ntiles; t += gridDim.x * wpb) {
        int row0 = t * 16;
        size_t arow = (size_t)(row0 + lc) * 64;
        U4S8 a[4];
        #pragma unroll
        for (int ks = 0; ks < 4; ++ks)
            a[ks].u = *(const uint4*)&aggb[arow + ks * 16 + lg * 4];
        float4v acc[8];
        #pragma unroll
        for (int cb = 0; cb < 8; ++cb) acc[cb] = (float4v){0.f, 0.f, 0.f, 0.f};
        #pragma unroll
        for (int ks = 0; ks < 4; ++ks) {
            #pragma unroll
            for (int cb = 0; cb < 8; ++cb) {
                U4S8 fb;
                fb.u = sB[(ks * 8 + cb) * 64 + lane];
                acc[cb] = __builtin_amdgcn_mfma_f32_16x16x32_bf16(a[ks].s, fb.s, acc[cb], 0, 0, 0);
            }
        }
        #pragma unroll
        for (int reg = 0; reg < 4; ++reg) {
            float s = 0.f;
            #pragma unroll
            for (int cb = 0; cb < 8; ++cb) { acc[cb][reg] += bs[cb]; s += acc[cb][reg]; }
            s += __shfl_xor(s, 1); s += __shfl_xor(s, 2);
            s += __shfl_xor(s, 4); s += __shfl_xor(s, 8);
            float mu = s * (1.f / 128.f);
            float q = 0.f;
            #pragma unroll
            for (int cb = 0; cb < 8; ++cb) { float e = acc[cb][reg] - mu; q += e * e; }
            q += __shfl_xor(q, 1); q += __shfl_xor(q, 2);
            q += __shfl_xor(q, 4); q += __shfl_xor(q, 8);
            float rstd = rsqrtf(q * (1.f / 128.f) + LN_EPS);
            #pragma unroll
            for (int cb = 0; cb < 8; ++cb)
                acc[cb][reg] = fmaf((acc[cb][reg] - mu) * rstd, gm[cb], bt[cb]);
        }
        int gmin = batch[row0];
        int gmax = batch[row0 + 15];
        int rg[4];
        #pragma unroll
        for (int reg = 0; reg < 4; ++reg) rg[reg] = batch[row0 + lg * 4 + reg];
        for (int g = gmin; g <= gmax; ++g) {
            #pragma unroll
            for (int cb = 0; cb < 8; ++cb) {
                float s = 0.f;
                #pragma unroll
                for (int reg = 0; reg < 4; ++reg)
                    s += (rg[reg] == g) ? acc[cb][reg] : 0.f;
                s += __shfl_xor(s, 16);
                s += __shfl_xor(s, 32);
                if (lg == 0) atomicAdd(&psum[g * 128 + cb * 16 + lc], s);
            }
        }
    }
}

// ---------------- divide by graph sizes ----------------

__device__ __forceinline__ int lowerb(const int* __restrict__ b, int n, int key) {
    int lo = 0, hi = n;
    while (lo < hi) {
        int m = (lo + hi) >> 1;
        if (b[m] < key) lo = m + 1; else hi = m;
    }
    return lo;
}

__global__ void k_div(float* __restrict__ out, const int* __restrict__ batch,
                      int n, int total) {
    int idx = blockIdx.x * blockDim.x + threadIdx.x;
    if (idx < total) {
        int g = idx >> 7;
        int start = lowerb(batch, n, g);
        int end   = lowerb(batch, n, g + 1);
        out[idx] /= fmaxf((float)(end - start), 1.f);
    }
}

// ---------------- launch ----------------

extern "C" void kernel_launch(void* const* d_in, const int* in_sizes, int n_in,
                              void* d_out, int out_size, void* d_ws, size_t ws_size,
                              hipStream_t stream) {
    const float* x   = (const float*)d_in[0];
    const int*   ei  = (const int*)d_in[1];
    const int*   bat = (const int*)d_in[2];
    const float* W1  = (const float*)d_in[3];
    const float* b1  = (const float*)d_in[4];
    const float* g1  = (const float*)d_in[5];
    const float* be1 = (const float*)d_in[6];
    const float* W2  = (const float*)d_in[7];
    const float* b2  = (const float*)d_in[8];
    const float* g2  = (const float*)d_in[9];
    const float* be2 = (const float*)d_in[10];

    int n = in_sizes[0] / 64;     // 100000
    int e = in_sizes[1] / 2;      // 1600000
    const int* src = ei;
    const int* dst = ei + e;

    char* ws = (char*)d_ws;
    size_t off = 0;
    auto take = [&](size_t bytes) -> void* {
        void* p = ws + off;
        off = (off + bytes + 255) & ~(size_t)255;
        return p;
    };
    int*      cnt     = (int*)     take((size_t)n * 4);
    float*    dinv    = (float*)   take((size_t)n * 4);
    int*      row_ptr = (int*)     take((size_t)(n + 1) * 4);
    int*      bsum    = (int*)     take(1024 * 4);
    int*      gcnt    = (int*)     take(NBMAX * 4);
    uint2*    stage   = (uint2*)   take((size_t)e * 8);
    int*      csr_src = (int*)     take((size_t)e * 4);
    unsigned* xb      = (unsigned*)take((size_t)n * 64 * 2);
    unsigned* aggb    = (unsigned*)take((size_t)n * 64 * 2);
    unsigned* hb      = (unsigned*)take((size_t)n * 128 * 2);
    unsigned* agg2b   = (unsigned*)take((size_t)n * 128 * 2);

    hipMemsetAsync(cnt, 0, (size_t)n * 4, stream);
    hipMemsetAsync(gcnt, 0, NBMAX * 4, stream);
    hipMemsetAsync(d_out, 0, (size_t)out_size * 4, stream);

    k_hist<<<(e + 255) / 256, 256, 0, stream>>>(dst, e, cnt);
    k_dinv<<<(n + 255) / 256, 256, 0, stream>>>(cnt, n, dinv);
    int nb = (n + 1023) / 1024;
    k_scan1<<<nb, 1024, 0, stream>>>(cnt, n, row_ptr, bsum);
    k_scan2<<<1, 1024, 0, stream>>>(bsum, nb);
    k_scan3<<<(n + 255) / 256, 256, 0, stream>>>(row_ptr, bsum, n, e);

    int nbk = (e + CHUNK - 1) / CHUNK;
    k_bucket<<<nbk, 256, 0, stream>>>(src, dst, e, row_ptr, gcnt, stage);
    int nbuckets = (n + 255) / 256;
    k_csr<<<nbuckets, 256, 0, stream>>>(stage, row_ptr, csr_src, n);

    int nux = n * 32;
    k_f2bs<<<(nux + 255) / 256, 256, 0, stream>>>(x, dinv, xb, nux);

    k_agg64b<<<2048, 256, 0, stream>>>((const uint4*)xb, dinv, row_ptr, csr_src,
                                       (uint4*)aggb, n);

    int ntiles = n / 16;  // 6250
    int mmblocks = (ntiles + 3) / 4;
    k_mm1<<<mmblocks, 256, 0, stream>>>(aggb, W1, b1, g1, be1, dinv,
                                        (unsigned short*)hb, ntiles);

    k_agg128b<<<2048, 256, 0, stream>>>((const uint4*)hb, dinv, row_ptr, csr_src,
                                        (uint4*)agg2b, n);

    k_mm2p<<<mmblocks, 256, 0, stream>>>(agg2b, W2, b2, g2, be2, bat, (float*)d_out, ntiles);

    int total = out_size;
    k_div<<<(total + 255) / 256, 256, 0, stream>>>((float*)d_out, bat, n, total);
}

// Round 6
// 233.326 us; speedup vs baseline: 4.8845x; 1.2622x over previous
//
#include <hip/hip_runtime.h>

#define LN_EPS 1e-5f

typedef __attribute__((ext_vector_type(8))) short short8v;
typedef __attribute__((ext_vector_type(4))) float float4v;

__device__ __forceinline__ float bflo(unsigned u) { return __uint_as_float(u << 16); }
__device__ __forceinline__ float bfhi(unsigned u) { return __uint_as_float(u & 0xffff0000u); }
__device__ __forceinline__ unsigned short f2bf(float f) {
    unsigned b = __float_as_uint(f);
    unsigned r = b + 0x7fffu + ((b >> 16) & 1u);
    return (unsigned short)(r >> 16);
}
__device__ __forceinline__ unsigned pack2(float x, float y) {
    return (unsigned)f2bf(x) | ((unsigned)f2bf(y) << 16);
}
__device__ __forceinline__ void add8(float* a, uint4 u) {
    a[0] += bflo(u.x); a[1] += bfhi(u.x);
    a[2] += bflo(u.y); a[3] += bfhi(u.y);
    a[4] += bflo(u.z); a[5] += bfhi(u.z);
    a[6] += bflo(u.w); a[7] += bfhi(u.w);
}

union U4S8 { uint4 u; short8v s; };

// ---------------- bucketed CSR build (no per-node global atomics) ----------------
// bucket b = dst >> 8 (256 nodes/bucket). Stage layout == CSR layout.

#define CHUNK 4096
#define NBMAX 512
#define CSRCAP 8192

// pass 0: per-chunk LDS bucket histogram -> <=NBMAX global atomics per block
__launch_bounds__(256)
__global__ void k_bcnt(const int* __restrict__ dst, int e, int* __restrict__ bcnt) {
    __shared__ int hist[NBMAX];
    int tid = threadIdx.x;
    int c0 = blockIdx.x * CHUNK;
    if (c0 >= e) return;
    int cnt = min(CHUNK, e - c0);
    for (int t = tid; t < NBMAX; t += 256) hist[t] = 0;
    __syncthreads();
    for (int t = tid; t < cnt; t += 256)
        atomicAdd(&hist[((unsigned)dst[c0 + t]) >> 8], 1);
    __syncthreads();
    for (int b = tid; b < NBMAX; b += 256) {
        int h = hist[b];
        if (h > 0) atomicAdd(&bcnt[b], h);
    }
}

// pass 0.5: single-block exclusive scan of bucket counts -> bptr[NBMAX+1]
__launch_bounds__(512)
__global__ void k_bscan(const int* __restrict__ bcnt, int* __restrict__ bptr) {
    __shared__ int s[NBMAX];
    int tid = threadIdx.x;
    int v = bcnt[tid];
    s[tid] = v; __syncthreads();
    for (int o = 1; o < NBMAX; o <<= 1) {
        int t = (tid >= o) ? s[tid - o] : 0;
        __syncthreads();
        s[tid] += t;
        __syncthreads();
    }
    bptr[tid + 1] = s[tid];
    if (tid == 0) bptr[0] = 0;
}

// pass 1: stage (src,dst) into bucket regions; one global atomic per (block,bucket)
__launch_bounds__(256)
__global__ void k_bucket(const int* __restrict__ src, const int* __restrict__ dst, int e,
                         const int* __restrict__ bptr, int* __restrict__ gcnt,
                         uint2* __restrict__ stage) {
    __shared__ uint2 ebuf[CHUNK];
    __shared__ int hist[NBMAX];
    __shared__ int base[NBMAX];
    int tid = threadIdx.x;
    int c0 = blockIdx.x * CHUNK;
    if (c0 >= e) return;
    int cnt = min(CHUNK, e - c0);

    for (int t = tid; t < NBMAX; t += 256) hist[t] = 0;
    __syncthreads();
    for (int t = tid; t < cnt; t += 256) {
        uint2 ed = make_uint2((unsigned)src[c0 + t], (unsigned)dst[c0 + t]);
        ebuf[t] = ed;
        atomicAdd(&hist[ed.y >> 8], 1);
    }
    __syncthreads();
    for (int b = tid; b < NBMAX; b += 256) {
        int h = hist[b];
        if (h > 0) base[b] = bptr[b] + atomicAdd(&gcnt[b], h);
    }
    __syncthreads();
    for (int t = tid; t < cnt; t += 256) {
        uint2 ed = ebuf[t];
        int p = atomicAdd(&base[ed.y >> 8], 1);
        stage[p] = ed;
    }
}

// pass 2: one block per bucket. Degrees + row_ptr + dinv + rank-scatter CSR, all in LDS.
__launch_bounds__(256)
__global__ void k_csr(const uint2* __restrict__ stage, const int* __restrict__ bptr,
                      int* __restrict__ csr_src, int* __restrict__ row_ptr,
                      float* __restrict__ dinv, int n, int e) {
    __shared__ int cntl[256];   // per-node count, then rank pos
    __shared__ int sc[256];     // inclusive scan
    __shared__ int excl[256];   // exclusive offsets (persist)
    __shared__ int cbuf[CSRCAP];
    int b = blockIdx.x;
    int lo = b << 8;
    int nn = min(n - lo, 256);
    int tid = threadIdx.x;
    int s0 = bptr[b], s1 = bptr[b + 1];
    int cntB = s1 - s0;

    cntl[tid] = 0;
    __syncthreads();
    for (int t = tid; t < cntB; t += 256) {
        int dl = (int)stage[s0 + t].y - lo;
        atomicAdd(&cntl[dl], 1);
    }
    __syncthreads();
    int deg = (tid < nn) ? cntl[tid] : 0;
    sc[tid] = deg; __syncthreads();
    for (int o = 1; o < 256; o <<= 1) {
        int t = (tid >= o) ? sc[tid - o] : 0;
        __syncthreads();
        sc[tid] += t;
        __syncthreads();
    }
    excl[tid] = sc[tid] - deg;
    if (tid < nn) {
        row_ptr[lo + tid] = s0 + excl[tid];
        dinv[lo + tid] = rsqrtf((float)(deg + 1));
    }
    if (b == 0 && tid == 0) row_ptr[n] = e;
    cntl[tid] = 0;
    __syncthreads();
    for (int t = tid; t < cntB; t += 256) {
        uint2 ed = stage[s0 + t];
        int dl = (int)ed.y - lo;
        int r = atomicAdd(&cntl[dl], 1);
        int p = excl[dl] + r;
        if (p < CSRCAP) cbuf[p] = (int)ed.x;
        else csr_src[s0 + p] = (int)ed.x;   // overflow fallback (stat. impossible here)
    }
    __syncthreads();
    int lim = min(cntB, CSRCAP);
    for (int t = tid; t < lim; t += 256) csr_src[s0 + t] = cbuf[t];
}

// ---------------- fp32 -> bf16x2 pack, pre-scaled by dinv[row] ----------------

__global__ void k_f2bs(const float* __restrict__ in, const float* __restrict__ dinv,
                       unsigned* __restrict__ out, int nu) {
    int i = blockIdx.x * blockDim.x + threadIdx.x;
    if (i < nu) {
        float2 v = ((const float2*)in)[i];
        float d = dinv[i >> 5];          // 32 uints per 64-feature row
        out[i] = pack2(v.x * d, v.y * d);
    }
}

// ---------------- Aggregation: out[d] = dinv[d] * (x'[d] + sum x'[s]) ----------------

// x': [N][64] bf16 = uint4[N][8]. 8 lanes/edge, 8 edge-groups, unroll 2.
__global__ void k_agg64b(const uint4* __restrict__ x4, const float* __restrict__ dinv,
                         const int* __restrict__ row_ptr, const int* __restrict__ csr_src,
                         uint4* __restrict__ out4, int n) {
    int lane = threadIdx.x & 63;
    int g = lane >> 3, c = lane & 7;
    int wid = (blockIdx.x * blockDim.x + threadIdx.x) >> 6;
    int nw = (gridDim.x * blockDim.x) >> 6;
    for (int i = wid; i < n; i += nw) {
        float a[8] = {0.f, 0.f, 0.f, 0.f, 0.f, 0.f, 0.f, 0.f};
        if (g == 0) {
            uint4 su = x4[(size_t)i * 8 + c];
            add8(a, su);
        }
        int j0 = row_ptr[i], j1 = row_ptr[i + 1];
        int j = j0 + g;
        for (; j + 8 < j1; j += 16) {
            int s0 = csr_src[j], s1 = csr_src[j + 8];
            uint4 u0 = x4[(size_t)s0 * 8 + c];
            uint4 u1 = x4[(size_t)s1 * 8 + c];
            add8(a, u0);
            add8(a, u1);
        }
        if (j < j1) {
            int s0 = csr_src[j];
            uint4 u0 = x4[(size_t)s0 * 8 + c];
            add8(a, u0);
        }
        #pragma unroll
        for (int k = 0; k < 8; ++k) {
            a[k] += __shfl_xor(a[k], 8);
            a[k] += __shfl_xor(a[k], 16);
            a[k] += __shfl_xor(a[k], 32);
        }
        if (g == 0) {
            float di = dinv[i];
            uint4 o;
            o.x = pack2(a[0] * di, a[1] * di);
            o.y = pack2(a[2] * di, a[3] * di);
            o.z = pack2(a[4] * di, a[5] * di);
            o.w = pack2(a[6] * di, a[7] * di);
            out4[(size_t)i * 8 + c] = o;
        }
    }
}

// h': [N][128] bf16 = uint4[N][16]. 16 lanes/edge, 4 edge-groups, unroll 4.
__global__ void k_agg128b(const uint4* __restrict__ h4, const float* __restrict__ dinv,
                          const int* __restrict__ row_ptr, const int* __restrict__ csr_src,
                          uint4* __restrict__ out4, int n) {
    int lane = threadIdx.x & 63;
    int q = lane >> 4, c = lane & 15;
    int wid = (blockIdx.x * blockDim.x + threadIdx.x) >> 6;
    int nw = (gridDim.x * blockDim.x) >> 6;
    for (int i = wid; i < n; i += nw) {
        float a[8] = {0.f, 0.f, 0.f, 0.f, 0.f, 0.f, 0.f, 0.f};
        if (q == 0) {
            uint4 su = h4[(size_t)i * 16 + c];
            add8(a, su);
        }
        int j0 = row_ptr[i], j1 = row_ptr[i + 1];
        int j = j0 + q;
        for (; j + 12 < j1; j += 16) {
            int s0 = csr_src[j], s1 = csr_src[j + 4];
            int s2 = csr_src[j + 8], s3 = csr_src[j + 12];
            uint4 u0 = h4[(size_t)s0 * 16 + c];
            uint4 u1 = h4[(size_t)s1 * 16 + c];
            uint4 u2 = h4[(size_t)s2 * 16 + c];
            uint4 u3 = h4[(size_t)s3 * 16 + c];
            add8(a, u0);
            add8(a, u1);
            add8(a, u2);
            add8(a, u3);
        }
        for (; j < j1; j += 4) {
            int s0 = csr_src[j];
            uint4 u0 = h4[(size_t)s0 * 16 + c];
            add8(a, u0);
        }
        #pragma unroll
        for (int k = 0; k < 8; ++k) {
            a[k] += __shfl_xor(a[k], 16);
            a[k] += __shfl_xor(a[k], 32);
        }
        if (q == 0) {
            float di = dinv[i];
            uint4 o;
            o.x = pack2(a[0] * di, a[1] * di);
            o.y = pack2(a[2] * di, a[3] * di);
            o.z = pack2(a[4] * di, a[5] * di);
            o.w = pack2(a[6] * di, a[7] * di);
            out4[(size_t)i * 16 + c] = o;
        }
    }
}

// ---------------- MFMA GEMM + LN (+ReLU) fused ----------------
// mfma_f32_16x16x32_bf16. A/B frag: k = (lane>>4)*8 + j. C/D: col=lane&15, row=(lane>>4)*4+reg.

// agg[N][64] bf16 @ W1[64][128] -> LN -> relu -> *dinv[row] -> hb[N][128] bf16
__launch_bounds__(256)
__global__ void k_mm1(const unsigned* __restrict__ aggb, const float* __restrict__ W1,
                      const float* __restrict__ b1, const float* __restrict__ g1,
                      const float* __restrict__ be1, const float* __restrict__ dinv,
                      unsigned short* __restrict__ hbs, int ntiles) {
    int lane = threadIdx.x & 63;
    int wv = threadIdx.x >> 6;
    int wpb = blockDim.x >> 6;
    int lc = lane & 15, lg = lane >> 4;

    short8v B[2][8];
    #pragma unroll
    for (int ks = 0; ks < 2; ++ks)
        #pragma unroll
        for (int cb = 0; cb < 8; ++cb) {
            short8v f;
            #pragma unroll
            for (int j = 0; j < 8; ++j) {
                int k = ks * 32 + lg * 8 + j;
                f[j] = (short)f2bf(W1[k * 128 + cb * 16 + lc]);
            }
            B[ks][cb] = f;
        }
    float bs[8], gm[8], bt[8];
    #pragma unroll
    for (int cb = 0; cb < 8; ++cb) {
        bs[cb] = b1[cb * 16 + lc];
        gm[cb] = g1[cb * 16 + lc];
        bt[cb] = be1[cb * 16 + lc];
    }

    for (int t = blockIdx.x * wpb + wv; t < ntiles; t += gridDim.x * wpb) {
        size_t arow = (size_t)(t * 16 + lc) * 32;
        U4S8 a0, a1;
        a0.u = *(const uint4*)&aggb[arow + lg * 4];
        a1.u = *(const uint4*)&aggb[arow + 16 + lg * 4];
        float4v acc[8];
        #pragma unroll
        for (int cb = 0; cb < 8; ++cb) acc[cb] = (float4v){0.f, 0.f, 0.f, 0.f};
        #pragma unroll
        for (int cb = 0; cb < 8; ++cb) {
            acc[cb] = __builtin_amdgcn_mfma_f32_16x16x32_bf16(a0.s, B[0][cb], acc[cb], 0, 0, 0);
            acc[cb] = __builtin_amdgcn_mfma_f32_16x16x32_bf16(a1.s, B[1][cb], acc[cb], 0, 0, 0);
        }
        #pragma unroll
        for (int reg = 0; reg < 4; ++reg) {
            float s = 0.f;
            #pragma unroll
            for (int cb = 0; cb < 8; ++cb) { acc[cb][reg] += bs[cb]; s += acc[cb][reg]; }
            s += __shfl_xor(s, 1); s += __shfl_xor(s, 2);
            s += __shfl_xor(s, 4); s += __shfl_xor(s, 8);
            float mu = s * (1.f / 128.f);
            float q = 0.f;
            #pragma unroll
            for (int cb = 0; cb < 8; ++cb) { float e = acc[cb][reg] - mu; q += e * e; }
            q += __shfl_xor(q, 1); q += __shfl_xor(q, 2);
            q += __shfl_xor(q, 4); q += __shfl_xor(q, 8);
            float rstd = rsqrtf(q * (1.f / 128.f) + LN_EPS);
            int rowi = t * 16 + lg * 4 + reg;
            float di = dinv[rowi];
            size_t row = (size_t)rowi * 128;
            #pragma unroll
            for (int cb = 0; cb < 8; ++cb) {
                float o = fmaf((acc[cb][reg] - mu) * rstd, gm[cb], bt[cb]);
                hbs[row + cb * 16 + lc] = f2bf(fmaxf(o, 0.f) * di);
            }
        }
    }
}

// agg2[N][128] bf16 @ W2[128][128] -> LN -> pooled atomicAdd into psum[G][128]
__launch_bounds__(256)
__global__ void k_mm2p(const unsigned* __restrict__ aggb, const float* __restrict__ W2,
                       const float* __restrict__ b2, const float* __restrict__ g2,
                       const float* __restrict__ be2, const int* __restrict__ batch,
                       float* __restrict__ psum, int ntiles) {
    __shared__ uint4 sB[4 * 8 * 64];   // 32 KiB
    for (int idx = threadIdx.x; idx < 2048; idx += blockDim.x) {
        int l = idx & 63;
        int f = idx >> 6;
        int ks = f >> 3, cb = f & 7;
        int kb = ks * 32 + (l >> 4) * 8;
        int col = cb * 16 + (l & 15);
        float p[8];
        #pragma unroll
        for (int j = 0; j < 8; ++j) p[j] = W2[(kb + j) * 128 + col];
        uint4 v;
        v.x = pack2(p[0], p[1]); v.y = pack2(p[2], p[3]);
        v.z = pack2(p[4], p[5]); v.w = pack2(p[6], p[7]);
        sB[idx] = v;
    }
    __syncthreads();

    int lane = threadIdx.x & 63;
    int wv = threadIdx.x >> 6;
    int wpb = blockDim.x >> 6;
    int lc = lane & 15, lg = lane >> 4;
    float bs[8], gm[8], bt[8];
    #pragma unroll
    for (int cb = 0; cb < 8; ++cb) {
        bs[cb] = b2[cb * 16 + lc];
        gm[cb] = g2[cb * 16 + lc];
        bt[cb] = be2[cb * 16 + lc];
    }

    for (int t = blockIdx.x * wpb + wv; t < ntiles; t += gridDim.x * wpb) {
        int row0 = t * 16;
        size_t arow = (size_t)(row0 + lc) * 64;
        U4S8 a[4];
        #pragma unroll
        for (int ks = 0; ks < 4; ++ks)
            a[ks].u = *(const uint4*)&aggb[arow + ks * 16 + lg * 4];
        float4v acc[8];
        #pragma unroll
        for (int cb = 0; cb < 8; ++cb) acc[cb] = (float4v){0.f, 0.f, 0.f, 0.f};
        #pragma unroll
        for (int ks = 0; ks < 4; ++ks) {
            #pragma unroll
            for (int cb = 0; cb < 8; ++cb) {
                U4S8 fb;
                fb.u = sB[(ks * 8 + cb) * 64 + lane];
                acc[cb] = __builtin_amdgcn_mfma_f32_16x16x32_bf16(a[ks].s, fb.s, acc[cb], 0, 0, 0);
            }
        }
        #pragma unroll
        for (int reg = 0; reg < 4; ++reg) {
            float s = 0.f;
            #pragma unroll
            for (int cb = 0; cb < 8; ++cb) { acc[cb][reg] += bs[cb]; s += acc[cb][reg]; }
            s += __shfl_xor(s, 1); s += __shfl_xor(s, 2);
            s += __shfl_xor(s, 4); s += __shfl_xor(s, 8);
            float mu = s * (1.f / 128.f);
            float q = 0.f;
            #pragma unroll
            for (int cb = 0; cb < 8; ++cb) { float e = acc[cb][reg] - mu; q += e * e; }
            q += __shfl_xor(q, 1); q += __shfl_xor(q, 2);
            q += __shfl_xor(q, 4); q += __shfl_xor(q, 8);
            float rstd = rsqrtf(q * (1.f / 128.f) + LN_EPS);
            #pragma unroll
            for (int cb = 0; cb < 8; ++cb)
                acc[cb][reg] = fmaf((acc[cb][reg] - mu) * rstd, gm[cb], bt[cb]);
        }
        int gmin = batch[row0];
        int gmax = batch[row0 + 15];
        int rg[4];
        #pragma unroll
        for (int reg = 0; reg < 4; ++reg) rg[reg] = batch[row0 + lg * 4 + reg];
        for (int g = gmin; g <= gmax; ++g) {
            #pragma unroll
            for (int cb = 0; cb < 8; ++cb) {
                float s = 0.f;
                #pragma unroll
                for (int reg = 0; reg < 4; ++reg)
                    s += (rg[reg] == g) ? acc[cb][reg] : 0.f;
                s += __shfl_xor(s, 16);
                s += __shfl_xor(s, 32);
                if (lg == 0) atomicAdd(&psum[g * 128 + cb * 16 + lc], s);
            }
        }
    }
}

// ---------------- divide by graph sizes ----------------

__device__ __forceinline__ int lowerb(const int* __restrict__ b, int n, int key) {
    int lo = 0, hi = n;
    while (lo < hi) {
        int m = (lo + hi) >> 1;
        if (b[m] < key) lo = m + 1; else hi = m;
    }
    return lo;
}

__global__ void k_div(float* __restrict__ out, const int* __restrict__ batch,
                      int n, int total) {
    int idx = blockIdx.x * blockDim.x + threadIdx.x;
    if (idx < total) {
        int g = idx >> 7;
        int start = lowerb(batch, n, g);
        int end   = lowerb(batch, n, g + 1);
        out[idx] /= fmaxf((float)(end - start), 1.f);
    }
}

// ---------------- launch ----------------

extern "C" void kernel_launch(void* const* d_in, const int* in_sizes, int n_in,
                              void* d_out, int out_size, void* d_ws, size_t ws_size,
                              hipStream_t stream) {
    const float* x   = (const float*)d_in[0];
    const int*   ei  = (const int*)d_in[1];
    const int*   bat = (const int*)d_in[2];
    const float* W1  = (const float*)d_in[3];
    const float* b1  = (const float*)d_in[4];
    const float* g1  = (const float*)d_in[5];
    const float* be1 = (const float*)d_in[6];
    const float* W2  = (const float*)d_in[7];
    const float* b2  = (const float*)d_in[8];
    const float* g2  = (const float*)d_in[9];
    const float* be2 = (const float*)d_in[10];

    int n = in_sizes[0] / 64;     // 100000
    int e = in_sizes[1] / 2;      // 1600000
    const int* src = ei;
    const int* dst = ei + e;

    char* ws = (char*)d_ws;
    size_t off = 0;
    auto take = [&](size_t bytes) -> void* {
        void* p = ws + off;
        off = (off + bytes + 255) & ~(size_t)255;
        return p;
    };
    float*    dinv    = (float*)   take((size_t)n * 4);
    int*      row_ptr = (int*)     take((size_t)(n + 1) * 4);
    int*      bcnt    = (int*)     take(NBMAX * 4);
    int*      bptr    = (int*)     take((NBMAX + 1) * 4);
    int*      gcnt    = (int*)     take(NBMAX * 4);
    uint2*    stage   = (uint2*)   take((size_t)e * 8);
    int*      csr_src = (int*)     take((size_t)e * 4);
    unsigned* xb      = (unsigned*)take((size_t)n * 64 * 2);
    unsigned* aggb    = (unsigned*)take((size_t)n * 64 * 2);
    unsigned* hb      = (unsigned*)take((size_t)n * 128 * 2);
    unsigned* agg2b   = (unsigned*)take((size_t)n * 128 * 2);

    hipMemsetAsync(bcnt, 0, NBMAX * 4, stream);
    hipMemsetAsync(gcnt, 0, NBMAX * 4, stream);
    hipMemsetAsync(d_out, 0, (size_t)out_size * 4, stream);

    int nbk = (e + CHUNK - 1) / CHUNK;
    k_bcnt<<<nbk, 256, 0, stream>>>(dst, e, bcnt);
    k_bscan<<<1, NBMAX, 0, stream>>>(bcnt, bptr);
    k_bucket<<<nbk, 256, 0, stream>>>(src, dst, e, bptr, gcnt, stage);
    int nbuckets = (n + 255) / 256;
    k_csr<<<nbuckets, 256, 0, stream>>>(stage, bptr, csr_src, row_ptr, dinv, n, e);

    int nux = n * 32;
    k_f2bs<<<(nux + 255) / 256, 256, 0, stream>>>(x, dinv, xb, nux);

    k_agg64b<<<2048, 256, 0, stream>>>((const uint4*)xb, dinv, row_ptr, csr_src,
                                       (uint4*)aggb, n);

    int ntiles = n / 16;  // 6250
    int mmblocks = (ntiles + 3) / 4;
    k_mm1<<<mmblocks, 256, 0, stream>>>(aggb, W1, b1, g1, be1, dinv,
                                        (unsigned short*)hb, ntiles);

    k_agg128b<<<2048, 256, 0, stream>>>((const uint4*)hb, dinv, row_ptr, csr_src,
                                        (uint4*)agg2b, n);

    k_mm2p<<<mmblocks, 256, 0, stream>>>(agg2b, W2, b2, g2, be2, bat, (float*)d_out, ntiles);

    int total = out_size;
    k_div<<<(total + 255) / 256, 256, 0, stream>>>((float*)d_out, bat, n, total);
}

// Round 7
// 226.774 us; speedup vs baseline: 5.0256x; 1.0289x over previous
//
#include <hip/hip_runtime.h>
#include <hip/hip_bf16.h>

#define LN_EPS 1e-5f

typedef __attribute__((ext_vector_type(8))) short short8v;
typedef __attribute__((ext_vector_type(4))) float float4v;

__device__ __forceinline__ float bflo(unsigned u) { return __uint_as_float(u << 16); }
__device__ __forceinline__ float bfhi(unsigned u) { return __uint_as_float(u & 0xffff0000u); }
__device__ __forceinline__ unsigned short f2bf(float f) {
    __hip_bfloat16 b = __float2bfloat16(f);
    return *reinterpret_cast<unsigned short*>(&b);
}
__device__ __forceinline__ unsigned pack2(float x, float y) {
    __hip_bfloat162 t = __float22bfloat162_rn(make_float2(x, y));
    return *reinterpret_cast<unsigned*>(&t);
}
__device__ __forceinline__ void add8(float* a, uint4 u) {
    a[0] += bflo(u.x); a[1] += bfhi(u.x);
    a[2] += bflo(u.y); a[3] += bfhi(u.y);
    a[4] += bflo(u.z); a[5] += bfhi(u.z);
    a[6] += bflo(u.w); a[7] += bfhi(u.w);
}

union U4S8 { uint4 u; short8v s; };

// ---------------- bucketed CSR build (no per-node global atomics) ----------------
// bucket b = dst >> 8 (256 nodes/bucket). Stage layout == CSR layout.
// stage entry: src | (dst&0xff)<<24  (src < 2^24)

#define CHUNK 4096
#define NBMAX 512
#define CSRCAP 8192

// pass 0: per-chunk LDS bucket histogram -> <=NBMAX global atomics per block
__launch_bounds__(256)
__global__ void k_bcnt(const int* __restrict__ dst, int e, int* __restrict__ bcnt) {
    __shared__ int hist[NBMAX];
    int tid = threadIdx.x;
    int c0 = blockIdx.x * CHUNK;
    if (c0 >= e) return;
    int cnt = min(CHUNK, e - c0);
    for (int t = tid; t < NBMAX; t += 256) hist[t] = 0;
    __syncthreads();
    for (int t = tid; t < cnt; t += 256)
        atomicAdd(&hist[((unsigned)dst[c0 + t]) >> 8], 1);
    __syncthreads();
    for (int b = tid; b < NBMAX; b += 256) {
        int h = hist[b];
        if (h > 0) atomicAdd(&bcnt[b], h);
    }
}

// pass 0.5: single-block exclusive scan of bucket counts -> bptr[NBMAX+1]
__launch_bounds__(512)
__global__ void k_bscan(const int* __restrict__ bcnt, int* __restrict__ bptr) {
    __shared__ int s[NBMAX];
    int tid = threadIdx.x;
    int v = bcnt[tid];
    s[tid] = v; __syncthreads();
    for (int o = 1; o < NBMAX; o <<= 1) {
        int t = (tid >= o) ? s[tid - o] : 0;
        __syncthreads();
        s[tid] += t;
        __syncthreads();
    }
    bptr[tid + 1] = s[tid];
    if (tid == 0) bptr[0] = 0;
}

// pass 1: stage packed (src|dstlow<<24) into bucket regions
__launch_bounds__(256)
__global__ void k_bucket(const int* __restrict__ src, const int* __restrict__ dst, int e,
                         const int* __restrict__ bptr, int* __restrict__ gcnt,
                         unsigned* __restrict__ stage) {
    __shared__ unsigned ebuf[CHUNK];
    __shared__ unsigned short ebkt[CHUNK];
    __shared__ int hist[NBMAX];
    __shared__ int base[NBMAX];
    int tid = threadIdx.x;
    int c0 = blockIdx.x * CHUNK;
    if (c0 >= e) return;
    int cnt = min(CHUNK, e - c0);

    for (int t = tid; t < NBMAX; t += 256) hist[t] = 0;
    __syncthreads();
    for (int t = tid; t < cnt; t += 256) {
        unsigned s = (unsigned)src[c0 + t];
        unsigned d = (unsigned)dst[c0 + t];
        ebuf[t] = s | ((d & 0xffu) << 24);
        ebkt[t] = (unsigned short)(d >> 8);
        atomicAdd(&hist[d >> 8], 1);
    }
    __syncthreads();
    for (int b = tid; b < NBMAX; b += 256) {
        int h = hist[b];
        if (h > 0) base[b] = bptr[b] + atomicAdd(&gcnt[b], h);
    }
    __syncthreads();
    for (int t = tid; t < cnt; t += 256) {
        int p = atomicAdd(&base[ebkt[t]], 1);
        stage[p] = ebuf[t];
    }
}

// pass 2: one block per bucket. Degrees + row_ptr + dinv + rank-scatter CSR, all in LDS.
__launch_bounds__(256)
__global__ void k_csr(const unsigned* __restrict__ stage, const int* __restrict__ bptr,
                      int* __restrict__ csr_src, int* __restrict__ row_ptr,
                      float* __restrict__ dinv, int n, int e) {
    __shared__ int cntl[256];   // per-node count, then rank pos
    __shared__ int sc[256];     // inclusive scan
    __shared__ int excl[256];   // exclusive offsets (persist)
    __shared__ int cbuf[CSRCAP];
    int b = blockIdx.x;
    int lo = b << 8;
    int nn = min(n - lo, 256);
    int tid = threadIdx.x;
    int s0 = bptr[b], s1 = bptr[b + 1];
    int cntB = s1 - s0;

    cntl[tid] = 0;
    __syncthreads();
    for (int t = tid; t < cntB; t += 256) {
        int dl = (int)(stage[s0 + t] >> 24);
        atomicAdd(&cntl[dl], 1);
    }
    __syncthreads();
    int deg = (tid < nn) ? cntl[tid] : 0;
    sc[tid] = deg; __syncthreads();
    for (int o = 1; o < 256; o <<= 1) {
        int t = (tid >= o) ? sc[tid - o] : 0;
        __syncthreads();
        sc[tid] += t;
        __syncthreads();
    }
    excl[tid] = sc[tid] - deg;
    if (tid < nn) {
        row_ptr[lo + tid] = s0 + excl[tid];
        dinv[lo + tid] = rsqrtf((float)(deg + 1));
    }
    if (b == 0 && tid == 0) row_ptr[n] = e;
    cntl[tid] = 0;
    __syncthreads();
    for (int t = tid; t < cntB; t += 256) {
        unsigned ed = stage[s0 + t];
        int dl = (int)(ed >> 24);
        int r = atomicAdd(&cntl[dl], 1);
        int p = excl[dl] + r;
        if (p < CSRCAP) cbuf[p] = (int)(ed & 0x00ffffffu);
        else csr_src[s0 + p] = (int)(ed & 0x00ffffffu);   // overflow fallback
    }
    __syncthreads();
    int lim = min(cntB, CSRCAP);
    for (int t = tid; t < lim; t += 256) csr_src[s0 + t] = cbuf[t];
}

// ---------------- fp32 -> bf16x2 pack, pre-scaled by dinv[row] ----------------

__global__ void k_f2bs(const float* __restrict__ in, const float* __restrict__ dinv,
                       unsigned* __restrict__ out, int nu) {
    int i = blockIdx.x * blockDim.x + threadIdx.x;
    if (i < nu) {
        float2 v = ((const float2*)in)[i];
        float d = dinv[i >> 5];          // 32 uints per 64-feature row
        out[i] = pack2(v.x * d, v.y * d);
    }
}

// ---------------- Aggregation: out[d] = dinv[d] * (x'[d] + sum x'[s]) ----------------

// x': [N][64] bf16 = uint4[N][8]. 8 lanes/edge, 8 edge-groups, unroll 2.
__global__ void k_agg64b(const uint4* __restrict__ x4, const float* __restrict__ dinv,
                         const int* __restrict__ row_ptr, const int* __restrict__ csr_src,
                         uint4* __restrict__ out4, int n) {
    int lane = threadIdx.x & 63;
    int g = lane >> 3, c = lane & 7;
    int wid = (blockIdx.x * blockDim.x + threadIdx.x) >> 6;
    int nw = (gridDim.x * blockDim.x) >> 6;
    for (int i = wid; i < n; i += nw) {
        float a[8] = {0.f, 0.f, 0.f, 0.f, 0.f, 0.f, 0.f, 0.f};
        if (g == 0) {
            uint4 su = x4[(size_t)i * 8 + c];
            add8(a, su);
        }
        int j0 = row_ptr[i], j1 = row_ptr[i + 1];
        int j = j0 + g;
        for (; j + 8 < j1; j += 16) {
            int s0 = csr_src[j], s1 = csr_src[j + 8];
            uint4 u0 = x4[(size_t)s0 * 8 + c];
            uint4 u1 = x4[(size_t)s1 * 8 + c];
            add8(a, u0);
            add8(a, u1);
        }
        if (j < j1) {
            int s0 = csr_src[j];
            uint4 u0 = x4[(size_t)s0 * 8 + c];
            add8(a, u0);
        }
        #pragma unroll
        for (int k = 0; k < 8; ++k) {
            a[k] += __shfl_xor(a[k], 8);
            a[k] += __shfl_xor(a[k], 16);
            a[k] += __shfl_xor(a[k], 32);
        }
        if (g == 0) {
            float di = dinv[i];
            uint4 o;
            o.x = pack2(a[0] * di, a[1] * di);
            o.y = pack2(a[2] * di, a[3] * di);
            o.z = pack2(a[4] * di, a[5] * di);
            o.w = pack2(a[6] * di, a[7] * di);
            out4[(size_t)i * 8 + c] = o;
        }
    }
}

// h': [N][128] bf16 = uint4[N][16]. 16 lanes/edge, 4 edge-groups, unroll 4.
__global__ void k_agg128b(const uint4* __restrict__ h4, const float* __restrict__ dinv,
                          const int* __restrict__ row_ptr, const int* __restrict__ csr_src,
                          uint4* __restrict__ out4, int n) {
    int lane = threadIdx.x & 63;
    int q = lane >> 4, c = lane & 15;
    int wid = (blockIdx.x * blockDim.x + threadIdx.x) >> 6;
    int nw = (gridDim.x * blockDim.x) >> 6;
    for (int i = wid; i < n; i += nw) {
        float a[8] = {0.f, 0.f, 0.f, 0.f, 0.f, 0.f, 0.f, 0.f};
        if (q == 0) {
            uint4 su = h4[(size_t)i * 16 + c];
            add8(a, su);
        }
        int j0 = row_ptr[i], j1 = row_ptr[i + 1];
        int j = j0 + q;
        for (; j + 12 < j1; j += 16) {
            int s0 = csr_src[j], s1 = csr_src[j + 4];
            int s2 = csr_src[j + 8], s3 = csr_src[j + 12];
            uint4 u0 = h4[(size_t)s0 * 16 + c];
            uint4 u1 = h4[(size_t)s1 * 16 + c];
            uint4 u2 = h4[(size_t)s2 * 16 + c];
            uint4 u3 = h4[(size_t)s3 * 16 + c];
            add8(a, u0);
            add8(a, u1);
            add8(a, u2);
            add8(a, u3);
        }
        for (; j < j1; j += 4) {
            int s0 = csr_src[j];
            uint4 u0 = h4[(size_t)s0 * 16 + c];
            add8(a, u0);
        }
        #pragma unroll
        for (int k = 0; k < 8; ++k) {
            a[k] += __shfl_xor(a[k], 16);
            a[k] += __shfl_xor(a[k], 32);
        }
        if (q == 0) {
            float di = dinv[i];
            uint4 o;
            o.x = pack2(a[0] * di, a[1] * di);
            o.y = pack2(a[2] * di, a[3] * di);
            o.z = pack2(a[4] * di, a[5] * di);
            o.w = pack2(a[6] * di, a[7] * di);
            out4[(size_t)i * 16 + c] = o;
        }
    }
}

// ---------------- MFMA GEMM + LN (+ReLU) fused ----------------
// mfma_f32_16x16x32_bf16. A/B frag: k = (lane>>4)*8 + j. C/D: col=lane&15, row=(lane>>4)*4+reg.

// agg[N][64] bf16 @ W1[64][128] -> LN -> relu -> *dinv[row] -> hb[N][128] bf16
__launch_bounds__(256)
__global__ void k_mm1(const unsigned* __restrict__ aggb, const float* __restrict__ W1,
                      const float* __restrict__ b1, const float* __restrict__ g1,
                      const float* __restrict__ be1, const float* __restrict__ dinv,
                      unsigned short* __restrict__ hbs, int ntiles) {
    int lane = threadIdx.x & 63;
    int wv = threadIdx.x >> 6;
    int wpb = blockDim.x >> 6;
    int lc = lane & 15, lg = lane >> 4;

    short8v B[2][8];
    #pragma unroll
    for (int ks = 0; ks < 2; ++ks)
        #pragma unroll
        for (int cb = 0; cb < 8; ++cb) {
            short8v f;
            #pragma unroll
            for (int j = 0; j < 8; ++j) {
                int k = ks * 32 + lg * 8 + j;
                f[j] = (short)f2bf(W1[k * 128 + cb * 16 + lc]);
            }
            B[ks][cb] = f;
        }
    float bs[8], gm[8], bt[8];
    #pragma unroll
    for (int cb = 0; cb < 8; ++cb) {
        bs[cb] = b1[cb * 16 + lc];
        gm[cb] = g1[cb * 16 + lc];
        bt[cb] = be1[cb * 16 + lc];
    }

    for (int t = blockIdx.x * wpb + wv; t < ntiles; t += gridDim.x * wpb) {
        size_t arow = (size_t)(t * 16 + lc) * 32;
        U4S8 a0, a1;
        a0.u = *(const uint4*)&aggb[arow + lg * 4];
        a1.u = *(const uint4*)&aggb[arow + 16 + lg * 4];
        float4v acc[8];
        #pragma unroll
        for (int cb = 0; cb < 8; ++cb) acc[cb] = (float4v){0.f, 0.f, 0.f, 0.f};
        #pragma unroll
        for (int cb = 0; cb < 8; ++cb) {
            acc[cb] = __builtin_amdgcn_mfma_f32_16x16x32_bf16(a0.s, B[0][cb], acc[cb], 0, 0, 0);
            acc[cb] = __builtin_amdgcn_mfma_f32_16x16x32_bf16(a1.s, B[1][cb], acc[cb], 0, 0, 0);
        }
        #pragma unroll
        for (int reg = 0; reg < 4; ++reg) {
            float s = 0.f, q = 0.f;
            #pragma unroll
            for (int cb = 0; cb < 8; ++cb) {
                float v = acc[cb][reg] + bs[cb];
                acc[cb][reg] = v;
                s += v; q = fmaf(v, v, q);
            }
            s += __shfl_xor(s, 1); q += __shfl_xor(q, 1);
            s += __shfl_xor(s, 2); q += __shfl_xor(q, 2);
            s += __shfl_xor(s, 4); q += __shfl_xor(q, 4);
            s += __shfl_xor(s, 8); q += __shfl_xor(q, 8);
            float mu = s * (1.f / 128.f);
            float var = fmaf(q, 1.f / 128.f, -mu * mu);
            float rstd = rsqrtf(var + LN_EPS);
            int rowi = t * 16 + lg * 4 + reg;
            float di = dinv[rowi];
            size_t row = (size_t)rowi * 128;
            #pragma unroll
            for (int cb = 0; cb < 8; ++cb) {
                float o = fmaf((acc[cb][reg] - mu) * rstd, gm[cb], bt[cb]);
                hbs[row + cb * 16 + lc] = f2bf(fmaxf(o, 0.f) * di);
            }
        }
    }
}

// agg2[N][128] bf16 @ W2[128][128] -> LN -> pooled atomicAdd into psum[G][128]
__launch_bounds__(256)
__global__ void k_mm2p(const unsigned* __restrict__ aggb, const float* __restrict__ W2,
                       const float* __restrict__ b2, const float* __restrict__ g2,
                       const float* __restrict__ be2, const int* __restrict__ batch,
                       float* __restrict__ psum, int ntiles) {
    __shared__ uint4 sB[4 * 8 * 64];   // 32 KiB
    for (int idx = threadIdx.x; idx < 2048; idx += blockDim.x) {
        int l = idx & 63;
        int f = idx >> 6;
        int ks = f >> 3, cb = f & 7;
        int kb = ks * 32 + (l >> 4) * 8;
        int col = cb * 16 + (l & 15);
        float p[8];
        #pragma unroll
        for (int j = 0; j < 8; ++j) p[j] = W2[(kb + j) * 128 + col];
        uint4 v;
        v.x = pack2(p[0], p[1]); v.y = pack2(p[2], p[3]);
        v.z = pack2(p[4], p[5]); v.w = pack2(p[6], p[7]);
        sB[idx] = v;
    }
    __syncthreads();

    int lane = threadIdx.x & 63;
    int wv = threadIdx.x >> 6;
    int wpb = blockDim.x >> 6;
    int lc = lane & 15, lg = lane >> 4;
    float bs[8], gm[8], bt[8];
    #pragma unroll
    for (int cb = 0; cb < 8; ++cb) {
        bs[cb] = b2[cb * 16 + lc];
        gm[cb] = g2[cb * 16 + lc];
        bt[cb] = be2[cb * 16 + lc];
    }

    for (int t = blockIdx.x * wpb + wv; t < ntiles; t += gridDim.x * wpb) {
        int row0 = t * 16;
        size_t arow = (size_t)(row0 + lc) * 64;
        U4S8 a[4];
        #pragma unroll
        for (int ks = 0; ks < 4; ++ks)
            a[ks].u = *(const uint4*)&aggb[arow + ks * 16 + lg * 4];
        float4v acc[8];
        #pragma unroll
        for (int cb = 0; cb < 8; ++cb) acc[cb] = (float4v){0.f, 0.f, 0.f, 0.f};
        #pragma unroll
        for (int ks = 0; ks < 4; ++ks) {
            #pragma unroll
            for (int cb = 0; cb < 8; ++cb) {
                U4S8 fb;
                fb.u = sB[(ks * 8 + cb) * 64 + lane];
                acc[cb] = __builtin_amdgcn_mfma_f32_16x16x32_bf16(a[ks].s, fb.s, acc[cb], 0, 0, 0);
            }
        }
        #pragma unroll
        for (int reg = 0; reg < 4; ++reg) {
            float s = 0.f, q = 0.f;
            #pragma unroll
            for (int cb = 0; cb < 8; ++cb) {
                float v = acc[cb][reg] + bs[cb];
                acc[cb][reg] = v;
                s += v; q = fmaf(v, v, q);
            }
            s += __shfl_xor(s, 1); q += __shfl_xor(q, 1);
            s += __shfl_xor(s, 2); q += __shfl_xor(q, 2);
            s += __shfl_xor(s, 4); q += __shfl_xor(q, 4);
            s += __shfl_xor(s, 8); q += __shfl_xor(q, 8);
            float mu = s * (1.f / 128.f);
            float var = fmaf(q, 1.f / 128.f, -mu * mu);
            float rstd = rsqrtf(var + LN_EPS);
            #pragma unroll
            for (int cb = 0; cb < 8; ++cb)
                acc[cb][reg] = fmaf((acc[cb][reg] - mu) * rstd, gm[cb], bt[cb]);
        }
        int gmin = batch[row0];
        int gmax = batch[row0 + 15];
        int rg[4];
        #pragma unroll
        for (int reg = 0; reg < 4; ++reg) rg[reg] = batch[row0 + lg * 4 + reg];
        for (int g = gmin; g <= gmax; ++g) {
            #pragma unroll
            for (int cb = 0; cb < 8; ++cb) {
                float s = 0.f;
                #pragma unroll
                for (int reg = 0; reg < 4; ++reg)
                    s += (rg[reg] == g) ? acc[cb][reg] : 0.f;
                s += __shfl_xor(s, 16);
                s += __shfl_xor(s, 32);
                if (lg == 0) atomicAdd(&psum[g * 128 + cb * 16 + lc], s);
            }
        }
    }
}

// ---------------- divide by graph sizes ----------------

__device__ __forceinline__ int lowerb(const int* __restrict__ b, int n, int key) {
    int lo = 0, hi = n;
    while (lo < hi) {
        int m = (lo + hi) >> 1;
        if (b[m] < key) lo = m + 1; else hi = m;
    }
    return lo;
}

__global__ void k_div(float* __restrict__ out, const int* __restrict__ batch,
                      int n, int total) {
    int idx = blockIdx.x * blockDim.x + threadIdx.x;
    if (idx < total) {
        int g = idx >> 7;
        int start = lowerb(batch, n, g);
        int end   = lowerb(batch, n, g + 1);
        out[idx] /= fmaxf((float)(end - start), 1.f);
    }
}

// ---------------- launch ----------------

extern "C" void kernel_launch(void* const* d_in, const int* in_sizes, int n_in,
                              void* d_out, int out_size, void* d_ws, size_t ws_size,
                              hipStream_t stream) {
    const float* x   = (const float*)d_in[0];
    const int*   ei  = (const int*)d_in[1];
    const int*   bat = (const int*)d_in[2];
    const float* W1  = (const float*)d_in[3];
    const float* b1  = (const float*)d_in[4];
    const float* g1  = (const float*)d_in[5];
    const float* be1 = (const float*)d_in[6];
    const float* W2  = (const float*)d_in[7];
    const float* b2  = (const float*)d_in[8];
    const float* g2  = (const float*)d_in[9];
    const float* be2 = (const float*)d_in[10];

    int n = in_sizes[0] / 64;     // 100000
    int e = in_sizes[1] / 2;      // 1600000
    const int* src = ei;
    const int* dst = ei + e;

    char* ws = (char*)d_ws;
    size_t off = 0;
    auto take = [&](size_t bytes) -> void* {
        void* p = ws + off;
        off = (off + bytes + 255) & ~(size_t)255;
        return p;
    };
    float*    dinv    = (float*)   take((size_t)n * 4);
    int*      row_ptr = (int*)     take((size_t)(n + 1) * 4);
    int*      bcnt    = (int*)     take(NBMAX * 4);
    int*      bptr    = (int*)     take((NBMAX + 1) * 4);
    int*      gcnt    = (int*)     take(NBMAX * 4);
    unsigned* stage   = (unsigned*)take((size_t)e * 4);
    int*      csr_src = (int*)     take((size_t)e * 4);
    unsigned* xb      = (unsigned*)take((size_t)n * 64 * 2);
    unsigned* aggb    = (unsigned*)take((size_t)n * 64 * 2);
    unsigned* hb      = (unsigned*)take((size_t)n * 128 * 2);
    unsigned* agg2b   = (unsigned*)take((size_t)n * 128 * 2);

    hipMemsetAsync(bcnt, 0, NBMAX * 4, stream);
    hipMemsetAsync(gcnt, 0, NBMAX * 4, stream);
    hipMemsetAsync(d_out, 0, (size_t)out_size * 4, stream);

    int nbk = (e + CHUNK - 1) / CHUNK;
    k_bcnt<<<nbk, 256, 0, stream>>>(dst, e, bcnt);
    k_bscan<<<1, NBMAX, 0, stream>>>(bcnt, bptr);
    k_bucket<<<nbk, 256, 0, stream>>>(src, dst, e, bptr, gcnt, stage);
    int nbuckets = (n + 255) / 256;
    k_csr<<<nbuckets, 256, 0, stream>>>(stage, bptr, csr_src, row_ptr, dinv, n, e);

    int nux = n * 32;
    k_f2bs<<<(nux + 255) / 256, 256, 0, stream>>>(x, dinv, xb, nux);

    k_agg64b<<<2048, 256, 0, stream>>>((const uint4*)xb, dinv, row_ptr, csr_src,
                                       (uint4*)aggb, n);

    int ntiles = n / 16;  // 6250
    int mmblocks = (ntiles + 3) / 4;
    k_mm1<<<mmblocks, 256, 0, stream>>>(aggb, W1, b1, g1, be1, dinv,
                                        (unsigned short*)hb, ntiles);

    k_agg128b<<<2048, 256, 0, stream>>>((const uint4*)hb, dinv, row_ptr, csr_src,
                                        (uint4*)agg2b, n);

    k_mm2p<<<mmblocks, 256, 0, stream>>>(agg2b, W2, b2, g2, be2, bat, (float*)d_out, ntiles);

    int total = out_size;
    k_div<<<(total + 255) / 256, 256, 0, stream>>>((float*)d_out, bat, n, total);
}

// Round 8
// 222.986 us; speedup vs baseline: 5.1110x; 1.0170x over previous
//
#include <hip/hip_runtime.h>
#include <hip/hip_bf16.h>

#define LN_EPS 1e-5f

typedef __attribute__((ext_vector_type(8))) short short8v;
typedef __attribute__((ext_vector_type(4))) float float4v;

__device__ __forceinline__ float bflo(unsigned u) { return __uint_as_float(u << 16); }
__device__ __forceinline__ float bfhi(unsigned u) { return __uint_as_float(u & 0xffff0000u); }
__device__ __forceinline__ unsigned short f2bf(float f) {
    __hip_bfloat16 b = __float2bfloat16(f);
    return *reinterpret_cast<unsigned short*>(&b);
}
__device__ __forceinline__ unsigned pack2(float x, float y) {
    __hip_bfloat162 t = __float22bfloat162_rn(make_float2(x, y));
    return *reinterpret_cast<unsigned*>(&t);
}
__device__ __forceinline__ void add8(float* a, uint4 u) {
    a[0] += bflo(u.x); a[1] += bfhi(u.x);
    a[2] += bflo(u.y); a[3] += bfhi(u.y);
    a[4] += bflo(u.z); a[5] += bfhi(u.z);
    a[6] += bflo(u.w); a[7] += bfhi(u.w);
}

union U4S8 { uint4 u; short8v s; };

// ---------------- bucketed CSR build, fixed-capacity regions ----------------
// bucket b = dst >> 8 (256 nodes/bucket). Region b = [b*BCAP, b*BCAP+cnt_b).
// stage entry: src | (dst&0xff)<<24  (src < 2^24)

#define CHUNK 4096
#define NBMAX 512
#define BCAP 5120      // mean 4096, sigma ~64 -> +16 sigma
#define CSRCAP 8192

// pass 1: stage packed (src|dstlow<<24) into fixed bucket regions
__launch_bounds__(256)
__global__ void k_bucket(const int* __restrict__ src, const int* __restrict__ dst, int e,
                         int* __restrict__ gcnt, unsigned* __restrict__ stage) {
    __shared__ unsigned ebuf[CHUNK];
    __shared__ unsigned short ebkt[CHUNK];
    __shared__ int hist[NBMAX];
    __shared__ int base[NBMAX];
    int tid = threadIdx.x;
    int c0 = blockIdx.x * CHUNK;
    if (c0 >= e) return;
    int cnt = min(CHUNK, e - c0);

    for (int t = tid; t < NBMAX; t += 256) hist[t] = 0;
    __syncthreads();
    for (int t = tid; t < cnt; t += 256) {
        unsigned s = (unsigned)src[c0 + t];
        unsigned d = (unsigned)dst[c0 + t];
        ebuf[t] = s | ((d & 0xffu) << 24);
        ebkt[t] = (unsigned short)(d >> 8);
        atomicAdd(&hist[d >> 8], 1);
    }
    __syncthreads();
    for (int b = tid; b < NBMAX; b += 256) {
        int h = hist[b];
        if (h > 0) base[b] = b * BCAP + atomicAdd(&gcnt[b], h);
    }
    __syncthreads();
    for (int t = tid; t < cnt; t += 256) {
        int p = atomicAdd(&base[ebkt[t]], 1);
        stage[p] = ebuf[t];
    }
}

// pass 2: one block per bucket. Degrees -> row_start/row_end/dinv, rank-scatter
// CSR via LDS, coalesced write-out, AND pack x -> xb (pre-scaled by dinv).
__launch_bounds__(256)
__global__ void k_csr(const unsigned* __restrict__ stage, const int* __restrict__ gcnt,
                      int* __restrict__ csr_src, int* __restrict__ row_start,
                      int* __restrict__ row_end, float* __restrict__ dinv,
                      const float* __restrict__ x, unsigned* __restrict__ xb, int n) {
    __shared__ int cntl[256];
    __shared__ int sc[256];
    __shared__ int excl[256];
    __shared__ float dfl[256];
    __shared__ int cbuf[CSRCAP];
    int b = blockIdx.x;
    int lo = b << 8;
    int nn = min(n - lo, 256);
    int tid = threadIdx.x;
    int s0 = b * BCAP;
    int cntB = gcnt[b];

    cntl[tid] = 0;
    __syncthreads();
    for (int t = tid; t < cntB; t += 256) {
        int dl = (int)(stage[s0 + t] >> 24);
        atomicAdd(&cntl[dl], 1);
    }
    __syncthreads();
    int deg = (tid < nn) ? cntl[tid] : 0;
    sc[tid] = deg; __syncthreads();
    for (int o = 1; o < 256; o <<= 1) {
        int t = (tid >= o) ? sc[tid - o] : 0;
        __syncthreads();
        sc[tid] += t;
        __syncthreads();
    }
    excl[tid] = sc[tid] - deg;
    float dv = rsqrtf((float)(deg + 1));
    dfl[tid] = dv;
    if (tid < nn) {
        row_start[lo + tid] = s0 + excl[tid];
        row_end[lo + tid]   = s0 + excl[tid] + deg;
        dinv[lo + tid] = dv;
    }
    cntl[tid] = 0;
    __syncthreads();
    for (int t = tid; t < cntB; t += 256) {
        unsigned ed = stage[s0 + t];
        int dl = (int)(ed >> 24);
        int r = atomicAdd(&cntl[dl], 1);
        int p = excl[dl] + r;
        if (p < CSRCAP) cbuf[p] = (int)(ed & 0x00ffffffu);
        else csr_src[s0 + p] = (int)(ed & 0x00ffffffu);
    }
    __syncthreads();
    int lim = min(cntB, CSRCAP);
    for (int t = tid; t < lim; t += 256) csr_src[s0 + t] = cbuf[t];

    // pack x rows [lo, lo+nn) -> xb, scaled by dinv (bf16x2 per uint)
    const float2* x2 = (const float2*)x;
    for (int idx = tid; idx < nn * 32; idx += 256) {
        int node = idx >> 5, c = idx & 31;
        size_t p = ((size_t)(lo + node) << 5) + c;
        float2 v = x2[p];
        float d = dfl[node];
        xb[p] = pack2(v.x * d, v.y * d);
    }
}

// ---------------- Aggregation: out[d] = dinv[d] * (x'[d] + sum x'[s]) ----------------

// x': [N][64] bf16 = uint4[N][8]. 8 lanes/edge, 8 edge-groups, unroll 2.
__global__ void k_agg64b(const uint4* __restrict__ x4, const float* __restrict__ dinv,
                         const int* __restrict__ row_start, const int* __restrict__ row_end,
                         const int* __restrict__ csr_src, uint4* __restrict__ out4, int n) {
    int lane = threadIdx.x & 63;
    int g = lane >> 3, c = lane & 7;
    int wid = (blockIdx.x * blockDim.x + threadIdx.x) >> 6;
    int nw = (gridDim.x * blockDim.x) >> 6;
    for (int i = wid; i < n; i += nw) {
        float a[8] = {0.f, 0.f, 0.f, 0.f, 0.f, 0.f, 0.f, 0.f};
        if (g == 0) {
            uint4 su = x4[(size_t)i * 8 + c];
            add8(a, su);
        }
        int j0 = row_start[i], j1 = row_end[i];
        int j = j0 + g;
        for (; j + 8 < j1; j += 16) {
            int s0 = csr_src[j], s1 = csr_src[j + 8];
            uint4 u0 = x4[(size_t)s0 * 8 + c];
            uint4 u1 = x4[(size_t)s1 * 8 + c];
            add8(a, u0);
            add8(a, u1);
        }
        if (j < j1) {
            int s0 = csr_src[j];
            uint4 u0 = x4[(size_t)s0 * 8 + c];
            add8(a, u0);
        }
        #pragma unroll
        for (int k = 0; k < 8; ++k) {
            a[k] += __shfl_xor(a[k], 8);
            a[k] += __shfl_xor(a[k], 16);
            a[k] += __shfl_xor(a[k], 32);
        }
        if (g == 0) {
            float di = dinv[i];
            uint4 o;
            o.x = pack2(a[0] * di, a[1] * di);
            o.y = pack2(a[2] * di, a[3] * di);
            o.z = pack2(a[4] * di, a[5] * di);
            o.w = pack2(a[6] * di, a[7] * di);
            out4[(size_t)i * 8 + c] = o;
        }
    }
}

// h': [N][128] bf16 = uint4[N][16]. 16 lanes/edge, 4 edge-groups, unroll 4.
__global__ void k_agg128b(const uint4* __restrict__ h4, const float* __restrict__ dinv,
                          const int* __restrict__ row_start, const int* __restrict__ row_end,
                          const int* __restrict__ csr_src, uint4* __restrict__ out4, int n) {
    int lane = threadIdx.x & 63;
    int q = lane >> 4, c = lane & 15;
    int wid = (blockIdx.x * blockDim.x + threadIdx.x) >> 6;
    int nw = (gridDim.x * blockDim.x) >> 6;
    for (int i = wid; i < n; i += nw) {
        float a[8] = {0.f, 0.f, 0.f, 0.f, 0.f, 0.f, 0.f, 0.f};
        if (q == 0) {
            uint4 su = h4[(size_t)i * 16 + c];
            add8(a, su);
        }
        int j0 = row_start[i], j1 = row_end[i];
        int j = j0 + q;
        for (; j + 12 < j1; j += 16) {
            int s0 = csr_src[j], s1 = csr_src[j + 4];
            int s2 = csr_src[j + 8], s3 = csr_src[j + 12];
            uint4 u0 = h4[(size_t)s0 * 16 + c];
            uint4 u1 = h4[(size_t)s1 * 16 + c];
            uint4 u2 = h4[(size_t)s2 * 16 + c];
            uint4 u3 = h4[(size_t)s3 * 16 + c];
            add8(a, u0);
            add8(a, u1);
            add8(a, u2);
            add8(a, u3);
        }
        for (; j < j1; j += 4) {
            int s0 = csr_src[j];
            uint4 u0 = h4[(size_t)s0 * 16 + c];
            add8(a, u0);
        }
        #pragma unroll
        for (int k = 0; k < 8; ++k) {
            a[k] += __shfl_xor(a[k], 16);
            a[k] += __shfl_xor(a[k], 32);
        }
        if (q == 0) {
            float di = dinv[i];
            uint4 o;
            o.x = pack2(a[0] * di, a[1] * di);
            o.y = pack2(a[2] * di, a[3] * di);
            o.z = pack2(a[4] * di, a[5] * di);
            o.w = pack2(a[6] * di, a[7] * di);
            out4[(size_t)i * 16 + c] = o;
        }
    }
}

// ---------------- MFMA GEMM + LN (+ReLU) fused ----------------
// mfma_f32_16x16x32_bf16. A/B frag: k = (lane>>4)*8 + j. C/D: col=lane&15, row=(lane>>4)*4+reg.

// agg[N][64] bf16 @ W1[64][128] -> LN -> relu -> *dinv[row] -> hb[N][128] bf16
__launch_bounds__(256)
__global__ void k_mm1(const unsigned* __restrict__ aggb, const float* __restrict__ W1,
                      const float* __restrict__ b1, const float* __restrict__ g1,
                      const float* __restrict__ be1, const float* __restrict__ dinv,
                      unsigned short* __restrict__ hbs, int ntiles) {
    int lane = threadIdx.x & 63;
    int wv = threadIdx.x >> 6;
    int wpb = blockDim.x >> 6;
    int lc = lane & 15, lg = lane >> 4;

    short8v B[2][8];
    #pragma unroll
    for (int ks = 0; ks < 2; ++ks)
        #pragma unroll
        for (int cb = 0; cb < 8; ++cb) {
            short8v f;
            #pragma unroll
            for (int j = 0; j < 8; ++j) {
                int k = ks * 32 + lg * 8 + j;
                f[j] = (short)f2bf(W1[k * 128 + cb * 16 + lc]);
            }
            B[ks][cb] = f;
        }
    float bs[8], gm[8], bt[8];
    #pragma unroll
    for (int cb = 0; cb < 8; ++cb) {
        bs[cb] = b1[cb * 16 + lc];
        gm[cb] = g1[cb * 16 + lc];
        bt[cb] = be1[cb * 16 + lc];
    }

    for (int t = blockIdx.x * wpb + wv; t < ntiles; t += gridDim.x * wpb) {
        size_t arow = (size_t)(t * 16 + lc) * 32;
        U4S8 a0, a1;
        a0.u = *(const uint4*)&aggb[arow + lg * 4];
        a1.u = *(const uint4*)&aggb[arow + 16 + lg * 4];
        float4v acc[8];
        #pragma unroll
        for (int cb = 0; cb < 8; ++cb) acc[cb] = (float4v){0.f, 0.f, 0.f, 0.f};
        #pragma unroll
        for (int cb = 0; cb < 8; ++cb) {
            acc[cb] = __builtin_amdgcn_mfma_f32_16x16x32_bf16(a0.s, B[0][cb], acc[cb], 0, 0, 0);
            acc[cb] = __builtin_amdgcn_mfma_f32_16x16x32_bf16(a1.s, B[1][cb], acc[cb], 0, 0, 0);
        }
        #pragma unroll
        for (int reg = 0; reg < 4; ++reg) {
            float s = 0.f, q = 0.f;
            #pragma unroll
            for (int cb = 0; cb < 8; ++cb) {
                float v = acc[cb][reg] + bs[cb];
                acc[cb][reg] = v;
                s += v; q = fmaf(v, v, q);
            }
            s += __shfl_xor(s, 1); q += __shfl_xor(q, 1);
            s += __shfl_xor(s, 2); q += __shfl_xor(q, 2);
            s += __shfl_xor(s, 4); q += __shfl_xor(q, 4);
            s += __shfl_xor(s, 8); q += __shfl_xor(q, 8);
            float mu = s * (1.f / 128.f);
            float var = fmaf(q, 1.f / 128.f, -mu * mu);
            float rstd = rsqrtf(var + LN_EPS);
            int rowi = t * 16 + lg * 4 + reg;
            float di = dinv[rowi];
            size_t row = (size_t)rowi * 128;
            #pragma unroll
            for (int cb = 0; cb < 8; ++cb) {
                float o = fmaf((acc[cb][reg] - mu) * rstd, gm[cb], bt[cb]);
                hbs[row + cb * 16 + lc] = f2bf(fmaxf(o, 0.f) * di);
            }
        }
    }
}

// agg2[N][128] bf16 @ W2[128][128] -> LN -> scaled pooled atomicAdd into out[G][128]
__launch_bounds__(256)
__global__ void k_mm2p(const unsigned* __restrict__ aggb, const float* __restrict__ W2,
                       const float* __restrict__ b2, const float* __restrict__ g2,
                       const float* __restrict__ be2, const int* __restrict__ batch,
                       float* __restrict__ psum, int ntiles, int n) {
    __shared__ uint4 sB[4 * 8 * 64];   // 32 KiB
    for (int idx = threadIdx.x; idx < 2048; idx += blockDim.x) {
        int l = idx & 63;
        int f = idx >> 6;
        int ks = f >> 3, cb = f & 7;
        int kb = ks * 32 + (l >> 4) * 8;
        int col = cb * 16 + (l & 15);
        float p[8];
        #pragma unroll
        for (int j = 0; j < 8; ++j) p[j] = W2[(kb + j) * 128 + col];
        uint4 v;
        v.x = pack2(p[0], p[1]); v.y = pack2(p[2], p[3]);
        v.z = pack2(p[4], p[5]); v.w = pack2(p[6], p[7]);
        sB[idx] = v;
    }
    __syncthreads();

    int lane = threadIdx.x & 63;
    int wv = threadIdx.x >> 6;
    int wpb = blockDim.x >> 6;
    int lc = lane & 15, lg = lane >> 4;
    float bs[8], gm[8], bt[8];
    #pragma unroll
    for (int cb = 0; cb < 8; ++cb) {
        bs[cb] = b2[cb * 16 + lc];
        gm[cb] = g2[cb * 16 + lc];
        bt[cb] = be2[cb * 16 + lc];
    }

    for (int t = blockIdx.x * wpb + wv; t < ntiles; t += gridDim.x * wpb) {
        int row0 = t * 16;
        size_t arow = (size_t)(row0 + lc) * 64;
        U4S8 a[4];
        #pragma unroll
        for (int ks = 0; ks < 4; ++ks)
            a[ks].u = *(const uint4*)&aggb[arow + ks * 16 + lg * 4];
        float4v acc[8];
        #pragma unroll
        for (int cb = 0; cb < 8; ++cb) acc[cb] = (float4v){0.f, 0.f, 0.f, 0.f};
        #pragma unroll
        for (int ks = 0; ks < 4; ++ks) {
            #pragma unroll
            for (int cb = 0; cb < 8; ++cb) {
                U4S8 fb;
                fb.u = sB[(ks * 8 + cb) * 64 + lane];
                acc[cb] = __builtin_amdgcn_mfma_f32_16x16x32_bf16(a[ks].s, fb.s, acc[cb], 0, 0, 0);
            }
        }
        #pragma unroll
        for (int reg = 0; reg < 4; ++reg) {
            float s = 0.f, q = 0.f;
            #pragma unroll
            for (int cb = 0; cb < 8; ++cb) {
                float v = acc[cb][reg] + bs[cb];
                acc[cb][reg] = v;
                s += v; q = fmaf(v, v, q);
            }
            s += __shfl_xor(s, 1); q += __shfl_xor(q, 1);
            s += __shfl_xor(s, 2); q += __shfl_xor(q, 2);
            s += __shfl_xor(s, 4); q += __shfl_xor(q, 4);
            s += __shfl_xor(s, 8); q += __shfl_xor(q, 8);
            float mu = s * (1.f / 128.f);
            float var = fmaf(q, 1.f / 128.f, -mu * mu);
            float rstd = rsqrtf(var + LN_EPS);
            #pragma unroll
            for (int cb = 0; cb < 8; ++cb)
                acc[cb][reg] = fmaf((acc[cb][reg] - mu) * rstd, gm[cb], bt[cb]);
        }
        int gmin = batch[row0];
        int gmax = batch[row0 + 15];
        int rg[4];
        #pragma unroll
        for (int reg = 0; reg < 4; ++reg) rg[reg] = batch[row0 + lg * 4 + reg];
        for (int g = gmin; g <= gmax; ++g) {
            // per-graph count via binary search (uniform across lanes)
            int lo = 0, hi = n;
            while (lo < hi) { int m = (lo + hi) >> 1; if (batch[m] < g) lo = m + 1; else hi = m; }
            int st = lo;
            hi = n;
            while (lo < hi) { int m = (lo + hi) >> 1; if (batch[m] < g + 1) lo = m + 1; else hi = m; }
            float rc = 1.f / fmaxf((float)(lo - st), 1.f);
            #pragma unroll
            for (int cb = 0; cb < 8; ++cb) {
                float s = 0.f;
                #pragma unroll
                for (int reg = 0; reg < 4; ++reg)
                    s += (rg[reg] == g) ? acc[cb][reg] : 0.f;
                s += __shfl_xor(s, 16);
                s += __shfl_xor(s, 32);
                if (lg == 0) atomicAdd(&psum[g * 128 + cb * 16 + lc], s * rc);
            }
        }
    }
}

// ---------------- launch ----------------

extern "C" void kernel_launch(void* const* d_in, const int* in_sizes, int n_in,
                              void* d_out, int out_size, void* d_ws, size_t ws_size,
                              hipStream_t stream) {
    const float* x   = (const float*)d_in[0];
    const int*   ei  = (const int*)d_in[1];
    const int*   bat = (const int*)d_in[2];
    const float* W1  = (const float*)d_in[3];
    const float* b1  = (const float*)d_in[4];
    const float* g1  = (const float*)d_in[5];
    const float* be1 = (const float*)d_in[6];
    const float* W2  = (const float*)d_in[7];
    const float* b2  = (const float*)d_in[8];
    const float* g2  = (const float*)d_in[9];
    const float* be2 = (const float*)d_in[10];

    int n = in_sizes[0] / 64;     // 100000
    int e = in_sizes[1] / 2;      // 1600000
    const int* src = ei;
    const int* dst = ei + e;

    int nbuckets = (n + 255) / 256;                 // 391

    char* ws = (char*)d_ws;
    size_t off = 0;
    auto take = [&](size_t bytes) -> void* {
        void* p = ws + off;
        off = (off + bytes + 255) & ~(size_t)255;
        return p;
    };
    float*    dinv      = (float*)   take((size_t)n * 4);
    int*      row_start = (int*)     take((size_t)n * 4);
    int*      row_end   = (int*)     take((size_t)n * 4);
    int*      gcnt      = (int*)     take(NBMAX * 4);
    unsigned* stage     = (unsigned*)take((size_t)nbuckets * BCAP * 4);
    int*      csr_src   = (int*)     take((size_t)nbuckets * BCAP * 4);
    unsigned* xb        = (unsigned*)take((size_t)n * 64 * 2);
    unsigned* aggb      = (unsigned*)take((size_t)n * 64 * 2);
    unsigned* hb        = (unsigned*)take((size_t)n * 128 * 2);
    unsigned* agg2b     = (unsigned*)take((size_t)n * 128 * 2);

    hipMemsetAsync(gcnt, 0, NBMAX * 4, stream);
    hipMemsetAsync(d_out, 0, (size_t)out_size * 4, stream);

    int nbk = (e + CHUNK - 1) / CHUNK;
    k_bucket<<<nbk, 256, 0, stream>>>(src, dst, e, gcnt, stage);
    k_csr<<<nbuckets, 256, 0, stream>>>(stage, gcnt, csr_src, row_start, row_end,
                                        dinv, x, xb, n);

    k_agg64b<<<2048, 256, 0, stream>>>((const uint4*)xb, dinv, row_start, row_end,
                                       csr_src, (uint4*)aggb, n);

    int ntiles = n / 16;  // 6250
    int mmblocks = (ntiles + 3) / 4;
    k_mm1<<<mmblocks, 256, 0, stream>>>(aggb, W1, b1, g1, be1, dinv,
                                        (unsigned short*)hb, ntiles);

    k_agg128b<<<2048, 256, 0, stream>>>((const uint4*)hb, dinv, row_start, row_end,
                                        csr_src, (uint4*)agg2b, n);

    k_mm2p<<<mmblocks, 256, 0, stream>>>(agg2b, W2, b2, g2, be2, bat,
                                         (float*)d_out, ntiles, n);
}

// Round 9
// 220.657 us; speedup vs baseline: 5.1650x; 1.0106x over previous
//
#include <hip/hip_runtime.h>
#include <hip/hip_bf16.h>

#define LN_EPS 1e-5f

typedef __attribute__((ext_vector_type(8))) short short8v;
typedef __attribute__((ext_vector_type(4))) float float4v;

__device__ __forceinline__ float bflo(unsigned u) { return __uint_as_float(u << 16); }
__device__ __forceinline__ float bfhi(unsigned u) { return __uint_as_float(u & 0xffff0000u); }
__device__ __forceinline__ unsigned short f2bf(float f) {
    __hip_bfloat16 b = __float2bfloat16(f);
    return *reinterpret_cast<unsigned short*>(&b);
}
__device__ __forceinline__ unsigned pack2(float x, float y) {
    __hip_bfloat162 t = __float22bfloat162_rn(make_float2(x, y));
    return *reinterpret_cast<unsigned*>(&t);
}
__device__ __forceinline__ void add8(float* a, uint4 u) {
    a[0] += bflo(u.x); a[1] += bfhi(u.x);
    a[2] += bflo(u.y); a[3] += bfhi(u.y);
    a[4] += bflo(u.z); a[5] += bfhi(u.z);
    a[6] += bflo(u.w); a[7] += bfhi(u.w);
}

union U4S8 { uint4 u; short8v s; };

// ---------------- bucketed CSR build, fixed-capacity regions ----------------
// bucket b = dst >> 8 (256 nodes/bucket). Region b = [b*BCAP, b*BCAP+cnt_b).
// stage entry: src | (dst&0xff)<<24  (src < 2^24)

#define CHUNK 4096
#define NBMAX 512
#define BCAP 5120
#define CSRCAP 8192

__launch_bounds__(256)
__global__ void k_bucket(const int* __restrict__ src, const int* __restrict__ dst, int e,
                         int* __restrict__ gcnt, unsigned* __restrict__ stage) {
    __shared__ unsigned ebuf[CHUNK];
    __shared__ unsigned short ebkt[CHUNK];
    __shared__ int hist[NBMAX];
    __shared__ int base[NBMAX];
    int tid = threadIdx.x;
    int c0 = blockIdx.x * CHUNK;
    if (c0 >= e) return;
    int cnt = min(CHUNK, e - c0);

    for (int t = tid; t < NBMAX; t += 256) hist[t] = 0;
    __syncthreads();
    for (int t = tid; t < cnt; t += 256) {
        unsigned s = (unsigned)src[c0 + t];
        unsigned d = (unsigned)dst[c0 + t];
        ebuf[t] = s | ((d & 0xffu) << 24);
        ebkt[t] = (unsigned short)(d >> 8);
        atomicAdd(&hist[d >> 8], 1);
    }
    __syncthreads();
    for (int b = tid; b < NBMAX; b += 256) {
        int h = hist[b];
        if (h > 0) base[b] = b * BCAP + atomicAdd(&gcnt[b], h);
    }
    __syncthreads();
    for (int t = tid; t < cnt; t += 256) {
        int p = atomicAdd(&base[ebkt[t]], 1);
        stage[p] = ebuf[t];
    }
}

// pass 2: degrees -> row_start/row_end/dinv, rank-scatter CSR via LDS,
// coalesced write-out, AND pack x -> xb (pre-scaled by dinv).
__launch_bounds__(256)
__global__ void k_csr(const unsigned* __restrict__ stage, const int* __restrict__ gcnt,
                      int* __restrict__ csr_src, int* __restrict__ row_start,
                      int* __restrict__ row_end, float* __restrict__ dinv,
                      const float* __restrict__ x, unsigned* __restrict__ xb, int n) {
    __shared__ int cntl[256];
    __shared__ int sc[256];
    __shared__ int excl[256];
    __shared__ float dfl[256];
    __shared__ int cbuf[CSRCAP];
    int b = blockIdx.x;
    int lo = b << 8;
    int nn = min(n - lo, 256);
    int tid = threadIdx.x;
    int s0 = b * BCAP;
    int cntB = gcnt[b];

    cntl[tid] = 0;
    __syncthreads();
    for (int t = tid; t < cntB; t += 256) {
        int dl = (int)(stage[s0 + t] >> 24);
        atomicAdd(&cntl[dl], 1);
    }
    __syncthreads();
    int deg = (tid < nn) ? cntl[tid] : 0;
    sc[tid] = deg; __syncthreads();
    for (int o = 1; o < 256; o <<= 1) {
        int t = (tid >= o) ? sc[tid - o] : 0;
        __syncthreads();
        sc[tid] += t;
        __syncthreads();
    }
    excl[tid] = sc[tid] - deg;
    float dv = rsqrtf((float)(deg + 1));
    dfl[tid] = dv;
    if (tid < nn) {
        row_start[lo + tid] = s0 + excl[tid];
        row_end[lo + tid]   = s0 + excl[tid] + deg;
        dinv[lo + tid] = dv;
    }
    cntl[tid] = 0;
    __syncthreads();
    for (int t = tid; t < cntB; t += 256) {
        unsigned ed = stage[s0 + t];
        int dl = (int)(ed >> 24);
        int r = atomicAdd(&cntl[dl], 1);
        int p = excl[dl] + r;
        if (p < CSRCAP) cbuf[p] = (int)(ed & 0x00ffffffu);
        else csr_src[s0 + p] = (int)(ed & 0x00ffffffu);
    }
    __syncthreads();
    int lim = min(cntB, CSRCAP);
    for (int t = tid; t < lim; t += 256) csr_src[s0 + t] = cbuf[t];

    // pack x rows [lo, lo+nn) -> xb, scaled by dinv (float4 -> uint2)
    const float4* x4 = (const float4*)x;
    uint2* xb2 = (uint2*)xb;
    for (int idx = tid; idx < nn * 16; idx += 256) {
        int node = idx >> 4, c = idx & 15;
        size_t p = ((size_t)(lo + node) << 4) + c;
        float4 v = x4[p];
        float d = dfl[node];
        xb2[p] = make_uint2(pack2(v.x * d, v.y * d), pack2(v.z * d, v.w * d));
    }
}

// ---------------- Aggregation: out[d] = dinv[d] * (x'[d] + sum x'[s]) ----------------

__global__ void k_agg64b(const uint4* __restrict__ x4, const float* __restrict__ dinv,
                         const int* __restrict__ row_start, const int* __restrict__ row_end,
                         const int* __restrict__ csr_src, uint4* __restrict__ out4, int n) {
    int lane = threadIdx.x & 63;
    int g = lane >> 3, c = lane & 7;
    int wid = (blockIdx.x * blockDim.x + threadIdx.x) >> 6;
    int nw = (gridDim.x * blockDim.x) >> 6;
    for (int i = wid; i < n; i += nw) {
        float a[8] = {0.f, 0.f, 0.f, 0.f, 0.f, 0.f, 0.f, 0.f};
        if (g == 0) {
            uint4 su = x4[(size_t)i * 8 + c];
            add8(a, su);
        }
        int j0 = row_start[i], j1 = row_end[i];
        int j = j0 + g;
        for (; j + 8 < j1; j += 16) {
            int s0 = csr_src[j], s1 = csr_src[j + 8];
            uint4 u0 = x4[(size_t)s0 * 8 + c];
            uint4 u1 = x4[(size_t)s1 * 8 + c];
            add8(a, u0);
            add8(a, u1);
        }
        if (j < j1) {
            int s0 = csr_src[j];
            uint4 u0 = x4[(size_t)s0 * 8 + c];
            add8(a, u0);
        }
        #pragma unroll
        for (int k = 0; k < 8; ++k) {
            a[k] += __shfl_xor(a[k], 8);
            a[k] += __shfl_xor(a[k], 16);
            a[k] += __shfl_xor(a[k], 32);
        }
        if (g == 0) {
            float di = dinv[i];
            uint4 o;
            o.x = pack2(a[0] * di, a[1] * di);
            o.y = pack2(a[2] * di, a[3] * di);
            o.z = pack2(a[4] * di, a[5] * di);
            o.w = pack2(a[6] * di, a[7] * di);
            out4[(size_t)i * 8 + c] = o;
        }
    }
}

__global__ void k_agg128b(const uint4* __restrict__ h4, const float* __restrict__ dinv,
                          const int* __restrict__ row_start, const int* __restrict__ row_end,
                          const int* __restrict__ csr_src, uint4* __restrict__ out4, int n) {
    int lane = threadIdx.x & 63;
    int q = lane >> 4, c = lane & 15;
    int wid = (blockIdx.x * blockDim.x + threadIdx.x) >> 6;
    int nw = (gridDim.x * blockDim.x) >> 6;
    for (int i = wid; i < n; i += nw) {
        float a[8] = {0.f, 0.f, 0.f, 0.f, 0.f, 0.f, 0.f, 0.f};
        if (q == 0) {
            uint4 su = h4[(size_t)i * 16 + c];
            add8(a, su);
        }
        int j0 = row_start[i], j1 = row_end[i];
        int j = j0 + q;
        for (; j + 12 < j1; j += 16) {
            int s0 = csr_src[j], s1 = csr_src[j + 4];
            int s2 = csr_src[j + 8], s3 = csr_src[j + 12];
            uint4 u0 = h4[(size_t)s0 * 16 + c];
            uint4 u1 = h4[(size_t)s1 * 16 + c];
            uint4 u2 = h4[(size_t)s2 * 16 + c];
            uint4 u3 = h4[(size_t)s3 * 16 + c];
            add8(a, u0);
            add8(a, u1);
            add8(a, u2);
            add8(a, u3);
        }
        for (; j < j1; j += 4) {
            int s0 = csr_src[j];
            uint4 u0 = h4[(size_t)s0 * 16 + c];
            add8(a, u0);
        }
        #pragma unroll
        for (int k = 0; k < 8; ++k) {
            a[k] += __shfl_xor(a[k], 16);
            a[k] += __shfl_xor(a[k], 32);
        }
        if (q == 0) {
            float di = dinv[i];
            uint4 o;
            o.x = pack2(a[0] * di, a[1] * di);
            o.y = pack2(a[2] * di, a[3] * di);
            o.z = pack2(a[4] * di, a[5] * di);
            o.w = pack2(a[6] * di, a[7] * di);
            out4[(size_t)i * 16 + c] = o;
        }
    }
}

// ---------------- MFMA GEMM + LN (+ReLU) fused ----------------
// mfma_f32_16x16x32_bf16. A/B frag: k-slot = (lane>>4)*8 + j. C/D: col=lane&15, row=(lane>>4)*4+reg.
//
// PERMUTED h LAYOUT: mm1 stores its epilogue row with column c = cb*16+lc at
// permuted position p = lc*8+cb (one uint4 per reg per lane). Aggregation and
// dinv-scaling are elementwise over columns, so agg128b is unaffected.
// mm2p compensates: k-slot s = ks*32+lg*8+j of its A-read corresponds to
// actual column c(s) = j*16 + ks*4 + lg, so sB packs W2 row c(s) into slot s.

// agg[N][64] bf16 @ W1[64][128] -> LN -> relu -> *dinv[row] -> hb[N][128] bf16 (permuted)
__launch_bounds__(256)
__global__ void k_mm1(const unsigned* __restrict__ aggb, const float* __restrict__ W1,
                      const float* __restrict__ b1, const float* __restrict__ g1,
                      const float* __restrict__ be1, const float* __restrict__ dinv,
                      uint4* __restrict__ hb4, int ntiles) {
    int lane = threadIdx.x & 63;
    int wv = threadIdx.x >> 6;
    int wpb = blockDim.x >> 6;
    int lc = lane & 15, lg = lane >> 4;

    short8v B[2][8];
    #pragma unroll
    for (int ks = 0; ks < 2; ++ks)
        #pragma unroll
        for (int cb = 0; cb < 8; ++cb) {
            short8v f;
            #pragma unroll
            for (int j = 0; j < 8; ++j) {
                int k = ks * 32 + lg * 8 + j;
                f[j] = (short)f2bf(W1[k * 128 + cb * 16 + lc]);
            }
            B[ks][cb] = f;
        }
    float bs[8], gm[8], bt[8];
    #pragma unroll
    for (int cb = 0; cb < 8; ++cb) {
        bs[cb] = b1[cb * 16 + lc];
        gm[cb] = g1[cb * 16 + lc];
        bt[cb] = be1[cb * 16 + lc];
    }

    for (int t = blockIdx.x * wpb + wv; t < ntiles; t += gridDim.x * wpb) {
        size_t arow = (size_t)(t * 16 + lc) * 32;
        U4S8 a0, a1;
        a0.u = *(const uint4*)&aggb[arow + lg * 4];
        a1.u = *(const uint4*)&aggb[arow + 16 + lg * 4];
        float4v acc[8];
        #pragma unroll
        for (int cb = 0; cb < 8; ++cb) acc[cb] = (float4v){0.f, 0.f, 0.f, 0.f};
        #pragma unroll
        for (int cb = 0; cb < 8; ++cb) {
            acc[cb] = __builtin_amdgcn_mfma_f32_16x16x32_bf16(a0.s, B[0][cb], acc[cb], 0, 0, 0);
            acc[cb] = __builtin_amdgcn_mfma_f32_16x16x32_bf16(a1.s, B[1][cb], acc[cb], 0, 0, 0);
        }
        #pragma unroll
        for (int reg = 0; reg < 4; ++reg) {
            float s = 0.f, q = 0.f;
            #pragma unroll
            for (int cb = 0; cb < 8; ++cb) {
                float v = acc[cb][reg] + bs[cb];
                acc[cb][reg] = v;
                s += v; q = fmaf(v, v, q);
            }
            s += __shfl_xor(s, 1); q += __shfl_xor(q, 1);
            s += __shfl_xor(s, 2); q += __shfl_xor(q, 2);
            s += __shfl_xor(s, 4); q += __shfl_xor(q, 4);
            s += __shfl_xor(s, 8); q += __shfl_xor(q, 8);
            float mu = s * (1.f / 128.f);
            float var = fmaf(q, 1.f / 128.f, -mu * mu);
            float rstd = rsqrtf(var + LN_EPS);
            int rowi = t * 16 + lg * 4 + reg;
            float di = dinv[rowi];
            float o[8];
            #pragma unroll
            for (int cb = 0; cb < 8; ++cb)
                o[cb] = fmaxf(fmaf((acc[cb][reg] - mu) * rstd, gm[cb], bt[cb]), 0.f) * di;
            uint4 st;
            st.x = pack2(o[0], o[1]);
            st.y = pack2(o[2], o[3]);
            st.z = pack2(o[4], o[5]);
            st.w = pack2(o[6], o[7]);
            hb4[(size_t)rowi * 16 + lc] = st;   // permuted: pos = lc*8+cb
        }
    }
}

// agg2[N][128] bf16 (permuted) @ W2[128][128] -> LN -> scaled pooled atomicAdd into out[G][128]
__launch_bounds__(256)
__global__ void k_mm2p(const unsigned* __restrict__ aggb, const float* __restrict__ W2,
                       const float* __restrict__ b2, const float* __restrict__ g2,
                       const float* __restrict__ be2, const int* __restrict__ batch,
                       float* __restrict__ psum, int ntiles, int n) {
    __shared__ uint4 sB[4 * 8 * 64];   // 32 KiB
    for (int idx = threadIdx.x; idx < 2048; idx += blockDim.x) {
        int l = idx & 63;
        int f = idx >> 6;
        int ks = f >> 3, cb = f & 7;
        int lg = l >> 4;
        int col = cb * 16 + (l & 15);
        float p[8];
        #pragma unroll
        for (int j = 0; j < 8; ++j)
            p[j] = W2[(j * 16 + ks * 4 + lg) * 128 + col];   // permuted k-slot -> column
        uint4 v;
        v.x = pack2(p[0], p[1]); v.y = pack2(p[2], p[3]);
        v.z = pack2(p[4], p[5]); v.w = pack2(p[6], p[7]);
        sB[idx] = v;
    }
    __syncthreads();

    int lane = threadIdx.x & 63;
    int wv = threadIdx.x >> 6;
    int wpb = blockDim.x >> 6;
    int lc = lane & 15, lg = lane >> 4;
    float bs[8], gm[8], bt[8];
    #pragma unroll
    for (int cb = 0; cb < 8; ++cb) {
        bs[cb] = b2[cb * 16 + lc];
        gm[cb] = g2[cb * 16 + lc];
        bt[cb] = be2[cb * 16 + lc];
    }

    for (int t = blockIdx.x * wpb + wv; t < ntiles; t += gridDim.x * wpb) {
        int row0 = t * 16;
        size_t arow = (size_t)(row0 + lc) * 64;
        U4S8 a[4];
        #pragma unroll
        for (int ks = 0; ks < 4; ++ks)
            a[ks].u = *(const uint4*)&aggb[arow + ks * 16 + lg * 4];
        float4v acc[8];
        #pragma unroll
        for (int cb = 0; cb < 8; ++cb) acc[cb] = (float4v){0.f, 0.f, 0.f, 0.f};
        #pragma unroll
        for (int ks = 0; ks < 4; ++ks) {
            #pragma unroll
            for (int cb = 0; cb < 8; ++cb) {
                U4S8 fb;
                fb.u = sB[(ks * 8 + cb) * 64 + lane];
                acc[cb] = __builtin_amdgcn_mfma_f32_16x16x32_bf16(a[ks].s, fb.s, acc[cb], 0, 0, 0);
            }
        }
        #pragma unroll
        for (int reg = 0; reg < 4; ++reg) {
            float s = 0.f, q = 0.f;
            #pragma unroll
            for (int cb = 0; cb < 8; ++cb) {
                float v = acc[cb][reg] + bs[cb];
                acc[cb][reg] = v;
                s += v; q = fmaf(v, v, q);
            }
            s += __shfl_xor(s, 1); q += __shfl_xor(q, 1);
            s += __shfl_xor(s, 2); q += __shfl_xor(q, 2);
            s += __shfl_xor(s, 4); q += __shfl_xor(q, 4);
            s += __shfl_xor(s, 8); q += __shfl_xor(q, 8);
            float mu = s * (1.f / 128.f);
            float var = fmaf(q, 1.f / 128.f, -mu * mu);
            float rstd = rsqrtf(var + LN_EPS);
            #pragma unroll
            for (int cb = 0; cb < 8; ++cb)
                acc[cb][reg] = fmaf((acc[cb][reg] - mu) * rstd, gm[cb], bt[cb]);
        }
        int gmin = batch[row0];
        int gmax = batch[row0 + 15];
        int rg[4];
        #pragma unroll
        for (int reg = 0; reg < 4; ++reg) rg[reg] = batch[row0 + lg * 4 + reg];
        for (int g = gmin; g <= gmax; ++g) {
            int lo = 0, hi = n;
            while (lo < hi) { int m = (lo + hi) >> 1; if (batch[m] < g) lo = m + 1; else hi = m; }
            int st = lo;
            hi = n;
            while (lo < hi) { int m = (lo + hi) >> 1; if (batch[m] < g + 1) lo = m + 1; else hi = m; }
            float rc = 1.f / fmaxf((float)(lo - st), 1.f);
            #pragma unroll
            for (int cb = 0; cb < 8; ++cb) {
                float s = 0.f;
                #pragma unroll
                for (int reg = 0; reg < 4; ++reg)
                    s += (rg[reg] == g) ? acc[cb][reg] : 0.f;
                s += __shfl_xor(s, 16);
                s += __shfl_xor(s, 32);
                if (lg == 0) atomicAdd(&psum[g * 128 + cb * 16 + lc], s * rc);
            }
        }
    }
}

// ---------------- launch ----------------

extern "C" void kernel_launch(void* const* d_in, const int* in_sizes, int n_in,
                              void* d_out, int out_size, void* d_ws, size_t ws_size,
                              hipStream_t stream) {
    const float* x   = (const float*)d_in[0];
    const int*   ei  = (const int*)d_in[1];
    const int*   bat = (const int*)d_in[2];
    const float* W1  = (const float*)d_in[3];
    const float* b1  = (const float*)d_in[4];
    const float* g1  = (const float*)d_in[5];
    const float* be1 = (const float*)d_in[6];
    const float* W2  = (const float*)d_in[7];
    const float* b2  = (const float*)d_in[8];
    const float* g2  = (const float*)d_in[9];
    const float* be2 = (const float*)d_in[10];

    int n = in_sizes[0] / 64;     // 100000
    int e = in_sizes[1] / 2;      // 1600000
    const int* src = ei;
    const int* dst = ei + e;

    int nbuckets = (n + 255) / 256;                 // 391

    char* ws = (char*)d_ws;
    size_t off = 0;
    auto take = [&](size_t bytes) -> void* {
        void* p = ws + off;
        off = (off + bytes + 255) & ~(size_t)255;
        return p;
    };
    float*    dinv      = (float*)   take((size_t)n * 4);
    int*      row_start = (int*)     take((size_t)n * 4);
    int*      row_end   = (int*)     take((size_t)n * 4);
    int*      gcnt      = (int*)     take(NBMAX * 4);
    unsigned* stage     = (unsigned*)take((size_t)nbuckets * BCAP * 4);
    int*      csr_src   = (int*)     take((size_t)nbuckets * BCAP * 4);
    unsigned* xb        = (unsigned*)take((size_t)n * 64 * 2);
    unsigned* aggb      = (unsigned*)take((size_t)n * 64 * 2);
    unsigned* hb        = (unsigned*)take((size_t)n * 128 * 2);
    unsigned* agg2b     = (unsigned*)take((size_t)n * 128 * 2);

    hipMemsetAsync(gcnt, 0, NBMAX * 4, stream);
    hipMemsetAsync(d_out, 0, (size_t)out_size * 4, stream);

    int nbk = (e + CHUNK - 1) / CHUNK;
    k_bucket<<<nbk, 256, 0, stream>>>(src, dst, e, gcnt, stage);
    k_csr<<<nbuckets, 256, 0, stream>>>(stage, gcnt, csr_src, row_start, row_end,
                                        dinv, x, xb, n);

    k_agg64b<<<2048, 256, 0, stream>>>((const uint4*)xb, dinv, row_start, row_end,
                                       csr_src, (uint4*)aggb, n);

    int ntiles = n / 16;  // 6250
    k_mm1<<<626, 256, 0, stream>>>(aggb, W1, b1, g1, be1, dinv,
                                   (uint4*)hb, ntiles);

    k_agg128b<<<2048, 256, 0, stream>>>((const uint4*)hb, dinv, row_start, row_end,
                                        csr_src, (uint4*)agg2b, n);

    k_mm2p<<<626, 256, 0, stream>>>(agg2b, W2, b2, g2, be2, bat,
                                    (float*)d_out, ntiles, n);
}

// Round 10
// 215.942 us; speedup vs baseline: 5.2777x; 1.0218x over previous
//
#include <hip/hip_runtime.h>
#include <hip/hip_bf16.h>

#define LN_EPS 1e-5f

typedef __attribute__((ext_vector_type(8))) short short8v;
typedef __attribute__((ext_vector_type(4))) float float4v;

__device__ __forceinline__ float bflo(unsigned u) { return __uint_as_float(u << 16); }
__device__ __forceinline__ float bfhi(unsigned u) { return __uint_as_float(u & 0xffff0000u); }
__device__ __forceinline__ unsigned pack2(float x, float y) {
    __hip_bfloat162 t = __float22bfloat162_rn(make_float2(x, y));
    return *reinterpret_cast<unsigned*>(&t);
}
__device__ __forceinline__ void add8(float* a, uint4 u) {
    a[0] += bflo(u.x); a[1] += bfhi(u.x);
    a[2] += bflo(u.y); a[3] += bfhi(u.y);
    a[4] += bflo(u.z); a[5] += bfhi(u.z);
    a[6] += bflo(u.w); a[7] += bfhi(u.w);
}

union U4S8 { uint4 u; short8v s; };

// ---------------- bucketed CSR build, fixed-capacity regions ----------------
// bucket b = dst >> 8 (256 nodes/bucket). Region b = [b*BCAP, b*BCAP+cnt_b).
// stage entry: src | (dst&0xff)<<24  (src < 2^24)

#define CHUNK 4096
#define NBMAX 512
#define BCAP 5120

__launch_bounds__(256)
__global__ void k_bucket(const int* __restrict__ src, const int* __restrict__ dst, int e,
                         int* __restrict__ gcnt, unsigned* __restrict__ stage) {
    __shared__ unsigned ebuf[CHUNK];
    __shared__ unsigned short ebkt[CHUNK];
    __shared__ int hist[NBMAX];
    __shared__ int base[NBMAX];
    int tid = threadIdx.x;
    int c0 = blockIdx.x * CHUNK;
    if (c0 >= e) return;
    int cnt = min(CHUNK, e - c0);

    for (int t = tid; t < NBMAX; t += 256) hist[t] = 0;
    __syncthreads();
    for (int t = tid; t < cnt; t += 256) {
        unsigned s = (unsigned)src[c0 + t];
        unsigned d = (unsigned)dst[c0 + t];
        ebuf[t] = s | ((d & 0xffu) << 24);
        ebkt[t] = (unsigned short)(d >> 8);
        atomicAdd(&hist[d >> 8], 1);
    }
    __syncthreads();
    for (int b = tid; b < NBMAX; b += 256) {
        int h = hist[b];
        if (h > 0) base[b] = b * BCAP + atomicAdd(&gcnt[b], h);
    }
    __syncthreads();
    for (int t = tid; t < cnt; t += 256) {
        int p = atomicAdd(&base[ebkt[t]], 1);
        stage[p] = ebuf[t];
    }
}

// pass 2: degrees -> row_start/row_end/dinv, direct global rank-scatter of CSR
// (region is L2-resident so scattered 4B stores coalesce in L2), AND pack x -> xb.
__launch_bounds__(256)
__global__ void k_csr(const unsigned* __restrict__ stage, const int* __restrict__ gcnt,
                      int* __restrict__ csr_src, int* __restrict__ row_start,
                      int* __restrict__ row_end, float* __restrict__ dinv,
                      const float* __restrict__ x, unsigned* __restrict__ xb, int n) {
    __shared__ int cntl[256];
    __shared__ int sc[256];
    __shared__ int excl[256];
    __shared__ float dfl[256];
    int b = blockIdx.x;
    int lo = b << 8;
    int nn = min(n - lo, 256);
    int tid = threadIdx.x;
    int s0 = b * BCAP;
    int cntB = gcnt[b];

    cntl[tid] = 0;
    __syncthreads();
    for (int t = tid; t < cntB; t += 256) {
        int dl = (int)(stage[s0 + t] >> 24);
        atomicAdd(&cntl[dl], 1);
    }
    __syncthreads();
    int deg = (tid < nn) ? cntl[tid] : 0;
    sc[tid] = deg; __syncthreads();
    for (int o = 1; o < 256; o <<= 1) {
        int t = (tid >= o) ? sc[tid - o] : 0;
        __syncthreads();
        sc[tid] += t;
        __syncthreads();
    }
    excl[tid] = sc[tid] - deg;
    float dv = rsqrtf((float)(deg + 1));
    dfl[tid] = dv;
    if (tid < nn) {
        row_start[lo + tid] = s0 + excl[tid];
        row_end[lo + tid]   = s0 + excl[tid] + deg;
        dinv[lo + tid] = dv;
    }
    cntl[tid] = 0;
    __syncthreads();
    for (int t = tid; t < cntB; t += 256) {
        unsigned ed = stage[s0 + t];
        int dl = (int)(ed >> 24);
        int r = atomicAdd(&cntl[dl], 1);
        csr_src[s0 + excl[dl] + r] = (int)(ed & 0x00ffffffu);
    }

    // pack x rows [lo, lo+nn) -> xb, scaled by dinv (float4 -> uint2)
    const float4* x4 = (const float4*)x;
    uint2* xb2 = (uint2*)xb;
    for (int idx = tid; idx < nn * 16; idx += 256) {
        int node = idx >> 4, c = idx & 15;
        size_t p = ((size_t)(lo + node) << 4) + c;
        float4 v = x4[p];
        float d = dfl[node];
        xb2[p] = make_uint2(pack2(v.x * d, v.y * d), pack2(v.z * d, v.w * d));
    }
}

// per-graph reciprocal counts (batch sorted)
__global__ void k_rc(const int* __restrict__ batch, int n, float* __restrict__ rc) {
    int g = threadIdx.x;
    int lo = 0, hi = n;
    while (lo < hi) { int m = (lo + hi) >> 1; if (batch[m] < g) lo = m + 1; else hi = m; }
    int st = lo;
    hi = n;
    while (lo < hi) { int m = (lo + hi) >> 1; if (batch[m] < g + 1) lo = m + 1; else hi = m; }
    rc[g] = 1.f / fmaxf((float)(lo - st), 1.f);
}

// ---------------- Aggregation: out[d] = dinv[d] * (x'[d] + sum x'[s]) ----------------

__global__ void k_agg64b(const uint4* __restrict__ x4, const float* __restrict__ dinv,
                         const int* __restrict__ row_start, const int* __restrict__ row_end,
                         const int* __restrict__ csr_src, uint4* __restrict__ out4, int n) {
    int lane = threadIdx.x & 63;
    int g = lane >> 3, c = lane & 7;
    int wid = (blockIdx.x * blockDim.x + threadIdx.x) >> 6;
    int nw = (gridDim.x * blockDim.x) >> 6;
    for (int i = wid; i < n; i += nw) {
        float a[8] = {0.f, 0.f, 0.f, 0.f, 0.f, 0.f, 0.f, 0.f};
        if (g == 0) {
            uint4 su = x4[(size_t)i * 8 + c];
            add8(a, su);
        }
        int j0 = row_start[i], j1 = row_end[i];
        int j = j0 + g;
        for (; j + 8 < j1; j += 16) {
            int s0 = csr_src[j], s1 = csr_src[j + 8];
            uint4 u0 = x4[(size_t)s0 * 8 + c];
            uint4 u1 = x4[(size_t)s1 * 8 + c];
            add8(a, u0);
            add8(a, u1);
        }
        if (j < j1) {
            int s0 = csr_src[j];
            uint4 u0 = x4[(size_t)s0 * 8 + c];
            add8(a, u0);
        }
        #pragma unroll
        for (int k = 0; k < 8; ++k) {
            a[k] += __shfl_xor(a[k], 8);
            a[k] += __shfl_xor(a[k], 16);
            a[k] += __shfl_xor(a[k], 32);
        }
        if (g == 0) {
            float di = dinv[i];
            uint4 o;
            o.x = pack2(a[0] * di, a[1] * di);
            o.y = pack2(a[2] * di, a[3] * di);
            o.z = pack2(a[4] * di, a[5] * di);
            o.w = pack2(a[6] * di, a[7] * di);
            out4[(size_t)i * 8 + c] = o;
        }
    }
}

__global__ void k_agg128b(const uint4* __restrict__ h4, const float* __restrict__ dinv,
                          const int* __restrict__ row_start, const int* __restrict__ row_end,
                          const int* __restrict__ csr_src, uint4* __restrict__ out4, int n) {
    int lane = threadIdx.x & 63;
    int q = lane >> 4, c = lane & 15;
    int wid = (blockIdx.x * blockDim.x + threadIdx.x) >> 6;
    int nw = (gridDim.x * blockDim.x) >> 6;
    for (int i = wid; i < n; i += nw) {
        float a[8] = {0.f, 0.f, 0.f, 0.f, 0.f, 0.f, 0.f, 0.f};
        if (q == 0) {
            uint4 su = h4[(size_t)i * 16 + c];
            add8(a, su);
        }
        int j0 = row_start[i], j1 = row_end[i];
        int j = j0 + q;
        for (; j + 12 < j1; j += 16) {
            int s0 = csr_src[j], s1 = csr_src[j + 4];
            int s2 = csr_src[j + 8], s3 = csr_src[j + 12];
            uint4 u0 = h4[(size_t)s0 * 16 + c];
            uint4 u1 = h4[(size_t)s1 * 16 + c];
            uint4 u2 = h4[(size_t)s2 * 16 + c];
            uint4 u3 = h4[(size_t)s3 * 16 + c];
            add8(a, u0);
            add8(a, u1);
            add8(a, u2);
            add8(a, u3);
        }
        for (; j < j1; j += 4) {
            int s0 = csr_src[j];
            uint4 u0 = h4[(size_t)s0 * 16 + c];
            add8(a, u0);
        }
        #pragma unroll
        for (int k = 0; k < 8; ++k) {
            a[k] += __shfl_xor(a[k], 16);
            a[k] += __shfl_xor(a[k], 32);
        }
        if (q == 0) {
            float di = dinv[i];
            uint4 o;
            o.x = pack2(a[0] * di, a[1] * di);
            o.y = pack2(a[2] * di, a[3] * di);
            o.z = pack2(a[4] * di, a[5] * di);
            o.w = pack2(a[6] * di, a[7] * di);
            out4[(size_t)i * 16 + c] = o;
        }
    }
}

// ---------------- MFMA GEMM + LN (+ReLU) fused ----------------
// mfma_f32_16x16x32_bf16. A/B frag: k-slot = (lane>>4)*8 + j. C/D: col=lane&15, row=(lane>>4)*4+reg.
//
// PERMUTED h LAYOUT: mm1 stores column c = cb*16+lc at position p = lc*8+cb
// (one uint4 per reg per lane). Elementwise agg/dinv commute with the permutation;
// mm2p compensates by packing W2 row c(s) = j*16+ks*4+lg into k-slot s.

// agg[N][64] bf16 @ W1[64][128] -> LN -> relu -> *dinv[row] -> hb[N][128] bf16 (permuted)
__launch_bounds__(256)
__global__ void k_mm1(const unsigned* __restrict__ aggb, const float* __restrict__ W1,
                      const float* __restrict__ b1, const float* __restrict__ g1,
                      const float* __restrict__ be1, const float* __restrict__ dinv,
                      uint4* __restrict__ hb4, int ntiles) {
    __shared__ uint4 sB[2 * 8 * 64];   // 16 KiB: frag (ks*8+cb), lane
    for (int idx = threadIdx.x; idx < 1024; idx += blockDim.x) {
        int l = idx & 63;
        int f = idx >> 6;
        int ks = f >> 3, cb = f & 7;
        int kb = ks * 32 + (l >> 4) * 8;
        int col = cb * 16 + (l & 15);
        float p[8];
        #pragma unroll
        for (int j = 0; j < 8; ++j) p[j] = W1[(kb + j) * 128 + col];
        uint4 v;
        v.x = pack2(p[0], p[1]); v.y = pack2(p[2], p[3]);
        v.z = pack2(p[4], p[5]); v.w = pack2(p[6], p[7]);
        sB[idx] = v;
    }
    __syncthreads();

    int lane = threadIdx.x & 63;
    int wv = threadIdx.x >> 6;
    int wpb = blockDim.x >> 6;
    int lc = lane & 15, lg = lane >> 4;

    // copy B fragments to registers once (register-resident main loop)
    U4S8 B[2][8];
    #pragma unroll
    for (int ks = 0; ks < 2; ++ks)
        #pragma unroll
        for (int cb = 0; cb < 8; ++cb)
            B[ks][cb].u = sB[(ks * 8 + cb) * 64 + lane];

    float bs[8], gm[8], bt[8];
    #pragma unroll
    for (int cb = 0; cb < 8; ++cb) {
        bs[cb] = b1[cb * 16 + lc];
        gm[cb] = g1[cb * 16 + lc];
        bt[cb] = be1[cb * 16 + lc];
    }

    for (int t = blockIdx.x * wpb + wv; t < ntiles; t += gridDim.x * wpb) {
        size_t arow = (size_t)(t * 16 + lc) * 32;
        U4S8 a0, a1;
        a0.u = *(const uint4*)&aggb[arow + lg * 4];
        a1.u = *(const uint4*)&aggb[arow + 16 + lg * 4];
        float4v acc[8];
        #pragma unroll
        for (int cb = 0; cb < 8; ++cb) acc[cb] = (float4v){0.f, 0.f, 0.f, 0.f};
        #pragma unroll
        for (int cb = 0; cb < 8; ++cb) {
            acc[cb] = __builtin_amdgcn_mfma_f32_16x16x32_bf16(a0.s, B[0][cb].s, acc[cb], 0, 0, 0);
            acc[cb] = __builtin_amdgcn_mfma_f32_16x16x32_bf16(a1.s, B[1][cb].s, acc[cb], 0, 0, 0);
        }
        #pragma unroll
        for (int reg = 0; reg < 4; ++reg) {
            float s = 0.f, q = 0.f;
            #pragma unroll
            for (int cb = 0; cb < 8; ++cb) {
                float v = acc[cb][reg] + bs[cb];
                acc[cb][reg] = v;
                s += v; q = fmaf(v, v, q);
            }
            s += __shfl_xor(s, 1); q += __shfl_xor(q, 1);
            s += __shfl_xor(s, 2); q += __shfl_xor(q, 2);
            s += __shfl_xor(s, 4); q += __shfl_xor(q, 4);
            s += __shfl_xor(s, 8); q += __shfl_xor(q, 8);
            float mu = s * (1.f / 128.f);
            float var = fmaf(q, 1.f / 128.f, -mu * mu);
            float rstd = rsqrtf(var + LN_EPS);
            int rowi = t * 16 + lg * 4 + reg;
            float di = dinv[rowi];
            float o[8];
            #pragma unroll
            for (int cb = 0; cb < 8; ++cb)
                o[cb] = fmaxf(fmaf((acc[cb][reg] - mu) * rstd, gm[cb], bt[cb]), 0.f) * di;
            uint4 st;
            st.x = pack2(o[0], o[1]);
            st.y = pack2(o[2], o[3]);
            st.z = pack2(o[4], o[5]);
            st.w = pack2(o[6], o[7]);
            hb4[(size_t)rowi * 16 + lc] = st;   // permuted: pos = lc*8+cb
        }
    }
}

// agg2[N][128] bf16 (permuted) @ W2[128][128] -> LN -> scaled pooled atomicAdd into out[G][128]
__launch_bounds__(256)
__global__ void k_mm2p(const unsigned* __restrict__ aggb, const float* __restrict__ W2,
                       const float* __restrict__ b2, const float* __restrict__ g2,
                       const float* __restrict__ be2, const int* __restrict__ batch,
                       const float* __restrict__ rc, float* __restrict__ psum, int ntiles) {
    __shared__ uint4 sB[4 * 8 * 64];   // 32 KiB
    for (int idx = threadIdx.x; idx < 2048; idx += blockDim.x) {
        int l = idx & 63;
        int f = idx >> 6;
        int ks = f >> 3, cb = f & 7;
        int lg = l >> 4;
        int col = cb * 16 + (l & 15);
        float p[8];
        #pragma unroll
        for (int j = 0; j < 8; ++j)
            p[j] = W2[(j * 16 + ks * 4 + lg) * 128 + col];   // permuted k-slot -> column
        uint4 v;
        v.x = pack2(p[0], p[1]); v.y = pack2(p[2], p[3]);
        v.z = pack2(p[4], p[5]); v.w = pack2(p[6], p[7]);
        sB[idx] = v;
    }
    __syncthreads();

    int lane = threadIdx.x & 63;
    int wv = threadIdx.x >> 6;
    int wpb = blockDim.x >> 6;
    int lc = lane & 15, lg = lane >> 4;
    float bs[8], gm[8], bt[8];
    #pragma unroll
    for (int cb = 0; cb < 8; ++cb) {
        bs[cb] = b2[cb * 16 + lc];
        gm[cb] = g2[cb * 16 + lc];
        bt[cb] = be2[cb * 16 + lc];
    }

    for (int t = blockIdx.x * wpb + wv; t < ntiles; t += gridDim.x * wpb) {
        int row0 = t * 16;
        size_t arow = (size_t)(row0 + lc) * 64;
        U4S8 a[4];
        #pragma unroll
        for (int ks = 0; ks < 4; ++ks)
            a[ks].u = *(const uint4*)&aggb[arow + ks * 16 + lg * 4];
        float4v acc[8];
        #pragma unroll
        for (int cb = 0; cb < 8; ++cb) acc[cb] = (float4v){0.f, 0.f, 0.f, 0.f};
        #pragma unroll
        for (int ks = 0; ks < 4; ++ks) {
            #pragma unroll
            for (int cb = 0; cb < 8; ++cb) {
                U4S8 fb;
                fb.u = sB[(ks * 8 + cb) * 64 + lane];
                acc[cb] = __builtin_amdgcn_mfma_f32_16x16x32_bf16(a[ks].s, fb.s, acc[cb], 0, 0, 0);
            }
        }
        #pragma unroll
        for (int reg = 0; reg < 4; ++reg) {
            float s = 0.f, q = 0.f;
            #pragma unroll
            for (int cb = 0; cb < 8; ++cb) {
                float v = acc[cb][reg] + bs[cb];
                acc[cb][reg] = v;
                s += v; q = fmaf(v, v, q);
            }
            s += __shfl_xor(s, 1); q += __shfl_xor(q, 1);
            s += __shfl_xor(s, 2); q += __shfl_xor(q, 2);
            s += __shfl_xor(s, 4); q += __shfl_xor(q, 4);
            s += __shfl_xor(s, 8); q += __shfl_xor(q, 8);
            float mu = s * (1.f / 128.f);
            float var = fmaf(q, 1.f / 128.f, -mu * mu);
            float rstd = rsqrtf(var + LN_EPS);
            #pragma unroll
            for (int cb = 0; cb < 8; ++cb)
                acc[cb][reg] = fmaf((acc[cb][reg] - mu) * rstd, gm[cb], bt[cb]);
        }
        int gmin = batch[row0];
        int gmax = batch[row0 + 15];
        int rg[4];
        #pragma unroll
        for (int reg = 0; reg < 4; ++reg) rg[reg] = batch[row0 + lg * 4 + reg];
        for (int g = gmin; g <= gmax; ++g) {
            float rcg = rc[g];
            #pragma unroll
            for (int cb = 0; cb < 8; ++cb) {
                float s = 0.f;
                #pragma unroll
                for (int reg = 0; reg < 4; ++reg)
                    s += (rg[reg] == g) ? acc[cb][reg] : 0.f;
                s += __shfl_xor(s, 16);
                s += __shfl_xor(s, 32);
                if (lg == 0) atomicAdd(&psum[g * 128 + cb * 16 + lc], s * rcg);
            }
        }
    }
}

// ---------------- launch ----------------

extern "C" void kernel_launch(void* const* d_in, const int* in_sizes, int n_in,
                              void* d_out, int out_size, void* d_ws, size_t ws_size,
                              hipStream_t stream) {
    const float* x   = (const float*)d_in[0];
    const int*   ei  = (const int*)d_in[1];
    const int*   bat = (const int*)d_in[2];
    const float* W1  = (const float*)d_in[3];
    const float* b1  = (const float*)d_in[4];
    const float* g1  = (const float*)d_in[5];
    const float* be1 = (const float*)d_in[6];
    const float* W2  = (const float*)d_in[7];
    const float* b2  = (const float*)d_in[8];
    const float* g2  = (const float*)d_in[9];
    const float* be2 = (const float*)d_in[10];

    int n = in_sizes[0] / 64;     // 100000
    int e = in_sizes[1] / 2;      // 1600000
    int G = out_size / 128;       // 128
    const int* src = ei;
    const int* dst = ei + e;

    int nbuckets = (n + 255) / 256;                 // 391

    char* ws = (char*)d_ws;
    size_t off = 0;
    auto take = [&](size_t bytes) -> void* {
        void* p = ws + off;
        off = (off + bytes + 255) & ~(size_t)255;
        return p;
    };
    float*    dinv      = (float*)   take((size_t)n * 4);
    int*      row_start = (int*)     take((size_t)n * 4);
    int*      row_end   = (int*)     take((size_t)n * 4);
    int*      gcnt      = (int*)     take(NBMAX * 4);
    float*    rcbuf     = (float*)   take((size_t)G * 4);
    unsigned* stage     = (unsigned*)take((size_t)nbuckets * BCAP * 4);
    int*      csr_src   = (int*)     take((size_t)nbuckets * BCAP * 4);
    unsigned* xb        = (unsigned*)take((size_t)n * 64 * 2);
    unsigned* aggb      = (unsigned*)take((size_t)n * 64 * 2);
    unsigned* hb        = (unsigned*)take((size_t)n * 128 * 2);
    unsigned* agg2b     = (unsigned*)take((size_t)n * 128 * 2);

    hipMemsetAsync(gcnt, 0, NBMAX * 4, stream);
    hipMemsetAsync(d_out, 0, (size_t)out_size * 4, stream);

    int nbk = (e + CHUNK - 1) / CHUNK;
    k_bucket<<<nbk, 256, 0, stream>>>(src, dst, e, gcnt, stage);
    k_csr<<<nbuckets, 256, 0, stream>>>(stage, gcnt, csr_src, row_start, row_end,
                                        dinv, x, xb, n);
    k_rc<<<1, G, 0, stream>>>(bat, n, rcbuf);

    k_agg64b<<<2048, 256, 0, stream>>>((const uint4*)xb, dinv, row_start, row_end,
                                       csr_src, (uint4*)aggb, n);

    int ntiles = n / 16;  // 6250
    k_mm1<<<626, 256, 0, stream>>>(aggb, W1, b1, g1, be1, dinv,
                                   (uint4*)hb, ntiles);

    k_agg128b<<<2048, 256, 0, stream>>>((const uint4*)hb, dinv, row_start, row_end,
                                        csr_src, (uint4*)agg2b, n);

    k_mm2p<<<626, 256, 0, stream>>>(agg2b, W2, b2, g2, be2, bat, rcbuf,
                                    (float*)d_out, ntiles);
}